// Round 6
// baseline (139.856 us; speedup 1.0000x reference)
//
#include <hip/hip_runtime.h>
#include <math.h>

// Problem dims: UNITS=512, MEM=16384, BATCH=64
// d_out offsets (floats): h, c, read, m, c_wu, c_wlu, c_wr
#define OUT_H    0
#define OUT_C    32768
#define OUT_READ 65536
#define OUT_M    98304
#define OUT_CWU  8486912
#define OUT_CWLU 9535488
#define OUT_CWR  10584064

// Scratch inside OUT_M region (8.4M floats), consumed before k_update
// overwrites m: preact 4*294912 floats; then read-partials 4M floats.
// ws offsets (floats) — total 98432 floats = 385 KB
#define WS_NKEY  0          // 512*64 normalized key^T (K-major)
#define WS_PMIN  32768      // 512*64 partial min values
#define WS_PIDX  65536      // 512*64 partial min indices (int)
#define WS_MINF  98304      // 64 final min
#define WS_IDXF  98368      // 64 final argmin (int)

__device__ __forceinline__ float hsig(float x) {
    return fminf(fmaxf(0.2f * x + 0.5f, 0.f), 1.f);
}

// ---------------------------------------------------------------------------
// K1: preactivations. Virtual col space 4608 = [x:2048 | hk:2048 | r_i:512]
// grid 288 = 72 col-tiles(64) x 4 K-quarters(128). Block 256, thread 4r x 4c.
// ---------------------------------------------------------------------------
__global__ __launch_bounds__(256) void k_preact(
    const float* __restrict__ inputs, const float* __restrict__ h_tm1,
    const float* __restrict__ r_tm1, const float* __restrict__ wk,
    const float* __restrict__ rk, float* __restrict__ pre)
{
    __shared__ alignas(16) float Ast[32][68];   // [k][row 0..63 + pad]
    __shared__ alignas(16) float Bs[32][72];    // [k][col]
    const int cb = blockIdx.x % 72, kh = blockIdx.x / 72;
    const int vcol0 = cb * 64;
    const float* A; const float* W; int wstride, wcol0;
    if (vcol0 < 2048)      { A = inputs; W = wk; wstride = 2048; wcol0 = vcol0; }
    else if (vcol0 < 4096) { A = h_tm1;  W = rk; wstride = 2560; wcol0 = vcol0 - 2048; }
    else                   { A = r_tm1;  W = rk; wstride = 2560; wcol0 = 2048 + (vcol0 - 4096); }
    const int tid = threadIdx.x;
    const int rgrp = tid >> 4, cgrp = tid & 15;     // rows rgrp*4.., cols cgrp*4..
    const int srow = tid >> 2, sk = (tid & 3) * 4;  // A staging
    const int skk = tid >> 3, sc = (tid & 7) * 4;   // W staging
    float acc[4][4] = {};
    for (int t = 0; t < 4; ++t) {
        const int k0 = kh * 128 + t * 32;
        float4 a0 = *(const float4*)&A[srow * 512 + k0 + sk];
        float4 a1 = *(const float4*)&A[srow * 512 + k0 + 16 + sk];
        float4 w0 = *(const float4*)&W[(size_t)(k0 + skk) * wstride + wcol0 + sc];
        float4 w1 = *(const float4*)&W[(size_t)(k0 + skk) * wstride + wcol0 + 32 + sc];
        Ast[sk + 0][srow] = a0.x; Ast[sk + 1][srow] = a0.y;
        Ast[sk + 2][srow] = a0.z; Ast[sk + 3][srow] = a0.w;
        Ast[16 + sk + 0][srow] = a1.x; Ast[16 + sk + 1][srow] = a1.y;
        Ast[16 + sk + 2][srow] = a1.z; Ast[16 + sk + 3][srow] = a1.w;
        Bs[skk][sc + 0] = w0.x; Bs[skk][sc + 1] = w0.y;
        Bs[skk][sc + 2] = w0.z; Bs[skk][sc + 3] = w0.w;
        Bs[skk][32 + sc + 0] = w1.x; Bs[skk][32 + sc + 1] = w1.y;
        Bs[skk][32 + sc + 2] = w1.z; Bs[skk][32 + sc + 3] = w1.w;
        __syncthreads();
        #pragma unroll
        for (int kk = 0; kk < 32; ++kk) {
            float4 av = *(const float4*)&Ast[kk][rgrp * 4];
            float4 bv = *(const float4*)&Bs[kk][cgrp * 4];
            acc[0][0] += av.x * bv.x; acc[0][1] += av.x * bv.y; acc[0][2] += av.x * bv.z; acc[0][3] += av.x * bv.w;
            acc[1][0] += av.y * bv.x; acc[1][1] += av.y * bv.y; acc[1][2] += av.y * bv.z; acc[1][3] += av.y * bv.w;
            acc[2][0] += av.z * bv.x; acc[2][1] += av.z * bv.y; acc[2][2] += av.z * bv.z; acc[2][3] += av.z * bv.w;
            acc[3][0] += av.w * bv.x; acc[3][1] += av.w * bv.y; acc[3][2] += av.w * bv.z; acc[3][3] += av.w * bv.w;
        }
        __syncthreads();
    }
    float* dst = pre + (size_t)kh * 294912;
    #pragma unroll
    for (int i = 0; i < 4; ++i) {
        float4 v = { acc[i][0], acc[i][1], acc[i][2], acc[i][3] };
        *(float4*)&dst[(rgrp * 4 + i) * 4608 + vcol0 + cgrp * 4] = v;
    }
}

// ---------------------------------------------------------------------------
// K1c: gate fusion (sums the four K-quarters) -> h, c
// ---------------------------------------------------------------------------
__global__ __launch_bounds__(256) void k_gates(
    const float* __restrict__ pre, const float* __restrict__ bias,
    const float* __restrict__ c_tm1, float* __restrict__ out)
{
    int idx = blockIdx.x * 256 + threadIdx.x;   // 32768
    int b = idx >> 9, u = idx & 511;
    const float* p0 = pre + b * 4608;
    const float* p1 = pre + 294912 + b * 4608;
    const float* p2 = pre + 2 * 294912 + b * 4608;
    const float* p3 = pre + 3 * 294912 + b * 4608;
    #define SUM4(o) (p0[o] + p1[o] + p2[o] + p3[o])
    float xi = SUM4(u)        + bias[u];
    float xf = SUM4(512 + u)  + bias[512 + u];
    float xc = SUM4(1024 + u) + bias[1024 + u];
    float xo = SUM4(1536 + u) + bias[1536 + u];
    float hi = SUM4(2048 + u);
    float hf = SUM4(2560 + u);
    float hc = SUM4(3072 + u);
    float ho = SUM4(3584 + u);
    float ri = SUM4(4096 + u);
    #undef SUM4
    float ig = hsig(xi + hi + ri);
    float fg = hsig(xf + hf);
    float cc = fg * c_tm1[idx] + ig * tanhf(xc + hc);
    float og = hsig(xo + ho);
    float hh = og * tanhf(cc);
    out[OUT_H + idx] = hh;
    out[OUT_C + idx] = cc;
}

// ---------------------------------------------------------------------------
// K1b: n_key^T (K-major, 512 x 64): per-batch L2 normalization of h
// ---------------------------------------------------------------------------
__global__ __launch_bounds__(256) void k_nkey(
    const float* __restrict__ h, float* __restrict__ nkeyT)
{
    int b = blockIdx.x, t = threadIdx.x;
    float v0 = h[b * 512 + t];
    float v1 = h[b * 512 + 256 + t];
    float ss = v0 * v0 + v1 * v1;
    __shared__ float red[4];
    for (int m = 1; m < 64; m <<= 1) ss += __shfl_xor(ss, m);
    if ((t & 63) == 0) red[t >> 6] = ss;
    __syncthreads();
    float tot = red[0] + red[1] + red[2] + red[3];
    float rn = rsqrtf(fmaxf(tot, 1e-12f));
    nkeyT[t * 64 + b]         = v0 * rn;
    nkeyT[(256 + t) * 64 + b] = v1 * rn;
}

// ---------------------------------------------------------------------------
// K2: cos GEMM 32 rows/block (grid 512, 2 blocks/CU), thread 4r x 2c.
// A transposed in LDS [k][row]; B staged as flat linear copy (conflict-free).
// Fused: row-norm, softmax over batch, c_ww/c_wu, column min/argmin partials.
// ---------------------------------------------------------------------------
__global__ __launch_bounds__(256) void k_cos(
    const float* __restrict__ m_tm1, const float* __restrict__ nkeyT,
    const float* __restrict__ cwr_tm1, const float* __restrict__ cwlu_tm1,
    const float* __restrict__ cwu_tm1, const float* __restrict__ wgp,
    float* out, float* __restrict__ pmin, int* __restrict__ pidx)
{
    __shared__ alignas(16) float Ast[32][36];   // [k][row 0..31 + pad]
    __shared__ alignas(16) float Bst[2048];     // flat copy of nkeyT k-slab [32][64]
    __shared__ float rn[32];
    __shared__ alignas(16) float pmv[8][64];
    __shared__ alignas(16) int   pmi[8][64];
    const int row0 = blockIdx.x * 32;
    const int tid = threadIdx.x;
    const int rgrp = tid >> 5;                      // 0..7, rows rgrp*4..
    const int cgrp = tid & 31;                      // cols cgrp*2..
    const int srow = tid >> 3, sk = (tid & 7) * 4;  // A staging: row, k-slot
    float acc[4][2] = {};
    float ssp = 0.f;
    for (int t = 0; t < 16; ++t) {
        const int k0 = t * 32;
        float4 a0 = *(const float4*)&m_tm1[(size_t)(row0 + srow) * 512 + k0 + sk];
        float4 b0v = *(const float4*)&nkeyT[k0 * 64 + tid * 8];
        float4 b1v = *(const float4*)&nkeyT[k0 * 64 + tid * 8 + 4];
        ssp += a0.x * a0.x + a0.y * a0.y + a0.z * a0.z + a0.w * a0.w;
        Ast[sk + 0][srow] = a0.x; Ast[sk + 1][srow] = a0.y;
        Ast[sk + 2][srow] = a0.z; Ast[sk + 3][srow] = a0.w;
        *(float4*)&Bst[tid * 8]     = b0v;
        *(float4*)&Bst[tid * 8 + 4] = b1v;
        __syncthreads();
        #pragma unroll
        for (int kk = 0; kk < 32; ++kk) {
            float4 av = *(const float4*)&Ast[kk][rgrp * 4];
            float2 bv = *(const float2*)&Bst[kk * 64 + cgrp * 2];
            acc[0][0] += av.x * bv.x; acc[0][1] += av.x * bv.y;
            acc[1][0] += av.y * bv.x; acc[1][1] += av.y * bv.y;
            acc[2][0] += av.z * bv.x; acc[2][1] += av.z * bv.y;
            acc[3][0] += av.w * bv.x; acc[3][1] += av.w * bv.y;
        }
        __syncthreads();
    }
    // row sumsq: reduce across the 8 staging k-slots (tid&7 lanes per row)
    ssp += __shfl_xor(ssp, 1);
    ssp += __shfl_xor(ssp, 2);
    ssp += __shfl_xor(ssp, 4);
    if ((tid & 7) == 0) rn[srow] = ssp;
    __syncthreads();

    const float wg = 1.f / (1.f + expf(-wgp[0]));
    float p[4][2];
    #pragma unroll
    for (int i = 0; i < 4; ++i) {
        float rsq = rsqrtf(fmaxf(rn[rgrp * 4 + i], 1e-12f));
        float c0 = acc[i][0] * rsq, c1 = acc[i][1] * rsq;
        // softmax over 64 cols; row's 32 threads are a contiguous 32-lane group
        float mx = fmaxf(c0, c1);
        mx = fmaxf(mx, __shfl_xor(mx, 1));
        mx = fmaxf(mx, __shfl_xor(mx, 2));
        mx = fmaxf(mx, __shfl_xor(mx, 4));
        mx = fmaxf(mx, __shfl_xor(mx, 8));
        mx = fmaxf(mx, __shfl_xor(mx, 16));
        float e0 = expf(c0 - mx), e1 = expf(c1 - mx);
        float sm = e0 + e1;
        sm += __shfl_xor(sm, 1);
        sm += __shfl_xor(sm, 2);
        sm += __shfl_xor(sm, 4);
        sm += __shfl_xor(sm, 8);
        sm += __shfl_xor(sm, 16);
        float inv = 1.f / sm;
        p[i][0] = e0 * inv; p[i][1] = e1 * inv;
    }
    const int colbase = cgrp * 2;
    float bmv[2] = { INFINITY, INFINITY };
    int bmi[2] = { 0, 0 };
    #pragma unroll
    for (int i = 0; i < 4; ++i) {
        int grow = row0 + rgrp * 4 + i;
        int g = grow * 64 + colbase;
        float2 pr = { p[i][0], p[i][1] };
        *(float2*)&out[OUT_CWR + g] = pr;
        float2 wr = *(const float2*)&cwr_tm1[g];
        float2 wl = *(const float2*)&cwlu_tm1[g];
        float2 wu = *(const float2*)&cwu_tm1[g];
        float2 cwu;
        cwu.x = 0.95f * wu.x + pr.x + (wg * wr.x + (1.f - wg) + wl.x);
        cwu.y = 0.95f * wu.y + pr.y + (wg * wr.y + (1.f - wg) + wl.y);
        *(float2*)&out[OUT_CWU + g] = cwu;
        if (cwu.x < bmv[0]) { bmv[0] = cwu.x; bmi[0] = grow; }
        if (cwu.y < bmv[1]) { bmv[1] = cwu.y; bmi[1] = grow; }
    }
    pmv[rgrp][colbase] = bmv[0];     pmi[rgrp][colbase] = bmi[0];
    pmv[rgrp][colbase + 1] = bmv[1]; pmi[rgrp][colbase + 1] = bmi[1];
    __syncthreads();
    if (tid < 64) {
        float bv = INFINITY; int bi = 0x7fffffff;
        #pragma unroll
        for (int rg = 0; rg < 8; ++rg) {
            float v = pmv[rg][tid];
            if (v < bv) { bv = v; bi = pmi[rg][tid]; }
        }
        pmin[blockIdx.x * 64 + tid] = bv;
        pidx[blockIdx.x * 64 + tid] = bi;
    }
}

// ---------------------------------------------------------------------------
// K3: final min/argmin reduce over 512 partials (first-occurrence semantics)
// ---------------------------------------------------------------------------
__global__ __launch_bounds__(256) void k_minfinal(
    const float* __restrict__ pmin, const int* __restrict__ pidx,
    float* __restrict__ minf, int* __restrict__ idxf)
{
    __shared__ float fv[4][64];
    __shared__ int   fi[4][64];
    const int part = threadIdx.x >> 6, col = threadIdx.x & 63;
    float bv = INFINITY; int bi = 0x7fffffff;
    for (int q = 0; q < 128; ++q) {
        int pp = part * 128 + q;
        float v = pmin[pp * 64 + col];
        int   i = pidx[pp * 64 + col];
        if (v < bv || (v == bv && i < bi)) { bv = v; bi = i; }
    }
    fv[part][col] = bv; fi[part][col] = bi;
    __syncthreads();
    if (threadIdx.x < 64) {
        float v = fv[0][threadIdx.x]; int i = fi[0][threadIdx.x];
        #pragma unroll
        for (int q = 1; q < 4; ++q) {
            float v2 = fv[q][threadIdx.x]; int i2 = fi[q][threadIdx.x];
            if (v2 < v || (v2 == v && i2 < i)) { v = v2; i = i2; }
        }
        minf[threadIdx.x] = v; idxf[threadIdx.x] = i;
    }
}

// ---------------------------------------------------------------------------
// K5a: read partials. read = c_wr^T @ m_tm1, split-K over 128 row-blocks(128)
// x 8 u-splits(64). Both operands staged in LDS; no atomics — partials to
// part[rs*32768 + b*512 + u] (16 MB scratch in OUT_M region).
// ---------------------------------------------------------------------------
__global__ __launch_bounds__(256) void k_read_part(
    const float* __restrict__ m_tm1, const float* __restrict__ cwr,
    float* __restrict__ part)
{
    __shared__ alignas(16) float Ms[64][64];
    __shared__ alignas(16) float Ws[64][64];
    const int rs = blockIdx.x >> 3, us = blockIdx.x & 7;
    const int row0 = rs * 128, u0 = us * 64;
    const int tid = threadIdx.x;
    const int bg = tid >> 5, ug = tid & 31;   // b0 = bg*8, u = u0+ug*2
    const int b0 = bg * 8;
    float2 acc[8] = {};
    for (int ch = 0; ch < 2; ++ch) {
        const int r0 = row0 + ch * 64;
        #pragma unroll
        for (int rr = 0; rr < 4; ++rr) {
            int row = rr * 16 + (tid >> 4);
            int c = (tid & 15) * 4;
            *(float4*)&Ms[row][c] = *(const float4*)&m_tm1[(size_t)(r0 + row) * 512 + u0 + c];
        }
        #pragma unroll
        for (int q = 0; q < 4; ++q) {
            int idx = q * 1024 + tid * 4;
            *(float4*)&Ws[idx >> 6][idx & 63] = *(const float4*)&cwr[r0 * 64 + idx];
        }
        __syncthreads();
        for (int r = 0; r < 64; ++r) {
            float4 w1 = *(const float4*)&Ws[r][b0];
            float4 w2 = *(const float4*)&Ws[r][b0 + 4];
            float2 mv = *(const float2*)&Ms[r][ug * 2];
            acc[0].x += w1.x * mv.x; acc[0].y += w1.x * mv.y;
            acc[1].x += w1.y * mv.x; acc[1].y += w1.y * mv.y;
            acc[2].x += w1.z * mv.x; acc[2].y += w1.z * mv.y;
            acc[3].x += w1.w * mv.x; acc[3].y += w1.w * mv.y;
            acc[4].x += w2.x * mv.x; acc[4].y += w2.x * mv.y;
            acc[5].x += w2.y * mv.x; acc[5].y += w2.y * mv.y;
            acc[6].x += w2.z * mv.x; acc[6].y += w2.z * mv.y;
            acc[7].x += w2.w * mv.x; acc[7].y += w2.w * mv.y;
        }
        __syncthreads();
    }
    #pragma unroll
    for (int bb = 0; bb < 8; ++bb) {
        *(float2*)&part[(size_t)rs * 32768 + (b0 + bb) * 512 + u0 + ug * 2] = acc[bb];
    }
}

// ---------------------------------------------------------------------------
// K5b: read final reduce over the 128 partials (deterministic order).
// ---------------------------------------------------------------------------
__global__ __launch_bounds__(256) void k_read_final(
    const float* __restrict__ part, float* __restrict__ readout)
{
    int gid = blockIdx.x * 256 + threadIdx.x;  // 32768
    float s = 0.f;
    #pragma unroll 8
    for (int rs = 0; rs < 128; ++rs) s += part[(size_t)rs * 32768 + gid];
    readout[gid] = s;
}

// ---------------------------------------------------------------------------
// K4: c_wlu compare + keep mask + m = m_tm1*keep + c_ww @ h (K=64)
// grid 1024 = 256 row-blocks(64) x 4 u-splits(128). Thread 8r x 4u.
// h slice staged in LDS; inner loop LDS-only.
// ---------------------------------------------------------------------------
__global__ __launch_bounds__(256) void k_update(
    const float* __restrict__ m_tm1, const float* __restrict__ cwr_tm1,
    const float* __restrict__ cwlu_tm1, const float* __restrict__ wgp,
    const float* __restrict__ minf, const int* __restrict__ idxf,
    float* out)
{
    __shared__ alignas(16) float Wst[64][68];   // c_ww transposed [b][r]
    __shared__ alignas(16) float Hs[64][128];   // h slice [b][u-128]
    __shared__ float keepf[64];
    __shared__ float minS[64];
    __shared__ int   idxS[64];
    const int rb = blockIdx.x >> 2, us = blockIdx.x & 3;
    const int row0 = rb * 64, u0 = us * 128;
    const int tid = threadIdx.x;
    const int rgrp = tid >> 5, cgrp = tid & 31;   // rows rgrp*8.., u = u0+cgrp*4
    if (tid < 64) { idxS[tid] = idxf[tid]; minS[tid] = minf[tid]; }
    __syncthreads();
    const float wg = 1.f / (1.f + expf(-wgp[0]));
    #pragma unroll
    for (int q = 0; q < 4; ++q) {
        int idx = q * 1024 + tid * 4;
        int r = idx >> 6, b = idx & 63;
        int g = (row0 + r) * 64 + b;
        float4 wr = *(const float4*)&cwr_tm1[g];
        float4 wl = *(const float4*)&cwlu_tm1[g];
        Wst[b + 0][r] = wg * wr.x + (1.f - wg) + wl.x;
        Wst[b + 1][r] = wg * wr.y + (1.f - wg) + wl.y;
        Wst[b + 2][r] = wg * wr.z + (1.f - wg) + wl.z;
        Wst[b + 3][r] = wg * wr.w + (1.f - wg) + wl.w;
    }
    #pragma unroll
    for (int q = 0; q < 8; ++q) {
        int idx = q * 1024 + tid * 4;
        int b = idx >> 7, c = idx & 127;
        *(float4*)&Hs[b][c] = *(const float4*)&out[OUT_H + b * 512 + u0 + c];
    }
    if (tid < 64) {
        int gr = row0 + tid;
        float f = 1.f;
        #pragma unroll
        for (int b = 0; b < 64; ++b) if (idxS[b] == gr) f = 0.f;
        keepf[tid] = f;
    }
    __syncthreads();
    if (us == 0) {
        #pragma unroll
        for (int q = 0; q < 4; ++q) {
            int idx = q * 1024 + tid * 4;
            int r = idx >> 6, b = idx & 63;
            int g = (row0 + r) * 64 + b;
            float4 cu = *(const float4*)&out[OUT_CWU + g];
            float4 res;
            res.x = (cu.x <= minS[b + 0]) ? 1.f : 0.f;
            res.y = (cu.y <= minS[b + 1]) ? 1.f : 0.f;
            res.z = (cu.z <= minS[b + 2]) ? 1.f : 0.f;
            res.w = (cu.w <= minS[b + 3]) ? 1.f : 0.f;
            *(float4*)&out[OUT_CWLU + g] = res;
        }
    }
    float4 acc[8];
    #pragma unroll
    for (int i = 0; i < 8; ++i) {
        int row = rgrp * 8 + i;
        float kf = keepf[row];
        float4 mv = *(const float4*)&m_tm1[(size_t)(row0 + row) * 512 + u0 + cgrp * 4];
        acc[i].x = mv.x * kf; acc[i].y = mv.y * kf; acc[i].z = mv.z * kf; acc[i].w = mv.w * kf;
    }
    for (int b = 0; b < 64; ++b) {
        float4 w1 = *(const float4*)&Wst[b][rgrp * 8];
        float4 w2 = *(const float4*)&Wst[b][rgrp * 8 + 4];
        float4 hv = *(const float4*)&Hs[b][cgrp * 4];
        acc[0].x += w1.x * hv.x; acc[0].y += w1.x * hv.y; acc[0].z += w1.x * hv.z; acc[0].w += w1.x * hv.w;
        acc[1].x += w1.y * hv.x; acc[1].y += w1.y * hv.y; acc[1].z += w1.y * hv.z; acc[1].w += w1.y * hv.w;
        acc[2].x += w1.z * hv.x; acc[2].y += w1.z * hv.y; acc[2].z += w1.z * hv.z; acc[2].w += w1.z * hv.w;
        acc[3].x += w1.w * hv.x; acc[3].y += w1.w * hv.y; acc[3].z += w1.w * hv.z; acc[3].w += w1.w * hv.w;
        acc[4].x += w2.x * hv.x; acc[4].y += w2.x * hv.y; acc[4].z += w2.x * hv.z; acc[4].w += w2.x * hv.w;
        acc[5].x += w2.y * hv.x; acc[5].y += w2.y * hv.y; acc[5].z += w2.y * hv.z; acc[5].w += w2.y * hv.w;
        acc[6].x += w2.z * hv.x; acc[6].y += w2.z * hv.y; acc[6].z += w2.z * hv.z; acc[6].w += w2.z * hv.w;
        acc[7].x += w2.w * hv.x; acc[7].y += w2.w * hv.y; acc[7].z += w2.w * hv.z; acc[7].w += w2.w * hv.w;
    }
    #pragma unroll
    for (int i = 0; i < 8; ++i) {
        int row = rgrp * 8 + i;
        *(float4*)&out[OUT_M + (size_t)(row0 + row) * 512 + u0 + cgrp * 4] = acc[i];
    }
}

extern "C" void kernel_launch(void* const* d_in, const int* in_sizes, int n_in,
                              void* d_out, int out_size, void* d_ws, size_t ws_size,
                              hipStream_t stream)
{
    const float* inputs    = (const float*)d_in[0];
    const float* h_tm1     = (const float*)d_in[1];
    const float* c_tm1     = (const float*)d_in[2];
    const float* r_tm1     = (const float*)d_in[3];
    const float* m_tm1     = (const float*)d_in[4];
    const float* c_wu_tm1  = (const float*)d_in[5];
    const float* c_wlu_tm1 = (const float*)d_in[6];
    const float* c_wr_tm1  = (const float*)d_in[7];
    const float* wk        = (const float*)d_in[8];
    const float* rk        = (const float*)d_in[9];
    const float* bias      = (const float*)d_in[10];
    const float* wgate     = (const float*)d_in[11];
    float* out = (float*)d_out;
    float* ws  = (float*)d_ws;
    float* pre   = out + OUT_M;   // scratch in OUT_M region; consumed by k_gates
    float* rpart = out + OUT_M;   // reused after gates: read partials (4M floats)

    k_preact<<<288, 256, 0, stream>>>(inputs, h_tm1, r_tm1, wk, rk, pre);
    k_gates<<<128, 256, 0, stream>>>(pre, bias, c_tm1, out);
    k_nkey<<<64, 256, 0, stream>>>(out + OUT_H, ws + WS_NKEY);
    k_cos<<<512, 256, 0, stream>>>(m_tm1, ws + WS_NKEY, c_wr_tm1, c_wlu_tm1,
                                   c_wu_tm1, wgate, out, ws + WS_PMIN,
                                   (int*)(ws + WS_PIDX));
    k_minfinal<<<1, 256, 0, stream>>>(ws + WS_PMIN, (const int*)(ws + WS_PIDX),
                                      ws + WS_MINF, (int*)(ws + WS_IDXF));
    k_read_part<<<1024, 256, 0, stream>>>(m_tm1, out + OUT_CWR, rpart);
    k_read_final<<<128, 256, 0, stream>>>(rpart, out + OUT_READ);
    k_update<<<1024, 256, 0, stream>>>(m_tm1, c_wr_tm1, c_wlu_tm1, wgate,
                                       ws + WS_MINF, (const int*)(ws + WS_IDXF), out);
}

// Round 7
// 97.694 us; speedup vs baseline: 1.4316x; 1.4316x over previous
//
#include <hip/hip_runtime.h>
#include <math.h>

// Problem dims: UNITS=512, MEM=16384, BATCH=64
// d_out offsets (floats): h, c, read, m, c_wu, c_wlu, c_wr
#define OUT_H    0
#define OUT_C    32768
#define OUT_READ 65536
#define OUT_M    98304
#define OUT_CWU  8486912
#define OUT_CWLU 9535488
#define OUT_CWR  10584064

// Scratch inside OUT_M region (8.4M floats), consumed before k_update
// overwrites m: preact 2*294912 floats; then read-partials 4M floats.
// ws offsets (floats) — total 49280 floats = 193 KB
#define WS_NKF   0          // 512*64 bf16 B-fragments (32768 ushort = 16384 floats)
#define WS_PMIN  16384      // 256*64 partial min values
#define WS_PIDX  32768      // 256*64 partial min indices (int)
#define WS_MINF  49152      // 64 final min
#define WS_IDXF  49216      // 64 final argmin (int)

typedef short bf16x8 __attribute__((ext_vector_type(8)));
typedef float f32x4  __attribute__((ext_vector_type(4)));

__device__ __forceinline__ float hsig(float x) {
    return fminf(fmaxf(0.2f * x + 0.5f, 0.f), 1.f);
}
__device__ __forceinline__ unsigned short f2bf(float x) {
    unsigned u = __float_as_uint(x);
    return (unsigned short)((u + 0x7fffu + ((u >> 16) & 1u)) >> 16);
}

// ---------------------------------------------------------------------------
// K1: preactivations. Virtual col space 4608 = [x:2048 | hk:2048 | r_i:512]
// grid 144 = 72 col-tiles(64) x 2 K-halves(256). Block 256, thread 4r x 4c.
// ---------------------------------------------------------------------------
__global__ __launch_bounds__(256) void k_preact(
    const float* __restrict__ inputs, const float* __restrict__ h_tm1,
    const float* __restrict__ r_tm1, const float* __restrict__ wk,
    const float* __restrict__ rk, float* __restrict__ pre)
{
    __shared__ alignas(16) float Ast[32][68];   // [k][row 0..63 + pad]
    __shared__ alignas(16) float Bs[32][72];    // [k][col]
    const int cb = blockIdx.x % 72, kh = blockIdx.x / 72;
    const int vcol0 = cb * 64;
    const float* A; const float* W; int wstride, wcol0;
    if (vcol0 < 2048)      { A = inputs; W = wk; wstride = 2048; wcol0 = vcol0; }
    else if (vcol0 < 4096) { A = h_tm1;  W = rk; wstride = 2560; wcol0 = vcol0 - 2048; }
    else                   { A = r_tm1;  W = rk; wstride = 2560; wcol0 = 2048 + (vcol0 - 4096); }
    const int tid = threadIdx.x;
    const int rgrp = tid >> 4, cgrp = tid & 15;
    const int srow = tid >> 2, sk = (tid & 3) * 4;
    const int skk = tid >> 3, sc = (tid & 7) * 4;
    float acc[4][4] = {};
    for (int t = 0; t < 8; ++t) {
        const int k0 = kh * 256 + t * 32;
        float4 a0 = *(const float4*)&A[srow * 512 + k0 + sk];
        float4 a1 = *(const float4*)&A[srow * 512 + k0 + 16 + sk];
        float4 w0 = *(const float4*)&W[(size_t)(k0 + skk) * wstride + wcol0 + sc];
        float4 w1 = *(const float4*)&W[(size_t)(k0 + skk) * wstride + wcol0 + 32 + sc];
        Ast[sk + 0][srow] = a0.x; Ast[sk + 1][srow] = a0.y;
        Ast[sk + 2][srow] = a0.z; Ast[sk + 3][srow] = a0.w;
        Ast[16 + sk + 0][srow] = a1.x; Ast[16 + sk + 1][srow] = a1.y;
        Ast[16 + sk + 2][srow] = a1.z; Ast[16 + sk + 3][srow] = a1.w;
        Bs[skk][sc + 0] = w0.x; Bs[skk][sc + 1] = w0.y;
        Bs[skk][sc + 2] = w0.z; Bs[skk][sc + 3] = w0.w;
        Bs[skk][32 + sc + 0] = w1.x; Bs[skk][32 + sc + 1] = w1.y;
        Bs[skk][32 + sc + 2] = w1.z; Bs[skk][32 + sc + 3] = w1.w;
        __syncthreads();
        #pragma unroll
        for (int kk = 0; kk < 32; ++kk) {
            float4 av = *(const float4*)&Ast[kk][rgrp * 4];
            float4 bv = *(const float4*)&Bs[kk][cgrp * 4];
            acc[0][0] += av.x * bv.x; acc[0][1] += av.x * bv.y; acc[0][2] += av.x * bv.z; acc[0][3] += av.x * bv.w;
            acc[1][0] += av.y * bv.x; acc[1][1] += av.y * bv.y; acc[1][2] += av.y * bv.z; acc[1][3] += av.y * bv.w;
            acc[2][0] += av.z * bv.x; acc[2][1] += av.z * bv.y; acc[2][2] += av.z * bv.z; acc[2][3] += av.z * bv.w;
            acc[3][0] += av.w * bv.x; acc[3][1] += av.w * bv.y; acc[3][2] += av.w * bv.z; acc[3][3] += av.w * bv.w;
        }
        __syncthreads();
    }
    float* dst = pre + (size_t)kh * 294912;
    #pragma unroll
    for (int i = 0; i < 4; ++i) {
        float4 v = { acc[i][0], acc[i][1], acc[i][2], acc[i][3] };
        *(float4*)&dst[(rgrp * 4 + i) * 4608 + vcol0 + cgrp * 4] = v;
    }
}

// ---------------------------------------------------------------------------
// K1c: gate fusion (sums the two K-halves) -> h, c
// ---------------------------------------------------------------------------
__global__ __launch_bounds__(256) void k_gates(
    const float* __restrict__ pre, const float* __restrict__ bias,
    const float* __restrict__ c_tm1, float* __restrict__ out)
{
    int idx = blockIdx.x * 256 + threadIdx.x;   // 32768
    int b = idx >> 9, u = idx & 511;
    const float* p0 = pre + b * 4608;
    const float* p1 = pre + 294912 + b * 4608;
    float xi = p0[u]        + p1[u]        + bias[u];
    float xf = p0[512 + u]  + p1[512 + u]  + bias[512 + u];
    float xc = p0[1024 + u] + p1[1024 + u] + bias[1024 + u];
    float xo = p0[1536 + u] + p1[1536 + u] + bias[1536 + u];
    float hi = p0[2048 + u] + p1[2048 + u];
    float hf = p0[2560 + u] + p1[2560 + u];
    float hc = p0[3072 + u] + p1[3072 + u];
    float ho = p0[3584 + u] + p1[3584 + u];
    float ri = p0[4096 + u] + p1[4096 + u];
    float ig = hsig(xi + hi + ri);
    float fg = hsig(xf + hf);
    float cc = fg * c_tm1[idx] + ig * tanhf(xc + hc);
    float og = hsig(xo + ho);
    float hh = og * tanhf(cc);
    out[OUT_H + idx] = hh;
    out[OUT_C + idx] = cc;
}

// ---------------------------------------------------------------------------
// K1b: n_key normalization + pack into bf16 B-fragments for MFMA.
// Frag layout for B (K=32 x N=16 tile, step s, n-tile n): lane l holds
// B[k=32s+8*(l>>4)+e][col=n*16+(l&15)] at nkf[((s*4+n)*64+l)*8 + e].
// ---------------------------------------------------------------------------
__global__ __launch_bounds__(256) void k_nkey(
    const float* __restrict__ h, unsigned short* __restrict__ nkf)
{
    int b = blockIdx.x, t = threadIdx.x;
    float v0 = h[b * 512 + t];
    float v1 = h[b * 512 + 256 + t];
    float ss = v0 * v0 + v1 * v1;
    __shared__ float red[4];
    for (int m = 1; m < 64; m <<= 1) ss += __shfl_xor(ss, m);
    if ((t & 63) == 0) red[t >> 6] = ss;
    __syncthreads();
    float tot = red[0] + red[1] + red[2] + red[3];
    float rn = rsqrtf(fmaxf(tot, 1e-12f));
    #pragma unroll
    for (int q = 0; q < 2; ++q) {
        int u = t + q * 256;
        float v = (q ? v1 : v0) * rn;
        int s = u >> 5, n = b >> 4;
        int lane = (b & 15) + 16 * ((u & 31) >> 3);
        int e = u & 7;
        nkf[(((s * 4 + n) * 64 + lane) << 3) + e] = f2bf(v);
    }
}

// ---------------------------------------------------------------------------
// K2: cos GEMM via MFMA bf16 (f32 accum). 64 rows/block, grid 256.
// A (m rows) staged f32->bf16 into LDS in frag-linear layout (XOR-swizzled),
// two K-halves (32KB). B frags read from global (L2-hot, packed by k_nkey).
// Row sumsq computed f32 during staging. Epilogue: norm, softmax over batch,
// c_wr/c_wu, per-block column min/argmin partials. Wave w owns rows w*16..+15.
// ---------------------------------------------------------------------------
__global__ __launch_bounds__(256) void k_cos(
    const float* __restrict__ m_tm1, const unsigned short* __restrict__ nkf,
    const float* __restrict__ cwr_tm1, const float* __restrict__ cwlu_tm1,
    const float* __restrict__ cwu_tm1, const float* __restrict__ wgp,
    float* out, float* __restrict__ pmin, int* __restrict__ pidx)
{
    __shared__ alignas(16) unsigned short Af[2048 * 8];   // 32 KB: [s_l][rt][lane][8]
    __shared__ float rn0[64], rn1[64];
    __shared__ float pmv[4][64];
    __shared__ int   pmi[4][64];
    const int row0 = blockIdx.x * 64;
    const int tid = threadIdx.x;
    const int w = tid >> 6, lane = tid & 63;
    f32x4 acc[4] = {};

    for (int half = 0; half < 2; ++half) {
        // --- stage 64 rows x 256 k (this half) into frag layout ---
        for (int i = 0; i < 8; ++i) {
            int r = i * 8 + (tid >> 5);          // 0..63
            int koct = tid & 31;                 // k-octet within half
            const float* src = &m_tm1[(size_t)(row0 + r) * 512 + half * 256 + koct * 8];
            float4 x0 = *(const float4*)src;
            float4 x1 = *(const float4*)&src[4];
            float ssi = x0.x*x0.x + x0.y*x0.y + x0.z*x0.z + x0.w*x0.w
                      + x1.x*x1.x + x1.y*x1.y + x1.z*x1.z + x1.w*x1.w;
            ssi += __shfl_xor(ssi, 1); ssi += __shfl_xor(ssi, 2);
            ssi += __shfl_xor(ssi, 4); ssi += __shfl_xor(ssi, 8);
            ssi += __shfl_xor(ssi, 16);
            if ((tid & 31) == 0) { if (half) rn1[r] = ssi; else rn0[r] = ssi; }
            int s_l = koct >> 2, rt = r >> 4;
            int ln = ((r & 15) + ((koct & 3) << 4)) ^ (s_l & 7);   // XOR swizzle
            union { unsigned short hx[8]; uint4 v; } pk;
            pk.hx[0] = f2bf(x0.x); pk.hx[1] = f2bf(x0.y);
            pk.hx[2] = f2bf(x0.z); pk.hx[3] = f2bf(x0.w);
            pk.hx[4] = f2bf(x1.x); pk.hx[5] = f2bf(x1.y);
            pk.hx[6] = f2bf(x1.z); pk.hx[7] = f2bf(x1.w);
            *(uint4*)&Af[((s_l * 4 + rt) * 64 + ln) << 3] = pk.v;
        }
        __syncthreads();
        // --- MFMA K-loop: 8 steps this half; wave w takes row-tile rt=w ---
        for (int s_l = 0; s_l < 8; ++s_l) {
            int lnx = lane ^ (s_l & 7);
            bf16x8 af = *(const bf16x8*)&Af[((s_l * 4 + w) * 64 + lnx) << 3];
            int s = half * 8 + s_l;
            #pragma unroll
            for (int n = 0; n < 4; ++n) {
                bf16x8 bf = *(const bf16x8*)&nkf[((s * 4 + n) * 64 + lane) << 3];
                acc[n] = __builtin_amdgcn_mfma_f32_16x16x32_bf16(af, bf, acc[n], 0, 0, 0);
            }
        }
        __syncthreads();
    }

    // --- epilogue ---
    const float wg = 1.f / (1.f + expf(-wgp[0]));
    const int lhi = lane >> 4, llo = lane & 15;
    float rsq[4];
    #pragma unroll
    for (int reg = 0; reg < 4; ++reg) {
        int rl = w * 16 + lhi * 4 + reg;
        rsq[reg] = rsqrtf(fmaxf(rn0[rl] + rn1[rl], 1e-12f));
    }
    float bmv[4] = { INFINITY, INFINITY, INFINITY, INFINITY };
    int   bmi[4] = { 0x7fffffff, 0x7fffffff, 0x7fffffff, 0x7fffffff };
    #pragma unroll
    for (int reg = 0; reg < 4; ++reg) {
        int r = row0 + w * 16 + lhi * 4 + reg;
        float c0 = acc[0][reg] * rsq[reg];
        float c1 = acc[1][reg] * rsq[reg];
        float c2 = acc[2][reg] * rsq[reg];
        float c3 = acc[3][reg] * rsq[reg];
        float mx = fmaxf(fmaxf(c0, c1), fmaxf(c2, c3));
        mx = fmaxf(mx, __shfl_xor(mx, 1));
        mx = fmaxf(mx, __shfl_xor(mx, 2));
        mx = fmaxf(mx, __shfl_xor(mx, 4));
        mx = fmaxf(mx, __shfl_xor(mx, 8));
        float e0 = expf(c0 - mx), e1 = expf(c1 - mx);
        float e2 = expf(c2 - mx), e3 = expf(c3 - mx);
        float sm = e0 + e1 + e2 + e3;
        sm += __shfl_xor(sm, 1);
        sm += __shfl_xor(sm, 2);
        sm += __shfl_xor(sm, 4);
        sm += __shfl_xor(sm, 8);
        float inv = 1.f / sm;
        float pv[4] = { e0 * inv, e1 * inv, e2 * inv, e3 * inv };
        #pragma unroll
        for (int n = 0; n < 4; ++n) {
            int g = r * 64 + n * 16 + llo;
            float p = pv[n];
            out[OUT_CWR + g] = p;
            float wr = cwr_tm1[g], wl = cwlu_tm1[g], wu = cwu_tm1[g];
            float cww = wg * wr + (1.f - wg) + wl;
            float cwu = 0.95f * wu + p + cww;
            out[OUT_CWU + g] = cwu;
            if (cwu < bmv[n]) { bmv[n] = cwu; bmi[n] = r; }
        }
    }
    // reduce across the 4 row-groups (lanes xor 16, 32) per n-tile
    #pragma unroll
    for (int n = 0; n < 4; ++n) {
        #pragma unroll
        for (int mk = 16; mk <= 32; mk <<= 1) {
            float ov = __shfl_xor(bmv[n], mk);
            int   oi = __shfl_xor(bmi[n], mk);
            if (ov < bmv[n] || (ov == bmv[n] && oi < bmi[n])) { bmv[n] = ov; bmi[n] = oi; }
        }
    }
    if (lhi == 0) {
        #pragma unroll
        for (int n = 0; n < 4; ++n) { pmv[w][n * 16 + llo] = bmv[n]; pmi[w][n * 16 + llo] = bmi[n]; }
    }
    __syncthreads();
    if (tid < 64) {
        float bv = pmv[0][tid]; int bi = pmi[0][tid];
        #pragma unroll
        for (int q = 1; q < 4; ++q) {
            float v = pmv[q][tid]; int i2 = pmi[q][tid];
            if (v < bv || (v == bv && i2 < bi)) { bv = v; bi = i2; }
        }
        pmin[blockIdx.x * 64 + tid] = bv;
        pidx[blockIdx.x * 64 + tid] = bi;
    }
}

// ---------------------------------------------------------------------------
// K3: final min/argmin over 256 partials; grid 64 (one block per column).
// ---------------------------------------------------------------------------
__global__ __launch_bounds__(256) void k_minfinal(
    const float* __restrict__ pmin, const int* __restrict__ pidx,
    float* __restrict__ minf, int* __restrict__ idxf)
{
    int col = blockIdx.x, t = threadIdx.x;
    float bv = pmin[t * 64 + col];
    int   bi = pidx[t * 64 + col];
    for (int mk = 1; mk < 64; mk <<= 1) {
        float ov = __shfl_xor(bv, mk);
        int   oi = __shfl_xor(bi, mk);
        if (ov < bv || (ov == bv && oi < bi)) { bv = ov; bi = oi; }
    }
    __shared__ float sv[4]; __shared__ int si[4];
    if ((t & 63) == 0) { sv[t >> 6] = bv; si[t >> 6] = bi; }
    __syncthreads();
    if (t == 0) {
        #pragma unroll
        for (int q = 1; q < 4; ++q) {
            if (sv[q] < bv || (sv[q] == bv && si[q] < bi)) { bv = sv[q]; bi = si[q]; }
        }
        minf[col] = bv; idxf[col] = bi;
    }
}

// ---------------------------------------------------------------------------
// K5a: read partials. read = c_wr^T @ m_tm1, split-K over 128 row-blocks(128)
// x 8 u-splits(64). Both operands staged in LDS; no atomics.
// ---------------------------------------------------------------------------
__global__ __launch_bounds__(256) void k_read_part(
    const float* __restrict__ m_tm1, const float* __restrict__ cwr,
    float* __restrict__ part)
{
    __shared__ alignas(16) float Ms[64][64];
    __shared__ alignas(16) float Ws[64][64];
    const int rs = blockIdx.x >> 3, us = blockIdx.x & 7;
    const int row0 = rs * 128, u0 = us * 64;
    const int tid = threadIdx.x;
    const int bg = tid >> 5, ug = tid & 31;
    const int b0 = bg * 8;
    float2 acc[8] = {};
    for (int ch = 0; ch < 2; ++ch) {
        const int r0 = row0 + ch * 64;
        #pragma unroll
        for (int rr = 0; rr < 4; ++rr) {
            int row = rr * 16 + (tid >> 4);
            int c = (tid & 15) * 4;
            *(float4*)&Ms[row][c] = *(const float4*)&m_tm1[(size_t)(r0 + row) * 512 + u0 + c];
        }
        #pragma unroll
        for (int q = 0; q < 4; ++q) {
            int idx = q * 1024 + tid * 4;
            *(float4*)&Ws[idx >> 6][idx & 63] = *(const float4*)&cwr[r0 * 64 + idx];
        }
        __syncthreads();
        for (int r = 0; r < 64; ++r) {
            float4 w1 = *(const float4*)&Ws[r][b0];
            float4 w2 = *(const float4*)&Ws[r][b0 + 4];
            float2 mv = *(const float2*)&Ms[r][ug * 2];
            acc[0].x += w1.x * mv.x; acc[0].y += w1.x * mv.y;
            acc[1].x += w1.y * mv.x; acc[1].y += w1.y * mv.y;
            acc[2].x += w1.z * mv.x; acc[2].y += w1.z * mv.y;
            acc[3].x += w1.w * mv.x; acc[3].y += w1.w * mv.y;
            acc[4].x += w2.x * mv.x; acc[4].y += w2.x * mv.y;
            acc[5].x += w2.y * mv.x; acc[5].y += w2.y * mv.y;
            acc[6].x += w2.z * mv.x; acc[6].y += w2.z * mv.y;
            acc[7].x += w2.w * mv.x; acc[7].y += w2.w * mv.y;
        }
        __syncthreads();
    }
    #pragma unroll
    for (int bb = 0; bb < 8; ++bb) {
        *(float2*)&part[(size_t)rs * 32768 + (b0 + bb) * 512 + u0 + ug * 2] = acc[bb];
    }
}

// ---------------------------------------------------------------------------
// K5b: read final reduce over the 128 partials (deterministic order).
// ---------------------------------------------------------------------------
__global__ __launch_bounds__(256) void k_read_final(
    const float* __restrict__ part, float* __restrict__ readout)
{
    int gid = blockIdx.x * 256 + threadIdx.x;  // 32768
    float s = 0.f;
    #pragma unroll 8
    for (int rs = 0; rs < 128; ++rs) s += part[(size_t)rs * 32768 + gid];
    readout[gid] = s;
}

// ---------------------------------------------------------------------------
// K4: c_wlu compare + keep mask + m = m_tm1*keep + c_ww @ h (K=64)
// grid 1024 = 256 row-blocks(64) x 4 u-splits(128). Thread 8r x 4u.
// ---------------------------------------------------------------------------
__global__ __launch_bounds__(256) void k_update(
    const float* __restrict__ m_tm1, const float* __restrict__ cwr_tm1,
    const float* __restrict__ cwlu_tm1, const float* __restrict__ wgp,
    const float* __restrict__ minf, const int* __restrict__ idxf,
    float* out)
{
    __shared__ alignas(16) float Wst[64][68];   // c_ww transposed [b][r]
    __shared__ alignas(16) float Hs[64][128];   // h slice [b][u-128]
    __shared__ float keepf[64];
    __shared__ float minS[64];
    __shared__ int   idxS[64];
    const int rb = blockIdx.x >> 2, us = blockIdx.x & 3;
    const int row0 = rb * 64, u0 = us * 128;
    const int tid = threadIdx.x;
    const int rgrp = tid >> 5, cgrp = tid & 31;
    if (tid < 64) { idxS[tid] = idxf[tid]; minS[tid] = minf[tid]; }
    __syncthreads();
    const float wg = 1.f / (1.f + expf(-wgp[0]));
    #pragma unroll
    for (int q = 0; q < 4; ++q) {
        int idx = q * 1024 + tid * 4;
        int r = idx >> 6, b = idx & 63;
        int g = (row0 + r) * 64 + b;
        float4 wr = *(const float4*)&cwr_tm1[g];
        float4 wl = *(const float4*)&cwlu_tm1[g];
        Wst[b + 0][r] = wg * wr.x + (1.f - wg) + wl.x;
        Wst[b + 1][r] = wg * wr.y + (1.f - wg) + wl.y;
        Wst[b + 2][r] = wg * wr.z + (1.f - wg) + wl.z;
        Wst[b + 3][r] = wg * wr.w + (1.f - wg) + wl.w;
    }
    #pragma unroll
    for (int q = 0; q < 8; ++q) {
        int idx = q * 1024 + tid * 4;
        int b = idx >> 7, c = idx & 127;
        *(float4*)&Hs[b][c] = *(const float4*)&out[OUT_H + b * 512 + u0 + c];
    }
    if (tid < 64) {
        int gr = row0 + tid;
        float f = 1.f;
        #pragma unroll
        for (int b = 0; b < 64; ++b) if (idxS[b] == gr) f = 0.f;
        keepf[tid] = f;
    }
    __syncthreads();
    if (us == 0) {
        #pragma unroll
        for (int q = 0; q < 4; ++q) {
            int idx = q * 1024 + tid * 4;
            int r = idx >> 6, b = idx & 63;
            int g = (row0 + r) * 64 + b;
            float4 cu = *(const float4*)&out[OUT_CWU + g];
            float4 res;
            res.x = (cu.x <= minS[b + 0]) ? 1.f : 0.f;
            res.y = (cu.y <= minS[b + 1]) ? 1.f : 0.f;
            res.z = (cu.z <= minS[b + 2]) ? 1.f : 0.f;
            res.w = (cu.w <= minS[b + 3]) ? 1.f : 0.f;
            *(float4*)&out[OUT_CWLU + g] = res;
        }
    }
    float4 acc[8];
    #pragma unroll
    for (int i = 0; i < 8; ++i) {
        int row = rgrp * 8 + i;
        float kf = keepf[row];
        float4 mv = *(const float4*)&m_tm1[(size_t)(row0 + row) * 512 + u0 + cgrp * 4];
        acc[i].x = mv.x * kf; acc[i].y = mv.y * kf; acc[i].z = mv.z * kf; acc[i].w = mv.w * kf;
    }
    for (int b = 0; b < 64; ++b) {
        float4 w1 = *(const float4*)&Wst[b][rgrp * 8];
        float4 w2 = *(const float4*)&Wst[b][rgrp * 8 + 4];
        float4 hv = *(const float4*)&Hs[b][cgrp * 4];
        acc[0].x += w1.x * hv.x; acc[0].y += w1.x * hv.y; acc[0].z += w1.x * hv.z; acc[0].w += w1.x * hv.w;
        acc[1].x += w1.y * hv.x; acc[1].y += w1.y * hv.y; acc[1].z += w1.y * hv.z; acc[1].w += w1.y * hv.w;
        acc[2].x += w1.z * hv.x; acc[2].y += w1.z * hv.y; acc[2].z += w1.z * hv.z; acc[2].w += w1.z * hv.w;
        acc[3].x += w1.w * hv.x; acc[3].y += w1.w * hv.y; acc[3].z += w1.w * hv.z; acc[3].w += w1.w * hv.w;
        acc[4].x += w2.x * hv.x; acc[4].y += w2.x * hv.y; acc[4].z += w2.x * hv.z; acc[4].w += w2.x * hv.w;
        acc[5].x += w2.y * hv.x; acc[5].y += w2.y * hv.y; acc[5].z += w2.y * hv.z; acc[5].w += w2.y * hv.w;
        acc[6].x += w2.z * hv.x; acc[6].y += w2.z * hv.y; acc[6].z += w2.z * hv.z; acc[6].w += w2.z * hv.w;
        acc[7].x += w2.w * hv.x; acc[7].y += w2.w * hv.y; acc[7].z += w2.w * hv.z; acc[7].w += w2.w * hv.w;
    }
    #pragma unroll
    for (int i = 0; i < 8; ++i) {
        int row = rgrp * 8 + i;
        *(float4*)&out[OUT_M + (size_t)(row0 + row) * 512 + u0 + cgrp * 4] = acc[i];
    }
}

extern "C" void kernel_launch(void* const* d_in, const int* in_sizes, int n_in,
                              void* d_out, int out_size, void* d_ws, size_t ws_size,
                              hipStream_t stream)
{
    const float* inputs    = (const float*)d_in[0];
    const float* h_tm1     = (const float*)d_in[1];
    const float* c_tm1     = (const float*)d_in[2];
    const float* r_tm1     = (const float*)d_in[3];
    const float* m_tm1     = (const float*)d_in[4];
    const float* c_wu_tm1  = (const float*)d_in[5];
    const float* c_wlu_tm1 = (const float*)d_in[6];
    const float* c_wr_tm1  = (const float*)d_in[7];
    const float* wk        = (const float*)d_in[8];
    const float* rk        = (const float*)d_in[9];
    const float* bias      = (const float*)d_in[10];
    const float* wgate     = (const float*)d_in[11];
    float* out = (float*)d_out;
    float* ws  = (float*)d_ws;
    float* pre   = out + OUT_M;   // scratch in OUT_M region; consumed by k_gates
    float* rpart = out + OUT_M;   // reused after gates: read partials (4M floats)
    unsigned short* nkf = (unsigned short*)(ws + WS_NKF);

    k_preact<<<144, 256, 0, stream>>>(inputs, h_tm1, r_tm1, wk, rk, pre);
    k_gates<<<128, 256, 0, stream>>>(pre, bias, c_tm1, out);
    k_nkey<<<64, 256, 0, stream>>>(out + OUT_H, nkf);
    k_cos<<<256, 256, 0, stream>>>(m_tm1, nkf, c_wr_tm1, c_wlu_tm1,
                                   c_wu_tm1, wgate, out, ws + WS_PMIN,
                                   (int*)(ws + WS_PIDX));
    k_minfinal<<<64, 256, 0, stream>>>(ws + WS_PMIN, (const int*)(ws + WS_PIDX),
                                       ws + WS_MINF, (int*)(ws + WS_IDXF));
    k_read_part<<<1024, 256, 0, stream>>>(m_tm1, out + OUT_CWR, rpart);
    k_read_final<<<128, 256, 0, stream>>>(rpart, out + OUT_READ);
    k_update<<<1024, 256, 0, stream>>>(m_tm1, c_wr_tm1, c_wlu_tm1, wgate,
                                       ws + WS_MINF, (const int*)(ws + WS_IDXF), out);
}

// Round 8
// 86.916 us; speedup vs baseline: 1.6091x; 1.1240x over previous
//
#include <hip/hip_runtime.h>
#include <math.h>

// Problem dims: UNITS=512, MEM=16384, BATCH=64
// d_out offsets (floats): h, c, read, m, c_wu, c_wlu, c_wr
#define OUT_H    0
#define OUT_C    32768
#define OUT_READ 65536
#define OUT_M    98304
#define OUT_CWU  8486912
#define OUT_CWLU 9535488
#define OUT_CWR  10584064

// Scratch inside OUT_M region (8.4M floats): preact 4*294912 floats (consumed
// by k_gates), then read-partials 4M floats (consumed by k_read_final before
// k_update overwrites m).
// ws offsets (floats) — total 65664 floats = 257 KB
#define WS_NKF   0          // 32768 ushort: normalized-key bf16 B-frags (cos)
#define WS_HBF   16384      // 32768 ushort: h bf16 B-frags (update)
#define WS_PMIN  32768      // 256*64 partial min values
#define WS_PIDX  49152      // 256*64 partial min indices (int)
#define WS_MINF  65536      // 64 final min
#define WS_IDXF  65600      // 64 final argmin (int)

typedef short bf16x8 __attribute__((ext_vector_type(8)));
typedef float f32x4  __attribute__((ext_vector_type(4)));

__device__ __forceinline__ float hsig(float x) {
    return fminf(fmaxf(0.2f * x + 0.5f, 0.f), 1.f);
}
__device__ __forceinline__ unsigned short f2bf(float x) {
    unsigned u = __float_as_uint(x);
    return (unsigned short)((u + 0x7fffu + ((u >> 16) & 1u)) >> 16);
}

// ---------------------------------------------------------------------------
// K1: preactivations. Virtual col space 4608 = [x:2048 | hk:2048 | r_i:512]
// grid 288 = 72 col-tiles(64) x 4 K-quarters(128). Block 256, thread 4r x 4c.
// ---------------------------------------------------------------------------
__global__ __launch_bounds__(256) void k_preact(
    const float* __restrict__ inputs, const float* __restrict__ h_tm1,
    const float* __restrict__ r_tm1, const float* __restrict__ wk,
    const float* __restrict__ rk, float* __restrict__ pre)
{
    __shared__ alignas(16) float Ast[32][68];   // [k][row 0..63 + pad]
    __shared__ alignas(16) float Bs[32][72];    // [k][col]
    const int cb = blockIdx.x % 72, kh = blockIdx.x / 72;
    const int vcol0 = cb * 64;
    const float* A; const float* W; int wstride, wcol0;
    if (vcol0 < 2048)      { A = inputs; W = wk; wstride = 2048; wcol0 = vcol0; }
    else if (vcol0 < 4096) { A = h_tm1;  W = rk; wstride = 2560; wcol0 = vcol0 - 2048; }
    else                   { A = r_tm1;  W = rk; wstride = 2560; wcol0 = 2048 + (vcol0 - 4096); }
    const int tid = threadIdx.x;
    const int rgrp = tid >> 4, cgrp = tid & 15;
    const int srow = tid >> 2, sk = (tid & 3) * 4;
    const int skk = tid >> 3, sc = (tid & 7) * 4;
    float acc[4][4] = {};
    for (int t = 0; t < 4; ++t) {
        const int k0 = kh * 128 + t * 32;
        float4 a0 = *(const float4*)&A[srow * 512 + k0 + sk];
        float4 a1 = *(const float4*)&A[srow * 512 + k0 + 16 + sk];
        float4 w0 = *(const float4*)&W[(size_t)(k0 + skk) * wstride + wcol0 + sc];
        float4 w1 = *(const float4*)&W[(size_t)(k0 + skk) * wstride + wcol0 + 32 + sc];
        Ast[sk + 0][srow] = a0.x; Ast[sk + 1][srow] = a0.y;
        Ast[sk + 2][srow] = a0.z; Ast[sk + 3][srow] = a0.w;
        Ast[16 + sk + 0][srow] = a1.x; Ast[16 + sk + 1][srow] = a1.y;
        Ast[16 + sk + 2][srow] = a1.z; Ast[16 + sk + 3][srow] = a1.w;
        Bs[skk][sc + 0] = w0.x; Bs[skk][sc + 1] = w0.y;
        Bs[skk][sc + 2] = w0.z; Bs[skk][sc + 3] = w0.w;
        Bs[skk][32 + sc + 0] = w1.x; Bs[skk][32 + sc + 1] = w1.y;
        Bs[skk][32 + sc + 2] = w1.z; Bs[skk][32 + sc + 3] = w1.w;
        __syncthreads();
        #pragma unroll
        for (int kk = 0; kk < 32; ++kk) {
            float4 av = *(const float4*)&Ast[kk][rgrp * 4];
            float4 bv = *(const float4*)&Bs[kk][cgrp * 4];
            acc[0][0] += av.x * bv.x; acc[0][1] += av.x * bv.y; acc[0][2] += av.x * bv.z; acc[0][3] += av.x * bv.w;
            acc[1][0] += av.y * bv.x; acc[1][1] += av.y * bv.y; acc[1][2] += av.y * bv.z; acc[1][3] += av.y * bv.w;
            acc[2][0] += av.z * bv.x; acc[2][1] += av.z * bv.y; acc[2][2] += av.z * bv.z; acc[2][3] += av.z * bv.w;
            acc[3][0] += av.w * bv.x; acc[3][1] += av.w * bv.y; acc[3][2] += av.w * bv.z; acc[3][3] += av.w * bv.w;
        }
        __syncthreads();
    }
    float* dst = pre + (size_t)kh * 294912;
    #pragma unroll
    for (int i = 0; i < 4; ++i) {
        float4 v = { acc[i][0], acc[i][1], acc[i][2], acc[i][3] };
        *(float4*)&dst[(rgrp * 4 + i) * 4608 + vcol0 + cgrp * 4] = v;
    }
}

// ---------------------------------------------------------------------------
// K1c: gate fusion (sums 4 K-quarters) -> h, c; fused L2-norm + bf16 packing:
// nkf = normalized-key B-frags (for k_cos), hbf = raw-h B-frags (for k_update).
// grid 64 (one block per batch column b), 256 threads, 2 u per thread.
// ---------------------------------------------------------------------------
__global__ __launch_bounds__(256) void k_gates(
    const float* __restrict__ pre, const float* __restrict__ bias,
    const float* __restrict__ c_tm1, float* __restrict__ out,
    unsigned short* __restrict__ nkf, unsigned short* __restrict__ hbf)
{
    int b = blockIdx.x, t = threadIdx.x;
    const float* p0 = pre + b * 4608;
    const float* p1 = pre + 294912 + b * 4608;
    const float* p2 = pre + 2 * 294912 + b * 4608;
    const float* p3 = pre + 3 * 294912 + b * 4608;
    float hh[2], cc[2];
    #pragma unroll
    for (int q = 0; q < 2; ++q) {
        int u = t + q * 256;
        #define S4(o) (p0[o] + p1[o] + p2[o] + p3[o])
        float xi = S4(u)        + bias[u];
        float xf = S4(512 + u)  + bias[512 + u];
        float xc = S4(1024 + u) + bias[1024 + u];
        float xo = S4(1536 + u) + bias[1536 + u];
        float hi = S4(2048 + u);
        float hf = S4(2560 + u);
        float hc = S4(3072 + u);
        float ho = S4(3584 + u);
        float ri = S4(4096 + u);
        #undef S4
        float ig = hsig(xi + hi + ri);
        float fg = hsig(xf + hf);
        cc[q] = fg * c_tm1[b * 512 + u] + ig * tanhf(xc + hc);
        float og = hsig(xo + ho);
        hh[q] = og * tanhf(cc[q]);
        out[OUT_H + b * 512 + u] = hh[q];
        out[OUT_C + b * 512 + u] = cc[q];
    }
    // block-wide sumsq of h[b][:]
    float ss = hh[0] * hh[0] + hh[1] * hh[1];
    __shared__ float red[4];
    for (int m = 1; m < 64; m <<= 1) ss += __shfl_xor(ss, m);
    if ((t & 63) == 0) red[t >> 6] = ss;
    __syncthreads();
    float tot = red[0] + red[1] + red[2] + red[3];
    float rn = rsqrtf(fmaxf(tot, 1e-12f));
    #pragma unroll
    for (int q = 0; q < 2; ++q) {
        int u = t + q * 256;
        // nkf: B[k=u][col=b], k-steps of 32
        int s = u >> 5, n = b >> 4;
        int lane = (b & 15) + 16 * ((u & 31) >> 3);
        int e = u & 7;
        nkf[(((s * 4 + n) * 64 + lane) << 3) + e] = f2bf(hh[q] * rn);
        // hbf: B[k=b][col=u], k-steps of 32
        int s2 = b >> 5, N = u >> 4;
        int l2 = (u & 15) + 16 * ((b & 31) >> 3);
        int e2 = b & 7;
        hbf[(((s2 * 32 + N) * 64 + l2) << 3) + e2] = f2bf(hh[q]);
    }
}

// ---------------------------------------------------------------------------
// K2: cos GEMM via MFMA bf16 (f32 accum). 64 rows/block, grid 256.
// (unchanged from round 7 — verified)
// ---------------------------------------------------------------------------
__global__ __launch_bounds__(256) void k_cos(
    const float* __restrict__ m_tm1, const unsigned short* __restrict__ nkf,
    const float* __restrict__ cwr_tm1, const float* __restrict__ cwlu_tm1,
    const float* __restrict__ cwu_tm1, const float* __restrict__ wgp,
    float* out, float* __restrict__ pmin, int* __restrict__ pidx)
{
    __shared__ alignas(16) unsigned short Af[2048 * 8];   // 32 KB
    __shared__ float rn0[64], rn1[64];
    __shared__ float pmv[4][64];
    __shared__ int   pmi[4][64];
    const int row0 = blockIdx.x * 64;
    const int tid = threadIdx.x;
    const int w = tid >> 6, lane = tid & 63;
    f32x4 acc[4] = {};

    for (int half = 0; half < 2; ++half) {
        for (int i = 0; i < 8; ++i) {
            int r = i * 8 + (tid >> 5);
            int koct = tid & 31;
            const float* src = &m_tm1[(size_t)(row0 + r) * 512 + half * 256 + koct * 8];
            float4 x0 = *(const float4*)src;
            float4 x1 = *(const float4*)&src[4];
            float ssi = x0.x*x0.x + x0.y*x0.y + x0.z*x0.z + x0.w*x0.w
                      + x1.x*x1.x + x1.y*x1.y + x1.z*x1.z + x1.w*x1.w;
            ssi += __shfl_xor(ssi, 1); ssi += __shfl_xor(ssi, 2);
            ssi += __shfl_xor(ssi, 4); ssi += __shfl_xor(ssi, 8);
            ssi += __shfl_xor(ssi, 16);
            if ((tid & 31) == 0) { if (half) rn1[r] = ssi; else rn0[r] = ssi; }
            int s_l = koct >> 2, rt = r >> 4;
            int ln = ((r & 15) + ((koct & 3) << 4)) ^ (s_l & 7);
            union { unsigned short hx[8]; uint4 v; } pk;
            pk.hx[0] = f2bf(x0.x); pk.hx[1] = f2bf(x0.y);
            pk.hx[2] = f2bf(x0.z); pk.hx[3] = f2bf(x0.w);
            pk.hx[4] = f2bf(x1.x); pk.hx[5] = f2bf(x1.y);
            pk.hx[6] = f2bf(x1.z); pk.hx[7] = f2bf(x1.w);
            *(uint4*)&Af[((s_l * 4 + rt) * 64 + ln) << 3] = pk.v;
        }
        __syncthreads();
        for (int s_l = 0; s_l < 8; ++s_l) {
            int lnx = lane ^ (s_l & 7);
            bf16x8 af = *(const bf16x8*)&Af[((s_l * 4 + w) * 64 + lnx) << 3];
            int s = half * 8 + s_l;
            #pragma unroll
            for (int n = 0; n < 4; ++n) {
                bf16x8 bf = *(const bf16x8*)&nkf[((s * 4 + n) * 64 + lane) << 3];
                acc[n] = __builtin_amdgcn_mfma_f32_16x16x32_bf16(af, bf, acc[n], 0, 0, 0);
            }
        }
        __syncthreads();
    }

    const float wg = 1.f / (1.f + expf(-wgp[0]));
    const int lhi = lane >> 4, llo = lane & 15;
    float rsq[4];
    #pragma unroll
    for (int reg = 0; reg < 4; ++reg) {
        int rl = w * 16 + lhi * 4 + reg;
        rsq[reg] = rsqrtf(fmaxf(rn0[rl] + rn1[rl], 1e-12f));
    }
    float bmv[4] = { INFINITY, INFINITY, INFINITY, INFINITY };
    int   bmi[4] = { 0x7fffffff, 0x7fffffff, 0x7fffffff, 0x7fffffff };
    #pragma unroll
    for (int reg = 0; reg < 4; ++reg) {
        int r = row0 + w * 16 + lhi * 4 + reg;
        float c0 = acc[0][reg] * rsq[reg];
        float c1 = acc[1][reg] * rsq[reg];
        float c2 = acc[2][reg] * rsq[reg];
        float c3 = acc[3][reg] * rsq[reg];
        float mx = fmaxf(fmaxf(c0, c1), fmaxf(c2, c3));
        mx = fmaxf(mx, __shfl_xor(mx, 1));
        mx = fmaxf(mx, __shfl_xor(mx, 2));
        mx = fmaxf(mx, __shfl_xor(mx, 4));
        mx = fmaxf(mx, __shfl_xor(mx, 8));
        float e0 = expf(c0 - mx), e1 = expf(c1 - mx);
        float e2 = expf(c2 - mx), e3 = expf(c3 - mx);
        float sm = e0 + e1 + e2 + e3;
        sm += __shfl_xor(sm, 1);
        sm += __shfl_xor(sm, 2);
        sm += __shfl_xor(sm, 4);
        sm += __shfl_xor(sm, 8);
        float inv = 1.f / sm;
        float pv[4] = { e0 * inv, e1 * inv, e2 * inv, e3 * inv };
        #pragma unroll
        for (int n = 0; n < 4; ++n) {
            int g = r * 64 + n * 16 + llo;
            float p = pv[n];
            out[OUT_CWR + g] = p;
            float wr = cwr_tm1[g], wl = cwlu_tm1[g], wu = cwu_tm1[g];
            float cww = wg * wr + (1.f - wg) + wl;
            float cwu = 0.95f * wu + p + cww;
            out[OUT_CWU + g] = cwu;
            if (cwu < bmv[n]) { bmv[n] = cwu; bmi[n] = r; }
        }
    }
    #pragma unroll
    for (int n = 0; n < 4; ++n) {
        #pragma unroll
        for (int mk = 16; mk <= 32; mk <<= 1) {
            float ov = __shfl_xor(bmv[n], mk);
            int   oi = __shfl_xor(bmi[n], mk);
            if (ov < bmv[n] || (ov == bmv[n] && oi < bmi[n])) { bmv[n] = ov; bmi[n] = oi; }
        }
    }
    if (lhi == 0) {
        #pragma unroll
        for (int n = 0; n < 4; ++n) { pmv[w][n * 16 + llo] = bmv[n]; pmi[w][n * 16 + llo] = bmi[n]; }
    }
    __syncthreads();
    if (tid < 64) {
        float bv = pmv[0][tid]; int bi = pmi[0][tid];
        #pragma unroll
        for (int q = 1; q < 4; ++q) {
            float v = pmv[q][tid]; int i2 = pmi[q][tid];
            if (v < bv || (v == bv && i2 < bi)) { bv = v; bi = i2; }
        }
        pmin[blockIdx.x * 64 + tid] = bv;
        pidx[blockIdx.x * 64 + tid] = bi;
    }
}

// ---------------------------------------------------------------------------
// K3: final min/argmin over 256 partials; grid 64 (one block per column).
// ---------------------------------------------------------------------------
__global__ __launch_bounds__(256) void k_minfinal(
    const float* __restrict__ pmin, const int* __restrict__ pidx,
    float* __restrict__ minf, int* __restrict__ idxf)
{
    int col = blockIdx.x, t = threadIdx.x;
    float bv = pmin[t * 64 + col];
    int   bi = pidx[t * 64 + col];
    for (int mk = 1; mk < 64; mk <<= 1) {
        float ov = __shfl_xor(bv, mk);
        int   oi = __shfl_xor(bi, mk);
        if (ov < bv || (ov == bv && oi < bi)) { bv = ov; bi = oi; }
    }
    __shared__ float sv[4]; __shared__ int si[4];
    if ((t & 63) == 0) { sv[t >> 6] = bv; si[t >> 6] = bi; }
    __syncthreads();
    if (t == 0) {
        #pragma unroll
        for (int q = 1; q < 4; ++q) {
            if (sv[q] < bv || (sv[q] == bv && si[q] < bi)) { bv = sv[q]; bi = si[q]; }
        }
        minf[col] = bv; idxf[col] = bi;
    }
}

// ---------------------------------------------------------------------------
// K5a: read partials (unchanged). K5b: final reduce (unchanged).
// ---------------------------------------------------------------------------
__global__ __launch_bounds__(256) void k_read_part(
    const float* __restrict__ m_tm1, const float* __restrict__ cwr,
    float* __restrict__ part)
{
    __shared__ alignas(16) float Ms[64][64];
    __shared__ alignas(16) float Ws[64][64];
    const int rs = blockIdx.x >> 3, us = blockIdx.x & 7;
    const int row0 = rs * 128, u0 = us * 64;
    const int tid = threadIdx.x;
    const int bg = tid >> 5, ug = tid & 31;
    const int b0 = bg * 8;
    float2 acc[8] = {};
    for (int ch = 0; ch < 2; ++ch) {
        const int r0 = row0 + ch * 64;
        #pragma unroll
        for (int rr = 0; rr < 4; ++rr) {
            int row = rr * 16 + (tid >> 4);
            int c = (tid & 15) * 4;
            *(float4*)&Ms[row][c] = *(const float4*)&m_tm1[(size_t)(r0 + row) * 512 + u0 + c];
        }
        #pragma unroll
        for (int q = 0; q < 4; ++q) {
            int idx = q * 1024 + tid * 4;
            *(float4*)&Ws[idx >> 6][idx & 63] = *(const float4*)&cwr[r0 * 64 + idx];
        }
        __syncthreads();
        for (int r = 0; r < 64; ++r) {
            float4 w1 = *(const float4*)&Ws[r][b0];
            float4 w2 = *(const float4*)&Ws[r][b0 + 4];
            float2 mv = *(const float2*)&Ms[r][ug * 2];
            acc[0].x += w1.x * mv.x; acc[0].y += w1.x * mv.y;
            acc[1].x += w1.y * mv.x; acc[1].y += w1.y * mv.y;
            acc[2].x += w1.z * mv.x; acc[2].y += w1.z * mv.y;
            acc[3].x += w1.w * mv.x; acc[3].y += w1.w * mv.y;
            acc[4].x += w2.x * mv.x; acc[4].y += w2.x * mv.y;
            acc[5].x += w2.y * mv.x; acc[5].y += w2.y * mv.y;
            acc[6].x += w2.z * mv.x; acc[6].y += w2.z * mv.y;
            acc[7].x += w2.w * mv.x; acc[7].y += w2.w * mv.y;
        }
        __syncthreads();
    }
    #pragma unroll
    for (int bb = 0; bb < 8; ++bb) {
        *(float2*)&part[(size_t)rs * 32768 + (b0 + bb) * 512 + u0 + ug * 2] = acc[bb];
    }
}

__global__ __launch_bounds__(256) void k_read_final(
    const float* __restrict__ part, float* __restrict__ readout)
{
    int gid = blockIdx.x * 256 + threadIdx.x;  // 32768
    float s = 0.f;
    #pragma unroll 8
    for (int rs = 0; rs < 128; ++rs) s += part[(size_t)rs * 32768 + gid];
    readout[gid] = s;
}

// ---------------------------------------------------------------------------
// K4: c_wlu compare + keep mask + m = m_tm1*keep + c_ww @ h via MFMA bf16.
// grid 1024 = 256 row-blocks(64) x 4 u-splits(128). Wave w owns rows w*16..+15.
// A = c_ww (bf16, on-the-fly from cwr/cwlu_tm1); B = hbf (pre-packed frags).
// acc initialized with exact f32 m_tm1*keep (mfma C-in).
// ---------------------------------------------------------------------------
__global__ __launch_bounds__(256) void k_update(
    const float* __restrict__ m_tm1, const float* __restrict__ cwr_tm1,
    const float* __restrict__ cwlu_tm1, const float* __restrict__ wgp,
    const unsigned short* __restrict__ hbf,
    const float* __restrict__ minf, const int* __restrict__ idxf,
    float* out)
{
    __shared__ float keepf[64];
    __shared__ float minS[64];
    __shared__ int   idxS[64];
    const int rb = blockIdx.x >> 2, us = blockIdx.x & 3;
    const int row0 = rb * 64, u0 = us * 128;
    const int tid = threadIdx.x;
    const int w = tid >> 6, lane = tid & 63;
    const int lhi = lane >> 4, llo = lane & 15;
    if (tid < 64) { idxS[tid] = idxf[tid]; minS[tid] = minf[tid]; }
    __syncthreads();
    if (tid < 64) {
        int gr = row0 + tid;
        float f = 1.f;
        #pragma unroll
        for (int b = 0; b < 64; ++b) if (idxS[b] == gr) f = 0.f;
        keepf[tid] = f;
    }
    __syncthreads();
    const float wg = 1.f / (1.f + expf(-wgp[0]));
    if (us == 0) {
        #pragma unroll
        for (int q = 0; q < 4; ++q) {
            int idx = q * 1024 + tid * 4;
            int r = idx >> 6, b = idx & 63;
            int g = (row0 + r) * 64 + b;
            float4 cu = *(const float4*)&out[OUT_CWU + g];
            float4 res;
            res.x = (cu.x <= minS[b + 0]) ? 1.f : 0.f;
            res.y = (cu.y <= minS[b + 1]) ? 1.f : 0.f;
            res.z = (cu.z <= minS[b + 2]) ? 1.f : 0.f;
            res.w = (cu.w <= minS[b + 3]) ? 1.f : 0.f;
            *(float4*)&out[OUT_CWLU + g] = res;
        }
    }
    // acc init: C[row=w*16+lhi*4+reg][col=u0+nt*16+llo] = m_tm1 * keep
    f32x4 acc[8];
    #pragma unroll
    for (int nt = 0; nt < 8; ++nt) {
        #pragma unroll
        for (int reg = 0; reg < 4; ++reg) {
            int rowl = w * 16 + lhi * 4 + reg;
            acc[nt][reg] = m_tm1[(size_t)(row0 + rowl) * 512 + u0 + nt * 16 + llo]
                         * keepf[rowl];
        }
    }
    // K loop: 2 steps of 32 batch
    #pragma unroll
    for (int s = 0; s < 2; ++s) {
        // A-frag: A[row=w*16+llo][k=s*32+lhi*8+e] = c_ww
        int arow = row0 + w * 16 + llo;
        int base = arow * 64 + s * 32 + lhi * 8;
        float4 c0 = *(const float4*)&cwr_tm1[base];
        float4 c1 = *(const float4*)&cwr_tm1[base + 4];
        float4 l0 = *(const float4*)&cwlu_tm1[base];
        float4 l1 = *(const float4*)&cwlu_tm1[base + 4];
        union { unsigned short hx[8]; bf16x8 v; } af;
        af.hx[0] = f2bf(wg * c0.x + (1.f - wg) + l0.x);
        af.hx[1] = f2bf(wg * c0.y + (1.f - wg) + l0.y);
        af.hx[2] = f2bf(wg * c0.z + (1.f - wg) + l0.z);
        af.hx[3] = f2bf(wg * c0.w + (1.f - wg) + l0.w);
        af.hx[4] = f2bf(wg * c1.x + (1.f - wg) + l1.x);
        af.hx[5] = f2bf(wg * c1.y + (1.f - wg) + l1.y);
        af.hx[6] = f2bf(wg * c1.z + (1.f - wg) + l1.z);
        af.hx[7] = f2bf(wg * c1.w + (1.f - wg) + l1.w);
        #pragma unroll
        for (int nt = 0; nt < 8; ++nt) {
            int N = (u0 >> 4) + nt;
            bf16x8 bf = *(const bf16x8*)&hbf[((s * 32 + N) * 64 + lane) << 3];
            acc[nt] = __builtin_amdgcn_mfma_f32_16x16x32_bf16(af.v, bf, acc[nt], 0, 0, 0);
        }
    }
    #pragma unroll
    for (int nt = 0; nt < 8; ++nt) {
        #pragma unroll
        for (int reg = 0; reg < 4; ++reg) {
            int rowl = w * 16 + lhi * 4 + reg;
            out[OUT_M + (size_t)(row0 + rowl) * 512 + u0 + nt * 16 + llo] = acc[nt][reg];
        }
    }
}

extern "C" void kernel_launch(void* const* d_in, const int* in_sizes, int n_in,
                              void* d_out, int out_size, void* d_ws, size_t ws_size,
                              hipStream_t stream)
{
    const float* inputs    = (const float*)d_in[0];
    const float* h_tm1     = (const float*)d_in[1];
    const float* c_tm1     = (const float*)d_in[2];
    const float* r_tm1     = (const float*)d_in[3];
    const float* m_tm1     = (const float*)d_in[4];
    const float* c_wu_tm1  = (const float*)d_in[5];
    const float* c_wlu_tm1 = (const float*)d_in[6];
    const float* c_wr_tm1  = (const float*)d_in[7];
    const float* wk        = (const float*)d_in[8];
    const float* rk        = (const float*)d_in[9];
    const float* bias      = (const float*)d_in[10];
    const float* wgate     = (const float*)d_in[11];
    float* out = (float*)d_out;
    float* ws  = (float*)d_ws;
    float* pre   = out + OUT_M;   // scratch in OUT_M region; consumed by k_gates
    float* rpart = out + OUT_M;   // reused after gates: read partials (4M floats)
    unsigned short* nkf = (unsigned short*)(ws + WS_NKF);
    unsigned short* hbf = (unsigned short*)(ws + WS_HBF);

    k_preact<<<288, 256, 0, stream>>>(inputs, h_tm1, r_tm1, wk, rk, pre);
    k_gates<<<64, 256, 0, stream>>>(pre, bias, c_tm1, out, nkf, hbf);
    k_cos<<<256, 256, 0, stream>>>(m_tm1, nkf, c_wr_tm1, c_wlu_tm1,
                                   c_wu_tm1, wgate, out, ws + WS_PMIN,
                                   (int*)(ws + WS_PIDX));
    k_minfinal<<<64, 256, 0, stream>>>(ws + WS_PMIN, (const int*)(ws + WS_PIDX),
                                       ws + WS_MINF, (int*)(ws + WS_IDXF));
    k_read_part<<<1024, 256, 0, stream>>>(m_tm1, out + OUT_CWR, rpart);
    k_read_final<<<128, 256, 0, stream>>>(rpart, out + OUT_READ);
    k_update<<<1024, 256, 0, stream>>>(m_tm1, c_wr_tm1, c_wlu_tm1, wgate, hbf,
                                       ws + WS_MINF, (const int*)(ws + WS_IDXF), out);
}

// Round 9
// 78.494 us; speedup vs baseline: 1.7817x; 1.1073x over previous
//
#include <hip/hip_runtime.h>
#include <math.h>

// Problem dims: UNITS=512, MEM=16384, BATCH=64
// d_out offsets (floats): h, c, read, m, c_wu, c_wlu, c_wr
#define OUT_H    0
#define OUT_C    32768
#define OUT_READ 65536
#define OUT_M    98304
#define OUT_CWU  8486912
#define OUT_CWLU 9535488
#define OUT_CWR  10584064

// preact scratch (4*294912 floats) lives in OUT_M region, consumed by k_gates
// before k_update overwrites m. Everything else in d_ws (ws_size ~268MB).
// ws offsets (floats):
#define WS_NKF   0          // 32768 ushort: normalized-key bf16 B-frags (cos)
#define WS_HBF   16384      // 32768 ushort: h bf16 B-frags (update)
#define WS_PMIN  32768      // 256*64 partial min values
#define WS_PIDX  49152      // 256*64 partial min indices (int)
#define WS_MINF  65536      // 64 final min
#define WS_IDXF  65600      // 64 final argmin (int)
#define WS_RPART 65664      // 64*32768 = 2M floats read partials (8 MB)

typedef short bf16x8 __attribute__((ext_vector_type(8)));
typedef float f32x4  __attribute__((ext_vector_type(4)));

__device__ __forceinline__ float hsig(float x) {
    return fminf(fmaxf(0.2f * x + 0.5f, 0.f), 1.f);
}
__device__ __forceinline__ unsigned short f2bf(float x) {
    unsigned u = __float_as_uint(x);
    return (unsigned short)((u + 0x7fffu + ((u >> 16) & 1u)) >> 16);
}

// ---------------------------------------------------------------------------
// K1: preactivations. Virtual col space 4608 = [x:2048 | hk:2048 | r_i:512]
// grid 288 = 72 col-tiles(64) x 4 K-quarters(128). Block 256, thread 4r x 4c.
// ---------------------------------------------------------------------------
__global__ __launch_bounds__(256) void k_preact(
    const float* __restrict__ inputs, const float* __restrict__ h_tm1,
    const float* __restrict__ r_tm1, const float* __restrict__ wk,
    const float* __restrict__ rk, float* __restrict__ pre)
{
    __shared__ alignas(16) float Ast[32][68];   // [k][row 0..63 + pad]
    __shared__ alignas(16) float Bs[32][72];    // [k][col]
    const int cb = blockIdx.x % 72, kh = blockIdx.x / 72;
    const int vcol0 = cb * 64;
    const float* A; const float* W; int wstride, wcol0;
    if (vcol0 < 2048)      { A = inputs; W = wk; wstride = 2048; wcol0 = vcol0; }
    else if (vcol0 < 4096) { A = h_tm1;  W = rk; wstride = 2560; wcol0 = vcol0 - 2048; }
    else                   { A = r_tm1;  W = rk; wstride = 2560; wcol0 = 2048 + (vcol0 - 4096); }
    const int tid = threadIdx.x;
    const int rgrp = tid >> 4, cgrp = tid & 15;
    const int srow = tid >> 2, sk = (tid & 3) * 4;
    const int skk = tid >> 3, sc = (tid & 7) * 4;
    float acc[4][4] = {};
    for (int t = 0; t < 4; ++t) {
        const int k0 = kh * 128 + t * 32;
        float4 a0 = *(const float4*)&A[srow * 512 + k0 + sk];
        float4 a1 = *(const float4*)&A[srow * 512 + k0 + 16 + sk];
        float4 w0 = *(const float4*)&W[(size_t)(k0 + skk) * wstride + wcol0 + sc];
        float4 w1 = *(const float4*)&W[(size_t)(k0 + skk) * wstride + wcol0 + 32 + sc];
        Ast[sk + 0][srow] = a0.x; Ast[sk + 1][srow] = a0.y;
        Ast[sk + 2][srow] = a0.z; Ast[sk + 3][srow] = a0.w;
        Ast[16 + sk + 0][srow] = a1.x; Ast[16 + sk + 1][srow] = a1.y;
        Ast[16 + sk + 2][srow] = a1.z; Ast[16 + sk + 3][srow] = a1.w;
        Bs[skk][sc + 0] = w0.x; Bs[skk][sc + 1] = w0.y;
        Bs[skk][sc + 2] = w0.z; Bs[skk][sc + 3] = w0.w;
        Bs[skk][32 + sc + 0] = w1.x; Bs[skk][32 + sc + 1] = w1.y;
        Bs[skk][32 + sc + 2] = w1.z; Bs[skk][32 + sc + 3] = w1.w;
        __syncthreads();
        #pragma unroll
        for (int kk = 0; kk < 32; ++kk) {
            float4 av = *(const float4*)&Ast[kk][rgrp * 4];
            float4 bv = *(const float4*)&Bs[kk][cgrp * 4];
            acc[0][0] += av.x * bv.x; acc[0][1] += av.x * bv.y; acc[0][2] += av.x * bv.z; acc[0][3] += av.x * bv.w;
            acc[1][0] += av.y * bv.x; acc[1][1] += av.y * bv.y; acc[1][2] += av.y * bv.z; acc[1][3] += av.y * bv.w;
            acc[2][0] += av.z * bv.x; acc[2][1] += av.z * bv.y; acc[2][2] += av.z * bv.z; acc[2][3] += av.z * bv.w;
            acc[3][0] += av.w * bv.x; acc[3][1] += av.w * bv.y; acc[3][2] += av.w * bv.z; acc[3][3] += av.w * bv.w;
        }
        __syncthreads();
    }
    float* dst = pre + (size_t)kh * 294912;
    #pragma unroll
    for (int i = 0; i < 4; ++i) {
        float4 v = { acc[i][0], acc[i][1], acc[i][2], acc[i][3] };
        *(float4*)&dst[(rgrp * 4 + i) * 4608 + vcol0 + cgrp * 4] = v;
    }
}

// ---------------------------------------------------------------------------
// K1c: gate fusion (sums 4 K-quarters) -> h, c; fused L2-norm + bf16 packing.
// grid 64 (one block per batch column b), 256 threads, 2 u per thread.
// ---------------------------------------------------------------------------
__global__ __launch_bounds__(256) void k_gates(
    const float* __restrict__ pre, const float* __restrict__ bias,
    const float* __restrict__ c_tm1, float* __restrict__ out,
    unsigned short* __restrict__ nkf, unsigned short* __restrict__ hbf)
{
    int b = blockIdx.x, t = threadIdx.x;
    const float* p0 = pre + b * 4608;
    const float* p1 = pre + 294912 + b * 4608;
    const float* p2 = pre + 2 * 294912 + b * 4608;
    const float* p3 = pre + 3 * 294912 + b * 4608;
    float hh[2], cc[2];
    #pragma unroll
    for (int q = 0; q < 2; ++q) {
        int u = t + q * 256;
        #define S4(o) (p0[o] + p1[o] + p2[o] + p3[o])
        float xi = S4(u)        + bias[u];
        float xf = S4(512 + u)  + bias[512 + u];
        float xc = S4(1024 + u) + bias[1024 + u];
        float xo = S4(1536 + u) + bias[1536 + u];
        float hi = S4(2048 + u);
        float hf = S4(2560 + u);
        float hc = S4(3072 + u);
        float ho = S4(3584 + u);
        float ri = S4(4096 + u);
        #undef S4
        float ig = hsig(xi + hi + ri);
        float fg = hsig(xf + hf);
        cc[q] = fg * c_tm1[b * 512 + u] + ig * tanhf(xc + hc);
        float og = hsig(xo + ho);
        hh[q] = og * tanhf(cc[q]);
        out[OUT_H + b * 512 + u] = hh[q];
        out[OUT_C + b * 512 + u] = cc[q];
    }
    float ss = hh[0] * hh[0] + hh[1] * hh[1];
    __shared__ float red[4];
    for (int m = 1; m < 64; m <<= 1) ss += __shfl_xor(ss, m);
    if ((t & 63) == 0) red[t >> 6] = ss;
    __syncthreads();
    float tot = red[0] + red[1] + red[2] + red[3];
    float rn = rsqrtf(fmaxf(tot, 1e-12f));
    #pragma unroll
    for (int q = 0; q < 2; ++q) {
        int u = t + q * 256;
        int s = u >> 5, n = b >> 4;
        int lane = (b & 15) + 16 * ((u & 31) >> 3);
        int e = u & 7;
        nkf[(((s * 4 + n) * 64 + lane) << 3) + e] = f2bf(hh[q] * rn);
        int s2 = b >> 5, N = u >> 4;
        int l2 = (u & 15) + 16 * ((b & 31) >> 3);
        int e2 = b & 7;
        hbf[(((s2 * 32 + N) * 64 + l2) << 3) + e2] = f2bf(hh[q]);
    }
}

// ---------------------------------------------------------------------------
// K2: cos GEMM via MFMA bf16 (f32 accum). 64 rows/block, grid 256.
// (verified round 7/8)
// ---------------------------------------------------------------------------
__global__ __launch_bounds__(256) void k_cos(
    const float* __restrict__ m_tm1, const unsigned short* __restrict__ nkf,
    const float* __restrict__ cwr_tm1, const float* __restrict__ cwlu_tm1,
    const float* __restrict__ cwu_tm1, const float* __restrict__ wgp,
    float* out, float* __restrict__ pmin, int* __restrict__ pidx)
{
    __shared__ alignas(16) unsigned short Af[2048 * 8];   // 32 KB
    __shared__ float rn0[64], rn1[64];
    __shared__ float pmv[4][64];
    __shared__ int   pmi[4][64];
    const int row0 = blockIdx.x * 64;
    const int tid = threadIdx.x;
    const int w = tid >> 6, lane = tid & 63;
    f32x4 acc[4] = {};

    for (int half = 0; half < 2; ++half) {
        for (int i = 0; i < 8; ++i) {
            int r = i * 8 + (tid >> 5);
            int koct = tid & 31;
            const float* src = &m_tm1[(size_t)(row0 + r) * 512 + half * 256 + koct * 8];
            float4 x0 = *(const float4*)src;
            float4 x1 = *(const float4*)&src[4];
            float ssi = x0.x*x0.x + x0.y*x0.y + x0.z*x0.z + x0.w*x0.w
                      + x1.x*x1.x + x1.y*x1.y + x1.z*x1.z + x1.w*x1.w;
            ssi += __shfl_xor(ssi, 1); ssi += __shfl_xor(ssi, 2);
            ssi += __shfl_xor(ssi, 4); ssi += __shfl_xor(ssi, 8);
            ssi += __shfl_xor(ssi, 16);
            if ((tid & 31) == 0) { if (half) rn1[r] = ssi; else rn0[r] = ssi; }
            int s_l = koct >> 2, rt = r >> 4;
            int ln = ((r & 15) + ((koct & 3) << 4)) ^ (s_l & 7);
            union { unsigned short hx[8]; uint4 v; } pk;
            pk.hx[0] = f2bf(x0.x); pk.hx[1] = f2bf(x0.y);
            pk.hx[2] = f2bf(x0.z); pk.hx[3] = f2bf(x0.w);
            pk.hx[4] = f2bf(x1.x); pk.hx[5] = f2bf(x1.y);
            pk.hx[6] = f2bf(x1.z); pk.hx[7] = f2bf(x1.w);
            *(uint4*)&Af[((s_l * 4 + rt) * 64 + ln) << 3] = pk.v;
        }
        __syncthreads();
        for (int s_l = 0; s_l < 8; ++s_l) {
            int lnx = lane ^ (s_l & 7);
            bf16x8 af = *(const bf16x8*)&Af[((s_l * 4 + w) * 64 + lnx) << 3];
            int s = half * 8 + s_l;
            #pragma unroll
            for (int n = 0; n < 4; ++n) {
                bf16x8 bf = *(const bf16x8*)&nkf[((s * 4 + n) * 64 + lane) << 3];
                acc[n] = __builtin_amdgcn_mfma_f32_16x16x32_bf16(af, bf, acc[n], 0, 0, 0);
            }
        }
        __syncthreads();
    }

    const float wg = 1.f / (1.f + expf(-wgp[0]));
    const int lhi = lane >> 4, llo = lane & 15;
    float rsq[4];
    #pragma unroll
    for (int reg = 0; reg < 4; ++reg) {
        int rl = w * 16 + lhi * 4 + reg;
        rsq[reg] = rsqrtf(fmaxf(rn0[rl] + rn1[rl], 1e-12f));
    }
    float bmv[4] = { INFINITY, INFINITY, INFINITY, INFINITY };
    int   bmi[4] = { 0x7fffffff, 0x7fffffff, 0x7fffffff, 0x7fffffff };
    #pragma unroll
    for (int reg = 0; reg < 4; ++reg) {
        int r = row0 + w * 16 + lhi * 4 + reg;
        float c0 = acc[0][reg] * rsq[reg];
        float c1 = acc[1][reg] * rsq[reg];
        float c2 = acc[2][reg] * rsq[reg];
        float c3 = acc[3][reg] * rsq[reg];
        float mx = fmaxf(fmaxf(c0, c1), fmaxf(c2, c3));
        mx = fmaxf(mx, __shfl_xor(mx, 1));
        mx = fmaxf(mx, __shfl_xor(mx, 2));
        mx = fmaxf(mx, __shfl_xor(mx, 4));
        mx = fmaxf(mx, __shfl_xor(mx, 8));
        float e0 = expf(c0 - mx), e1 = expf(c1 - mx);
        float e2 = expf(c2 - mx), e3 = expf(c3 - mx);
        float sm = e0 + e1 + e2 + e3;
        sm += __shfl_xor(sm, 1);
        sm += __shfl_xor(sm, 2);
        sm += __shfl_xor(sm, 4);
        sm += __shfl_xor(sm, 8);
        float inv = 1.f / sm;
        float pv[4] = { e0 * inv, e1 * inv, e2 * inv, e3 * inv };
        #pragma unroll
        for (int n = 0; n < 4; ++n) {
            int g = r * 64 + n * 16 + llo;
            float p = pv[n];
            out[OUT_CWR + g] = p;
            float wr = cwr_tm1[g], wl = cwlu_tm1[g], wu = cwu_tm1[g];
            float cww = wg * wr + (1.f - wg) + wl;
            float cwu = 0.95f * wu + p + cww;
            out[OUT_CWU + g] = cwu;
            if (cwu < bmv[n]) { bmv[n] = cwu; bmi[n] = r; }
        }
    }
    #pragma unroll
    for (int n = 0; n < 4; ++n) {
        #pragma unroll
        for (int mk = 16; mk <= 32; mk <<= 1) {
            float ov = __shfl_xor(bmv[n], mk);
            int   oi = __shfl_xor(bmi[n], mk);
            if (ov < bmv[n] || (ov == bmv[n] && oi < bmi[n])) { bmv[n] = ov; bmi[n] = oi; }
        }
    }
    if (lhi == 0) {
        #pragma unroll
        for (int n = 0; n < 4; ++n) { pmv[w][n * 16 + llo] = bmv[n]; pmi[w][n * 16 + llo] = bmi[n]; }
    }
    __syncthreads();
    if (tid < 64) {
        float bv = pmv[0][tid]; int bi = pmi[0][tid];
        #pragma unroll
        for (int q = 1; q < 4; ++q) {
            float v = pmv[q][tid]; int i2 = pmi[q][tid];
            if (v < bv || (v == bv && i2 < bi)) { bv = v; bi = i2; }
        }
        pmin[blockIdx.x * 64 + tid] = bv;
        pidx[blockIdx.x * 64 + tid] = bi;
    }
}

// ---------------------------------------------------------------------------
// K5: read partials + embedded minfinal.
// grid 512 = 64 row-splits(256 rows) x 8 u-splits(64). Partials to ws.
// Blocks 0..63 additionally compute the global min/argmin for their column.
// ---------------------------------------------------------------------------
__global__ __launch_bounds__(256) void k_read_part(
    const float* __restrict__ m_tm1, const float* __restrict__ cwr,
    float* __restrict__ part,
    const float* __restrict__ pmin, const int* __restrict__ pidx,
    float* __restrict__ minf, int* __restrict__ idxf)
{
    __shared__ alignas(16) float Ms[64][64];
    __shared__ alignas(16) float Ws[64][64];
    __shared__ float sv[4]; __shared__ int si[4];
    const int bid = blockIdx.x;
    const int tid = threadIdx.x;
    if (bid < 64) {   // embedded minfinal (uniform per block)
        int col = bid;
        float bv = pmin[tid * 64 + col];
        int   bi = pidx[tid * 64 + col];
        for (int mk = 1; mk < 64; mk <<= 1) {
            float ov = __shfl_xor(bv, mk);
            int   oi = __shfl_xor(bi, mk);
            if (ov < bv || (ov == bv && oi < bi)) { bv = ov; bi = oi; }
        }
        if ((tid & 63) == 0) { sv[tid >> 6] = bv; si[tid >> 6] = bi; }
        __syncthreads();
        if (tid == 0) {
            #pragma unroll
            for (int q = 1; q < 4; ++q) {
                if (sv[q] < bv || (sv[q] == bv && si[q] < bi)) { bv = sv[q]; bi = si[q]; }
            }
            minf[col] = bv; idxf[col] = bi;
        }
    }
    const int rs = bid >> 3, us = bid & 7;
    const int row0 = rs * 256, u0 = us * 64;
    const int bg = tid >> 5, ug = tid & 31;
    const int b0 = bg * 8;
    float2 acc[8] = {};
    for (int ch = 0; ch < 4; ++ch) {
        const int r0 = row0 + ch * 64;
        __syncthreads();
        #pragma unroll
        for (int rr = 0; rr < 4; ++rr) {
            int row = rr * 16 + (tid >> 4);
            int c = (tid & 15) * 4;
            *(float4*)&Ms[row][c] = *(const float4*)&m_tm1[(size_t)(r0 + row) * 512 + u0 + c];
        }
        #pragma unroll
        for (int q = 0; q < 4; ++q) {
            int idx = q * 1024 + tid * 4;
            *(float4*)&Ws[idx >> 6][idx & 63] = *(const float4*)&cwr[r0 * 64 + idx];
        }
        __syncthreads();
        for (int r = 0; r < 64; ++r) {
            float4 w1 = *(const float4*)&Ws[r][b0];
            float4 w2 = *(const float4*)&Ws[r][b0 + 4];
            float2 mv = *(const float2*)&Ms[r][ug * 2];
            acc[0].x += w1.x * mv.x; acc[0].y += w1.x * mv.y;
            acc[1].x += w1.y * mv.x; acc[1].y += w1.y * mv.y;
            acc[2].x += w1.z * mv.x; acc[2].y += w1.z * mv.y;
            acc[3].x += w1.w * mv.x; acc[3].y += w1.w * mv.y;
            acc[4].x += w2.x * mv.x; acc[4].y += w2.x * mv.y;
            acc[5].x += w2.y * mv.x; acc[5].y += w2.y * mv.y;
            acc[6].x += w2.z * mv.x; acc[6].y += w2.z * mv.y;
            acc[7].x += w2.w * mv.x; acc[7].y += w2.w * mv.y;
        }
    }
    #pragma unroll
    for (int bb = 0; bb < 8; ++bb) {
        *(float2*)&part[(size_t)rs * 32768 + (b0 + bb) * 512 + u0 + ug * 2] = acc[bb];
    }
}

// ---------------------------------------------------------------------------
// K4: c_wlu compare + keep mask + m = m_tm1*keep + c_ww @ h via MFMA bf16,
// with embedded read-final reduce (us==1 blocks).
// grid 1024 = 256 row-blocks(64) x 4 u-splits(128).
// ---------------------------------------------------------------------------
__global__ __launch_bounds__(256) void k_update(
    const float* __restrict__ m_tm1, const float* __restrict__ cwr_tm1,
    const float* __restrict__ cwlu_tm1, const float* __restrict__ wgp,
    const unsigned short* __restrict__ hbf,
    const float* __restrict__ minf, const int* __restrict__ idxf,
    const float* __restrict__ rpart, float* out)
{
    __shared__ float keepf[64];
    __shared__ float minS[64];
    __shared__ int   idxS[64];
    const int rb = blockIdx.x >> 2, us = blockIdx.x & 3;
    const int row0 = rb * 64, u0 = us * 128;
    const int tid = threadIdx.x;
    const int w = tid >> 6, lane = tid & 63;
    const int lhi = lane >> 4, llo = lane & 15;
    if (tid < 64) { idxS[tid] = idxf[tid]; minS[tid] = minf[tid]; }
    __syncthreads();
    if (tid < 64) {
        int gr = row0 + tid;
        float f = 1.f;
        #pragma unroll
        for (int b = 0; b < 64; ++b) if (idxS[b] == gr) f = 0.f;
        keepf[tid] = f;
    }
    __syncthreads();
    const float wg = 1.f / (1.f + expf(-wgp[0]));
    if (us == 0) {
        #pragma unroll
        for (int q = 0; q < 4; ++q) {
            int idx = q * 1024 + tid * 4;
            int r = idx >> 6, b = idx & 63;
            int g = (row0 + r) * 64 + b;
            float4 cu = *(const float4*)&out[OUT_CWU + g];
            float4 res;
            res.x = (cu.x <= minS[b + 0]) ? 1.f : 0.f;
            res.y = (cu.y <= minS[b + 1]) ? 1.f : 0.f;
            res.z = (cu.z <= minS[b + 2]) ? 1.f : 0.f;
            res.w = (cu.w <= minS[b + 3]) ? 1.f : 0.f;
            *(float4*)&out[OUT_CWLU + g] = res;
        }
    } else if (us == 1) {
        // embedded read-final: this rb covers output floats rb*128 .. +127
        if (tid < 128) {
            int gid = rb * 128 + tid;
            float s = 0.f;
            #pragma unroll 8
            for (int rs = 0; rs < 64; ++rs) s += rpart[(size_t)rs * 32768 + gid];
            out[OUT_READ + gid] = s;
        }
    }
    f32x4 acc[8];
    #pragma unroll
    for (int nt = 0; nt < 8; ++nt) {
        #pragma unroll
        for (int reg = 0; reg < 4; ++reg) {
            int rowl = w * 16 + lhi * 4 + reg;
            acc[nt][reg] = m_tm1[(size_t)(row0 + rowl) * 512 + u0 + nt * 16 + llo]
                         * keepf[rowl];
        }
    }
    #pragma unroll
    for (int s = 0; s < 2; ++s) {
        int arow = row0 + w * 16 + llo;
        int base = arow * 64 + s * 32 + lhi * 8;
        float4 c0 = *(const float4*)&cwr_tm1[base];
        float4 c1 = *(const float4*)&cwr_tm1[base + 4];
        float4 l0 = *(const float4*)&cwlu_tm1[base];
        float4 l1 = *(const float4*)&cwlu_tm1[base + 4];
        union { unsigned short hx[8]; bf16x8 v; } af;
        af.hx[0] = f2bf(wg * c0.x + (1.f - wg) + l0.x);
        af.hx[1] = f2bf(wg * c0.y + (1.f - wg) + l0.y);
        af.hx[2] = f2bf(wg * c0.z + (1.f - wg) + l0.z);
        af.hx[3] = f2bf(wg * c0.w + (1.f - wg) + l0.w);
        af.hx[4] = f2bf(wg * c1.x + (1.f - wg) + l1.x);
        af.hx[5] = f2bf(wg * c1.y + (1.f - wg) + l1.y);
        af.hx[6] = f2bf(wg * c1.z + (1.f - wg) + l1.z);
        af.hx[7] = f2bf(wg * c1.w + (1.f - wg) + l1.w);
        #pragma unroll
        for (int nt = 0; nt < 8; ++nt) {
            int N = (u0 >> 4) + nt;
            bf16x8 bf = *(const bf16x8*)&hbf[((s * 32 + N) * 64 + lane) << 3];
            acc[nt] = __builtin_amdgcn_mfma_f32_16x16x32_bf16(af.v, bf, acc[nt], 0, 0, 0);
        }
    }
    #pragma unroll
    for (int nt = 0; nt < 8; ++nt) {
        #pragma unroll
        for (int reg = 0; reg < 4; ++reg) {
            int rowl = w * 16 + lhi * 4 + reg;
            out[OUT_M + (size_t)(row0 + rowl) * 512 + u0 + nt * 16 + llo] = acc[nt][reg];
        }
    }
}

extern "C" void kernel_launch(void* const* d_in, const int* in_sizes, int n_in,
                              void* d_out, int out_size, void* d_ws, size_t ws_size,
                              hipStream_t stream)
{
    const float* inputs    = (const float*)d_in[0];
    const float* h_tm1     = (const float*)d_in[1];
    const float* c_tm1     = (const float*)d_in[2];
    const float* r_tm1     = (const float*)d_in[3];
    const float* m_tm1     = (const float*)d_in[4];
    const float* c_wu_tm1  = (const float*)d_in[5];
    const float* c_wlu_tm1 = (const float*)d_in[6];
    const float* c_wr_tm1  = (const float*)d_in[7];
    const float* wk        = (const float*)d_in[8];
    const float* rk        = (const float*)d_in[9];
    const float* bias      = (const float*)d_in[10];
    const float* wgate     = (const float*)d_in[11];
    float* out = (float*)d_out;
    float* ws  = (float*)d_ws;
    float* pre = out + OUT_M;   // scratch in OUT_M region; consumed by k_gates
    unsigned short* nkf = (unsigned short*)(ws + WS_NKF);
    unsigned short* hbf = (unsigned short*)(ws + WS_HBF);
    float* rpart = ws + WS_RPART;

    k_preact<<<288, 256, 0, stream>>>(inputs, h_tm1, r_tm1, wk, rk, pre);
    k_gates<<<64, 256, 0, stream>>>(pre, bias, c_tm1, out, nkf, hbf);
    k_cos<<<256, 256, 0, stream>>>(m_tm1, nkf, c_wr_tm1, c_wlu_tm1,
                                   c_wu_tm1, wgate, out, ws + WS_PMIN,
                                   (int*)(ws + WS_PIDX));
    k_read_part<<<512, 256, 0, stream>>>(m_tm1, out + OUT_CWR, rpart,
                                         ws + WS_PMIN, (const int*)(ws + WS_PIDX),
                                         ws + WS_MINF, (int*)(ws + WS_IDXF));
    k_update<<<1024, 256, 0, stream>>>(m_tm1, c_wr_tm1, c_wlu_tm1, wgate, hbf,
                                       ws + WS_MINF, (const int*)(ws + WS_IDXF),
                                       rpart, out);
}

// Round 10
// 71.558 us; speedup vs baseline: 1.9544x; 1.0969x over previous
//
#include <hip/hip_runtime.h>
#include <math.h>

// Problem dims: UNITS=512, MEM=16384, BATCH=64
// d_out offsets (floats): h, c, read, m, c_wu, c_wlu, c_wr
#define OUT_H    0
#define OUT_C    32768
#define OUT_READ 65536
#define OUT_M    98304
#define OUT_CWU  8486912
#define OUT_CWLU 9535488
#define OUT_CWR  10584064

// preact scratch (4*294912 floats) lives in OUT_M region, consumed by k_gates
// before k_update overwrites m. Everything else in d_ws (ws_size ~268MB).
// ws offsets (floats):
#define WS_NKF   0          // 32768 ushort: normalized-key bf16 B-frags (cos)
#define WS_HBF   16384      // 32768 ushort: h bf16 B-frags (update)
#define WS_PMIN  32768      // 256*64 partial min values
#define WS_PIDX  49152      // 256*64 partial min indices (int)
#define WS_MINF  65536      // 64 final min
#define WS_IDXF  65600      // 64 final argmin (int)
#define WS_RPART 65664      // 64*32768 = 2M floats read partials (8 MB)

typedef short bf16x8 __attribute__((ext_vector_type(8)));
typedef float f32x4  __attribute__((ext_vector_type(4)));

__device__ __forceinline__ float hsig(float x) {
    return fminf(fmaxf(0.2f * x + 0.5f, 0.f), 1.f);
}
__device__ __forceinline__ unsigned short f2bf(float x) {
    unsigned u = __float_as_uint(x);
    return (unsigned short)((u + 0x7fffu + ((u >> 16) & 1u)) >> 16);
}

// ---------------------------------------------------------------------------
// K1: preactivations. Virtual col space 4608 = [x:2048 | hk:2048 | r_i:512]
// grid 288 = 72 col-tiles(64) x 4 K-quarters(128). Block 256, thread 4r x 4c.
// ---------------------------------------------------------------------------
__global__ __launch_bounds__(256) void k_preact(
    const float* __restrict__ inputs, const float* __restrict__ h_tm1,
    const float* __restrict__ r_tm1, const float* __restrict__ wk,
    const float* __restrict__ rk, float* __restrict__ pre)
{
    __shared__ alignas(16) float Ast[32][68];   // [k][row 0..63 + pad]
    __shared__ alignas(16) float Bs[32][72];    // [k][col]
    const int cb = blockIdx.x % 72, kh = blockIdx.x / 72;
    const int vcol0 = cb * 64;
    const float* A; const float* W; int wstride, wcol0;
    if (vcol0 < 2048)      { A = inputs; W = wk; wstride = 2048; wcol0 = vcol0; }
    else if (vcol0 < 4096) { A = h_tm1;  W = rk; wstride = 2560; wcol0 = vcol0 - 2048; }
    else                   { A = r_tm1;  W = rk; wstride = 2560; wcol0 = 2048 + (vcol0 - 4096); }
    const int tid = threadIdx.x;
    const int rgrp = tid >> 4, cgrp = tid & 15;
    const int srow = tid >> 2, sk = (tid & 3) * 4;
    const int skk = tid >> 3, sc = (tid & 7) * 4;
    float acc[4][4] = {};
    for (int t = 0; t < 4; ++t) {
        const int k0 = kh * 128 + t * 32;
        float4 a0 = *(const float4*)&A[srow * 512 + k0 + sk];
        float4 a1 = *(const float4*)&A[srow * 512 + k0 + 16 + sk];
        float4 w0 = *(const float4*)&W[(size_t)(k0 + skk) * wstride + wcol0 + sc];
        float4 w1 = *(const float4*)&W[(size_t)(k0 + skk) * wstride + wcol0 + 32 + sc];
        Ast[sk + 0][srow] = a0.x; Ast[sk + 1][srow] = a0.y;
        Ast[sk + 2][srow] = a0.z; Ast[sk + 3][srow] = a0.w;
        Ast[16 + sk + 0][srow] = a1.x; Ast[16 + sk + 1][srow] = a1.y;
        Ast[16 + sk + 2][srow] = a1.z; Ast[16 + sk + 3][srow] = a1.w;
        Bs[skk][sc + 0] = w0.x; Bs[skk][sc + 1] = w0.y;
        Bs[skk][sc + 2] = w0.z; Bs[skk][sc + 3] = w0.w;
        Bs[skk][32 + sc + 0] = w1.x; Bs[skk][32 + sc + 1] = w1.y;
        Bs[skk][32 + sc + 2] = w1.z; Bs[skk][32 + sc + 3] = w1.w;
        __syncthreads();
        #pragma unroll
        for (int kk = 0; kk < 32; ++kk) {
            float4 av = *(const float4*)&Ast[kk][rgrp * 4];
            float4 bv = *(const float4*)&Bs[kk][cgrp * 4];
            acc[0][0] += av.x * bv.x; acc[0][1] += av.x * bv.y; acc[0][2] += av.x * bv.z; acc[0][3] += av.x * bv.w;
            acc[1][0] += av.y * bv.x; acc[1][1] += av.y * bv.y; acc[1][2] += av.y * bv.z; acc[1][3] += av.y * bv.w;
            acc[2][0] += av.z * bv.x; acc[2][1] += av.z * bv.y; acc[2][2] += av.z * bv.z; acc[2][3] += av.z * bv.w;
            acc[3][0] += av.w * bv.x; acc[3][1] += av.w * bv.y; acc[3][2] += av.w * bv.z; acc[3][3] += av.w * bv.w;
        }
        __syncthreads();
    }
    float* dst = pre + (size_t)kh * 294912;
    #pragma unroll
    for (int i = 0; i < 4; ++i) {
        float4 v = { acc[i][0], acc[i][1], acc[i][2], acc[i][3] };
        *(float4*)&dst[(rgrp * 4 + i) * 4608 + vcol0 + cgrp * 4] = v;
    }
}

// ---------------------------------------------------------------------------
// K1c: gate fusion (sums 4 K-quarters) -> h, c; fused L2-norm + bf16 packing.
// grid 64 (one block per batch column b), 256 threads, 2 u per thread.
// ---------------------------------------------------------------------------
__global__ __launch_bounds__(256) void k_gates(
    const float* __restrict__ pre, const float* __restrict__ bias,
    const float* __restrict__ c_tm1, float* __restrict__ out,
    unsigned short* __restrict__ nkf, unsigned short* __restrict__ hbf)
{
    int b = blockIdx.x, t = threadIdx.x;
    const float* p0 = pre + b * 4608;
    const float* p1 = pre + 294912 + b * 4608;
    const float* p2 = pre + 2 * 294912 + b * 4608;
    const float* p3 = pre + 3 * 294912 + b * 4608;
    float hh[2], cc[2];
    #pragma unroll
    for (int q = 0; q < 2; ++q) {
        int u = t + q * 256;
        #define S4(o) (p0[o] + p1[o] + p2[o] + p3[o])
        float xi = S4(u)        + bias[u];
        float xf = S4(512 + u)  + bias[512 + u];
        float xc = S4(1024 + u) + bias[1024 + u];
        float xo = S4(1536 + u) + bias[1536 + u];
        float hi = S4(2048 + u);
        float hf = S4(2560 + u);
        float hc = S4(3072 + u);
        float ho = S4(3584 + u);
        float ri = S4(4096 + u);
        #undef S4
        float ig = hsig(xi + hi + ri);
        float fg = hsig(xf + hf);
        cc[q] = fg * c_tm1[b * 512 + u] + ig * tanhf(xc + hc);
        float og = hsig(xo + ho);
        hh[q] = og * tanhf(cc[q]);
        out[OUT_H + b * 512 + u] = hh[q];
        out[OUT_C + b * 512 + u] = cc[q];
    }
    float ss = hh[0] * hh[0] + hh[1] * hh[1];
    __shared__ float red[4];
    for (int m = 1; m < 64; m <<= 1) ss += __shfl_xor(ss, m);
    if ((t & 63) == 0) red[t >> 6] = ss;
    __syncthreads();
    float tot = red[0] + red[1] + red[2] + red[3];
    float rn = rsqrtf(fmaxf(tot, 1e-12f));
    #pragma unroll
    for (int q = 0; q < 2; ++q) {
        int u = t + q * 256;
        int s = u >> 5, n = b >> 4;
        int lane = (b & 15) + 16 * ((u & 31) >> 3);
        int e = u & 7;
        nkf[(((s * 4 + n) * 64 + lane) << 3) + e] = f2bf(hh[q] * rn);
        int s2 = b >> 5, N = u >> 4;
        int l2 = (u & 15) + 16 * ((b & 31) >> 3);
        int e2 = b & 7;
        hbf[(((s2 * 32 + N) * 64 + l2) << 3) + e2] = f2bf(hh[q]);
    }
}

// ---------------------------------------------------------------------------
// K2: cos GEMM via MFMA bf16 (f32 accum). 64 rows/block, grid 256.
// (verified rounds 7-9)
// ---------------------------------------------------------------------------
__global__ __launch_bounds__(256) void k_cos(
    const float* __restrict__ m_tm1, const unsigned short* __restrict__ nkf,
    const float* __restrict__ cwr_tm1, const float* __restrict__ cwlu_tm1,
    const float* __restrict__ cwu_tm1, const float* __restrict__ wgp,
    float* out, float* __restrict__ pmin, int* __restrict__ pidx)
{
    __shared__ alignas(16) unsigned short Af[2048 * 8];   // 32 KB
    __shared__ float rn0[64], rn1[64];
    __shared__ float pmv[4][64];
    __shared__ int   pmi[4][64];
    const int row0 = blockIdx.x * 64;
    const int tid = threadIdx.x;
    const int w = tid >> 6, lane = tid & 63;
    f32x4 acc[4] = {};

    for (int half = 0; half < 2; ++half) {
        for (int i = 0; i < 8; ++i) {
            int r = i * 8 + (tid >> 5);
            int koct = tid & 31;
            const float* src = &m_tm1[(size_t)(row0 + r) * 512 + half * 256 + koct * 8];
            float4 x0 = *(const float4*)src;
            float4 x1 = *(const float4*)&src[4];
            float ssi = x0.x*x0.x + x0.y*x0.y + x0.z*x0.z + x0.w*x0.w
                      + x1.x*x1.x + x1.y*x1.y + x1.z*x1.z + x1.w*x1.w;
            ssi += __shfl_xor(ssi, 1); ssi += __shfl_xor(ssi, 2);
            ssi += __shfl_xor(ssi, 4); ssi += __shfl_xor(ssi, 8);
            ssi += __shfl_xor(ssi, 16);
            if ((tid & 31) == 0) { if (half) rn1[r] = ssi; else rn0[r] = ssi; }
            int s_l = koct >> 2, rt = r >> 4;
            int ln = ((r & 15) + ((koct & 3) << 4)) ^ (s_l & 7);
            union { unsigned short hx[8]; uint4 v; } pk;
            pk.hx[0] = f2bf(x0.x); pk.hx[1] = f2bf(x0.y);
            pk.hx[2] = f2bf(x0.z); pk.hx[3] = f2bf(x0.w);
            pk.hx[4] = f2bf(x1.x); pk.hx[5] = f2bf(x1.y);
            pk.hx[6] = f2bf(x1.z); pk.hx[7] = f2bf(x1.w);
            *(uint4*)&Af[((s_l * 4 + rt) * 64 + ln) << 3] = pk.v;
        }
        __syncthreads();
        for (int s_l = 0; s_l < 8; ++s_l) {
            int lnx = lane ^ (s_l & 7);
            bf16x8 af = *(const bf16x8*)&Af[((s_l * 4 + w) * 64 + lnx) << 3];
            int s = half * 8 + s_l;
            #pragma unroll
            for (int n = 0; n < 4; ++n) {
                bf16x8 bf = *(const bf16x8*)&nkf[((s * 4 + n) * 64 + lane) << 3];
                acc[n] = __builtin_amdgcn_mfma_f32_16x16x32_bf16(af, bf, acc[n], 0, 0, 0);
            }
        }
        __syncthreads();
    }

    const float wg = 1.f / (1.f + expf(-wgp[0]));
    const int lhi = lane >> 4, llo = lane & 15;
    float rsq[4];
    #pragma unroll
    for (int reg = 0; reg < 4; ++reg) {
        int rl = w * 16 + lhi * 4 + reg;
        rsq[reg] = rsqrtf(fmaxf(rn0[rl] + rn1[rl], 1e-12f));
    }
    float bmv[4] = { INFINITY, INFINITY, INFINITY, INFINITY };
    int   bmi[4] = { 0x7fffffff, 0x7fffffff, 0x7fffffff, 0x7fffffff };
    #pragma unroll
    for (int reg = 0; reg < 4; ++reg) {
        int r = row0 + w * 16 + lhi * 4 + reg;
        float c0 = acc[0][reg] * rsq[reg];
        float c1 = acc[1][reg] * rsq[reg];
        float c2 = acc[2][reg] * rsq[reg];
        float c3 = acc[3][reg] * rsq[reg];
        float mx = fmaxf(fmaxf(c0, c1), fmaxf(c2, c3));
        mx = fmaxf(mx, __shfl_xor(mx, 1));
        mx = fmaxf(mx, __shfl_xor(mx, 2));
        mx = fmaxf(mx, __shfl_xor(mx, 4));
        mx = fmaxf(mx, __shfl_xor(mx, 8));
        float e0 = expf(c0 - mx), e1 = expf(c1 - mx);
        float e2 = expf(c2 - mx), e3 = expf(c3 - mx);
        float sm = e0 + e1 + e2 + e3;
        sm += __shfl_xor(sm, 1);
        sm += __shfl_xor(sm, 2);
        sm += __shfl_xor(sm, 4);
        sm += __shfl_xor(sm, 8);
        float inv = 1.f / sm;
        float pv[4] = { e0 * inv, e1 * inv, e2 * inv, e3 * inv };
        #pragma unroll
        for (int n = 0; n < 4; ++n) {
            int g = r * 64 + n * 16 + llo;
            float p = pv[n];
            out[OUT_CWR + g] = p;
            float wr = cwr_tm1[g], wl = cwlu_tm1[g], wu = cwu_tm1[g];
            float cww = wg * wr + (1.f - wg) + wl;
            float cwu = 0.95f * wu + p + cww;
            out[OUT_CWU + g] = cwu;
            if (cwu < bmv[n]) { bmv[n] = cwu; bmi[n] = r; }
        }
    }
    #pragma unroll
    for (int n = 0; n < 4; ++n) {
        #pragma unroll
        for (int mk = 16; mk <= 32; mk <<= 1) {
            float ov = __shfl_xor(bmv[n], mk);
            int   oi = __shfl_xor(bmi[n], mk);
            if (ov < bmv[n] || (ov == bmv[n] && oi < bmi[n])) { bmv[n] = ov; bmi[n] = oi; }
        }
    }
    if (lhi == 0) {
        #pragma unroll
        for (int n = 0; n < 4; ++n) { pmv[w][n * 16 + llo] = bmv[n]; pmi[w][n * 16 + llo] = bmi[n]; }
    }
    __syncthreads();
    if (tid < 64) {
        float bv = pmv[0][tid]; int bi = pmi[0][tid];
        #pragma unroll
        for (int q = 1; q < 4; ++q) {
            float v = pmv[q][tid]; int i2 = pmi[q][tid];
            if (v < bv || (v == bv && i2 < bi)) { bv = v; bi = i2; }
        }
        pmin[blockIdx.x * 64 + tid] = bv;
        pidx[blockIdx.x * 64 + tid] = bi;
    }
}

// ---------------------------------------------------------------------------
// K5: read partials via MFMA bf16 + embedded minfinal.
// grid 512 = 64 row-splits(256 rows) x 8 u-splits(64).
// D[b][u] per block: A = cwr^T (A-frags), B = m (B-frags), K = 256 rows,
// 2 chunks of 128. Frag conventions identical to k_cos/k_nkey (verified).
// ---------------------------------------------------------------------------
__global__ __launch_bounds__(256) void k_read_part(
    const float* __restrict__ m_tm1, const float* __restrict__ cwr,
    float* __restrict__ part,
    const float* __restrict__ pmin, const int* __restrict__ pidx,
    float* __restrict__ minf, int* __restrict__ idxf)
{
    __shared__ alignas(16) unsigned short Mf[8192];   // 16 KB: m B-frags [s4][tu4][lane64][e8]
    __shared__ alignas(16) unsigned short Cf[8192];   // 16 KB: cwr A-frags [s4][tb4][lane64][e8]
    __shared__ float sv[4]; __shared__ int si[4];
    const int bid = blockIdx.x;
    const int tid = threadIdx.x;
    if (bid < 64) {   // embedded minfinal (block-uniform branch)
        int col = bid;
        float bv = pmin[tid * 64 + col];
        int   bi = pidx[tid * 64 + col];
        for (int mk = 1; mk < 64; mk <<= 1) {
            float ov = __shfl_xor(bv, mk);
            int   oi = __shfl_xor(bi, mk);
            if (ov < bv || (ov == bv && oi < bi)) { bv = ov; bi = oi; }
        }
        if ((tid & 63) == 0) { sv[tid >> 6] = bv; si[tid >> 6] = bi; }
        __syncthreads();
        if (tid == 0) {
            #pragma unroll
            for (int q = 1; q < 4; ++q) {
                if (sv[q] < bv || (sv[q] == bv && si[q] < bi)) { bv = sv[q]; bi = si[q]; }
            }
            minf[col] = bv; idxf[col] = bi;
        }
    }
    const int rs = bid >> 3, us = bid & 7;
    const int row0 = rs * 256, u0 = us * 64;
    const int w = tid >> 6, lane = tid & 63;
    f32x4 acc[4] = {};   // D tiles: rows b = tb*16.., cols u = u0 + w*16..
    for (int ch = 0; ch < 2; ++ch) {
        const int r0 = row0 + ch * 128;
        __syncthreads();
        #pragma unroll
        for (int q = 0; q < 8; ++q) {
            int idx = q * 1024 + tid * 4;        // 8192 elems per array
            int rr = idx >> 6, cc = idx & 63;    // rr 0..127 (k), cc col base
            float4 mv = *(const float4*)&m_tm1[(size_t)(r0 + rr) * 512 + u0 + cc];
            float4 cv = *(const float4*)&cwr[(r0 + rr) * 64 + cc];
            int s = rr >> 5, e = rr & 7, lo = 16 * ((rr & 31) >> 3);
            float mvs[4] = { mv.x, mv.y, mv.z, mv.w };
            float cvs[4] = { cv.x, cv.y, cv.z, cv.w };
            #pragma unroll
            for (int i = 0; i < 4; ++i) {
                int col = cc + i;
                int ln = (col & 15) + lo;
                int t4 = col >> 4;
                int slot = (((s * 4 + t4) * 64 + ln) << 3) + e;
                Mf[slot] = f2bf(mvs[i]);
                Cf[slot] = f2bf(cvs[i]);
            }
        }
        __syncthreads();
        #pragma unroll
        for (int s = 0; s < 4; ++s) {
            bf16x8 bf = *(const bf16x8*)&Mf[((s * 4 + w) * 64 + lane) << 3];
            #pragma unroll
            for (int tb = 0; tb < 4; ++tb) {
                bf16x8 af = *(const bf16x8*)&Cf[((s * 4 + tb) * 64 + lane) << 3];
                acc[tb] = __builtin_amdgcn_mfma_f32_16x16x32_bf16(af, bf, acc[tb], 0, 0, 0);
            }
        }
    }
    const int lhi = lane >> 4, llo = lane & 15;
    #pragma unroll
    for (int tb = 0; tb < 4; ++tb) {
        #pragma unroll
        for (int reg = 0; reg < 4; ++reg) {
            int b = tb * 16 + lhi * 4 + reg;
            part[(size_t)rs * 32768 + b * 512 + u0 + w * 16 + llo] = acc[tb][reg];
        }
    }
}

// ---------------------------------------------------------------------------
// K4: c_wlu compare + keep mask + m = m_tm1*keep + c_ww @ h via MFMA bf16,
// with embedded read-final reduce (us==1 blocks).
// grid 1024 = 256 row-blocks(64) x 4 u-splits(128).
// ---------------------------------------------------------------------------
__global__ __launch_bounds__(256) void k_update(
    const float* __restrict__ m_tm1, const float* __restrict__ cwr_tm1,
    const float* __restrict__ cwlu_tm1, const float* __restrict__ wgp,
    const unsigned short* __restrict__ hbf,
    const float* __restrict__ minf, const int* __restrict__ idxf,
    const float* __restrict__ rpart, float* out)
{
    __shared__ float keepf[64];
    __shared__ float minS[64];
    __shared__ int   idxS[64];
    const int rb = blockIdx.x >> 2, us = blockIdx.x & 3;
    const int row0 = rb * 64, u0 = us * 128;
    const int tid = threadIdx.x;
    const int w = tid >> 6, lane = tid & 63;
    const int lhi = lane >> 4, llo = lane & 15;
    if (tid < 64) { idxS[tid] = idxf[tid]; minS[tid] = minf[tid]; }
    __syncthreads();
    if (tid < 64) {
        int gr = row0 + tid;
        float f = 1.f;
        #pragma unroll
        for (int b = 0; b < 64; ++b) if (idxS[b] == gr) f = 0.f;
        keepf[tid] = f;
    }
    __syncthreads();
    const float wg = 1.f / (1.f + expf(-wgp[0]));
    if (us == 0) {
        #pragma unroll
        for (int q = 0; q < 4; ++q) {
            int idx = q * 1024 + tid * 4;
            int r = idx >> 6, b = idx & 63;
            int g = (row0 + r) * 64 + b;
            float4 cu = *(const float4*)&out[OUT_CWU + g];
            float4 res;
            res.x = (cu.x <= minS[b + 0]) ? 1.f : 0.f;
            res.y = (cu.y <= minS[b + 1]) ? 1.f : 0.f;
            res.z = (cu.z <= minS[b + 2]) ? 1.f : 0.f;
            res.w = (cu.w <= minS[b + 3]) ? 1.f : 0.f;
            *(float4*)&out[OUT_CWLU + g] = res;
        }
    } else if (us == 1) {
        if (tid < 128) {
            int gid = rb * 128 + tid;
            float s = 0.f;
            #pragma unroll 8
            for (int rs = 0; rs < 64; ++rs) s += rpart[(size_t)rs * 32768 + gid];
            out[OUT_READ + gid] = s;
        }
    }
    f32x4 acc[8];
    #pragma unroll
    for (int nt = 0; nt < 8; ++nt) {
        #pragma unroll
        for (int reg = 0; reg < 4; ++reg) {
            int rowl = w * 16 + lhi * 4 + reg;
            acc[nt][reg] = m_tm1[(size_t)(row0 + rowl) * 512 + u0 + nt * 16 + llo]
                         * keepf[rowl];
        }
    }
    #pragma unroll
    for (int s = 0; s < 2; ++s) {
        int arow = row0 + w * 16 + llo;
        int base = arow * 64 + s * 32 + lhi * 8;
        float4 c0 = *(const float4*)&cwr_tm1[base];
        float4 c1 = *(const float4*)&cwr_tm1[base + 4];
        float4 l0 = *(const float4*)&cwlu_tm1[base];
        float4 l1 = *(const float4*)&cwlu_tm1[base + 4];
        union { unsigned short hx[8]; bf16x8 v; } af;
        af.hx[0] = f2bf(wg * c0.x + (1.f - wg) + l0.x);
        af.hx[1] = f2bf(wg * c0.y + (1.f - wg) + l0.y);
        af.hx[2] = f2bf(wg * c0.z + (1.f - wg) + l0.z);
        af.hx[3] = f2bf(wg * c0.w + (1.f - wg) + l0.w);
        af.hx[4] = f2bf(wg * c1.x + (1.f - wg) + l1.x);
        af.hx[5] = f2bf(wg * c1.y + (1.f - wg) + l1.y);
        af.hx[6] = f2bf(wg * c1.z + (1.f - wg) + l1.z);
        af.hx[7] = f2bf(wg * c1.w + (1.f - wg) + l1.w);
        #pragma unroll
        for (int nt = 0; nt < 8; ++nt) {
            int N = (u0 >> 4) + nt;
            bf16x8 bf = *(const bf16x8*)&hbf[((s * 32 + N) * 64 + lane) << 3];
            acc[nt] = __builtin_amdgcn_mfma_f32_16x16x32_bf16(af.v, bf, acc[nt], 0, 0, 0);
        }
    }
    #pragma unroll
    for (int nt = 0; nt < 8; ++nt) {
        #pragma unroll
        for (int reg = 0; reg < 4; ++reg) {
            int rowl = w * 16 + lhi * 4 + reg;
            out[OUT_M + (size_t)(row0 + rowl) * 512 + u0 + nt * 16 + llo] = acc[nt][reg];
        }
    }
}

extern "C" void kernel_launch(void* const* d_in, const int* in_sizes, int n_in,
                              void* d_out, int out_size, void* d_ws, size_t ws_size,
                              hipStream_t stream)
{
    const float* inputs    = (const float*)d_in[0];
    const float* h_tm1     = (const float*)d_in[1];
    const float* c_tm1     = (const float*)d_in[2];
    const float* r_tm1     = (const float*)d_in[3];
    const float* m_tm1     = (const float*)d_in[4];
    const float* c_wu_tm1  = (const float*)d_in[5];
    const float* c_wlu_tm1 = (const float*)d_in[6];
    const float* c_wr_tm1  = (const float*)d_in[7];
    const float* wk        = (const float*)d_in[8];
    const float* rk        = (const float*)d_in[9];
    const float* bias      = (const float*)d_in[10];
    const float* wgate     = (const float*)d_in[11];
    float* out = (float*)d_out;
    float* ws  = (float*)d_ws;
    float* pre = out + OUT_M;   // scratch in OUT_M region; consumed by k_gates
    unsigned short* nkf = (unsigned short*)(ws + WS_NKF);
    unsigned short* hbf = (unsigned short*)(ws + WS_HBF);
    float* rpart = ws + WS_RPART;

    k_preact<<<288, 256, 0, stream>>>(inputs, h_tm1, r_tm1, wk, rk, pre);
    k_gates<<<64, 256, 0, stream>>>(pre, bias, c_tm1, out, nkf, hbf);
    k_cos<<<256, 256, 0, stream>>>(m_tm1, nkf, c_wr_tm1, c_wlu_tm1,
                                   c_wu_tm1, wgate, out, ws + WS_PMIN,
                                   (int*)(ws + WS_PIDX));
    k_read_part<<<512, 256, 0, stream>>>(m_tm1, out + OUT_CWR, rpart,
                                         ws + WS_PMIN, (const int*)(ws + WS_PIDX),
                                         ws + WS_MINF, (int*)(ws + WS_IDXF));
    k_update<<<1024, 256, 0, stream>>>(m_tm1, c_wr_tm1, c_wlu_tm1, wgate, hbf,
                                       ws + WS_MINF, (const int*)(ws + WS_IDXF),
                                       rpart, out);
}

// Round 12
// 66.534 us; speedup vs baseline: 2.1020x; 1.0755x over previous
//
#include <hip/hip_runtime.h>
#include <math.h>

// Problem dims: UNITS=512, MEM=16384, BATCH=64
// d_out offsets (floats): h, c, read, m, c_wu, c_wlu, c_wr
#define OUT_H    0
#define OUT_C    32768
#define OUT_READ 65536
#define OUT_M    98304
#define OUT_CWU  8486912
#define OUT_CWLU 9535488
#define OUT_CWR  10584064

// preact scratch (4*294912 floats) lives in OUT_M region, consumed by k_gates
// before k_update overwrites m. Everything else in d_ws (ws_size ~268MB).
// ws offsets (floats):
#define WS_NKF   0          // 32768 ushort: normalized-key bf16 B-frags (cos)
#define WS_HBF   16384      // 32768 ushort: h bf16 B-frags (update)
#define WS_PMIN  32768      // 256*64 partial min values
#define WS_PIDX  49152      // 256*64 partial min indices (int)
#define WS_MINF  65536      // 64 final min
#define WS_IDXF  65600      // 64 final argmin (int)
#define WS_CWWF  65664      // 256 blocks * 4096 ushort = 524288 FLOATS c_ww A-frags
#define WS_RPART 589952     // 64*32768 = 2M floats read partials (8 MB)
                            // (round-11 bug: was 327808, overlapped cwwf -> NaN)

typedef short bf16x8 __attribute__((ext_vector_type(8)));
typedef float f32x4  __attribute__((ext_vector_type(4)));

__device__ __forceinline__ float hsig(float x) {
    return fminf(fmaxf(0.2f * x + 0.5f, 0.f), 1.f);
}
__device__ __forceinline__ unsigned short f2bf(float x) {
    unsigned u = __float_as_uint(x);
    return (unsigned short)((u + 0x7fffu + ((u >> 16) & 1u)) >> 16);
}

// ---------------------------------------------------------------------------
// K1: preactivations. Virtual col space 4608 = [x:2048 | hk:2048 | r_i:512]
// grid 288 = 72 col-tiles(64) x 4 K-quarters(128). Block 256, thread 4r x 4c.
// ---------------------------------------------------------------------------
__global__ __launch_bounds__(256) void k_preact(
    const float* __restrict__ inputs, const float* __restrict__ h_tm1,
    const float* __restrict__ r_tm1, const float* __restrict__ wk,
    const float* __restrict__ rk, float* __restrict__ pre)
{
    __shared__ alignas(16) float Ast[32][68];   // [k][row 0..63 + pad]
    __shared__ alignas(16) float Bs[32][72];    // [k][col]
    const int cb = blockIdx.x % 72, kh = blockIdx.x / 72;
    const int vcol0 = cb * 64;
    const float* A; const float* W; int wstride, wcol0;
    if (vcol0 < 2048)      { A = inputs; W = wk; wstride = 2048; wcol0 = vcol0; }
    else if (vcol0 < 4096) { A = h_tm1;  W = rk; wstride = 2560; wcol0 = vcol0 - 2048; }
    else                   { A = r_tm1;  W = rk; wstride = 2560; wcol0 = 2048 + (vcol0 - 4096); }
    const int tid = threadIdx.x;
    const int rgrp = tid >> 4, cgrp = tid & 15;
    const int srow = tid >> 2, sk = (tid & 3) * 4;
    const int skk = tid >> 3, sc = (tid & 7) * 4;
    float acc[4][4] = {};
    for (int t = 0; t < 4; ++t) {
        const int k0 = kh * 128 + t * 32;
        float4 a0 = *(const float4*)&A[srow * 512 + k0 + sk];
        float4 a1 = *(const float4*)&A[srow * 512 + k0 + 16 + sk];
        float4 w0 = *(const float4*)&W[(size_t)(k0 + skk) * wstride + wcol0 + sc];
        float4 w1 = *(const float4*)&W[(size_t)(k0 + skk) * wstride + wcol0 + 32 + sc];
        Ast[sk + 0][srow] = a0.x; Ast[sk + 1][srow] = a0.y;
        Ast[sk + 2][srow] = a0.z; Ast[sk + 3][srow] = a0.w;
        Ast[16 + sk + 0][srow] = a1.x; Ast[16 + sk + 1][srow] = a1.y;
        Ast[16 + sk + 2][srow] = a1.z; Ast[16 + sk + 3][srow] = a1.w;
        Bs[skk][sc + 0] = w0.x; Bs[skk][sc + 1] = w0.y;
        Bs[skk][sc + 2] = w0.z; Bs[skk][sc + 3] = w0.w;
        Bs[skk][32 + sc + 0] = w1.x; Bs[skk][32 + sc + 1] = w1.y;
        Bs[skk][32 + sc + 2] = w1.z; Bs[skk][32 + sc + 3] = w1.w;
        __syncthreads();
        #pragma unroll
        for (int kk = 0; kk < 32; ++kk) {
            float4 av = *(const float4*)&Ast[kk][rgrp * 4];
            float4 bv = *(const float4*)&Bs[kk][cgrp * 4];
            acc[0][0] += av.x * bv.x; acc[0][1] += av.x * bv.y; acc[0][2] += av.x * bv.z; acc[0][3] += av.x * bv.w;
            acc[1][0] += av.y * bv.x; acc[1][1] += av.y * bv.y; acc[1][2] += av.y * bv.z; acc[1][3] += av.y * bv.w;
            acc[2][0] += av.z * bv.x; acc[2][1] += av.z * bv.y; acc[2][2] += av.z * bv.z; acc[2][3] += av.z * bv.w;
            acc[3][0] += av.w * bv.x; acc[3][1] += av.w * bv.y; acc[3][2] += av.w * bv.z; acc[3][3] += av.w * bv.w;
        }
        __syncthreads();
    }
    float* dst = pre + (size_t)kh * 294912;
    #pragma unroll
    for (int i = 0; i < 4; ++i) {
        float4 v = { acc[i][0], acc[i][1], acc[i][2], acc[i][3] };
        *(float4*)&dst[(rgrp * 4 + i) * 4608 + vcol0 + cgrp * 4] = v;
    }
}

// ---------------------------------------------------------------------------
// K1c: gate fusion (sums 4 K-quarters) -> h, c; fused L2-norm + bf16 packing.
// grid 64 (one block per batch column b), 256 threads, 2 u per thread.
// ---------------------------------------------------------------------------
__global__ __launch_bounds__(256) void k_gates(
    const float* __restrict__ pre, const float* __restrict__ bias,
    const float* __restrict__ c_tm1, float* __restrict__ out,
    unsigned short* __restrict__ nkf, unsigned short* __restrict__ hbf)
{
    int b = blockIdx.x, t = threadIdx.x;
    const float* p0 = pre + b * 4608;
    const float* p1 = pre + 294912 + b * 4608;
    const float* p2 = pre + 2 * 294912 + b * 4608;
    const float* p3 = pre + 3 * 294912 + b * 4608;
    float hh[2], cc[2];
    #pragma unroll
    for (int q = 0; q < 2; ++q) {
        int u = t + q * 256;
        #define S4(o) (p0[o] + p1[o] + p2[o] + p3[o])
        float xi = S4(u)        + bias[u];
        float xf = S4(512 + u)  + bias[512 + u];
        float xc = S4(1024 + u) + bias[1024 + u];
        float xo = S4(1536 + u) + bias[1536 + u];
        float hi = S4(2048 + u);
        float hf = S4(2560 + u);
        float hc = S4(3072 + u);
        float ho = S4(3584 + u);
        float ri = S4(4096 + u);
        #undef S4
        float ig = hsig(xi + hi + ri);
        float fg = hsig(xf + hf);
        cc[q] = fg * c_tm1[b * 512 + u] + ig * tanhf(xc + hc);
        float og = hsig(xo + ho);
        hh[q] = og * tanhf(cc[q]);
        out[OUT_H + b * 512 + u] = hh[q];
        out[OUT_C + b * 512 + u] = cc[q];
    }
    float ss = hh[0] * hh[0] + hh[1] * hh[1];
    __shared__ float red[4];
    for (int m = 1; m < 64; m <<= 1) ss += __shfl_xor(ss, m);
    if ((t & 63) == 0) red[t >> 6] = ss;
    __syncthreads();
    float tot = red[0] + red[1] + red[2] + red[3];
    float rn = rsqrtf(fmaxf(tot, 1e-12f));
    #pragma unroll
    for (int q = 0; q < 2; ++q) {
        int u = t + q * 256;
        int s = u >> 5, n = b >> 4;
        int lane = (b & 15) + 16 * ((u & 31) >> 3);
        int e = u & 7;
        nkf[(((s * 4 + n) * 64 + lane) << 3) + e] = f2bf(hh[q] * rn);
        int s2 = b >> 5, N = u >> 4;
        int l2 = (u & 15) + 16 * ((b & 31) >> 3);
        int e2 = b & 7;
        hbf[(((s2 * 32 + N) * 64 + l2) << 3) + e2] = f2bf(hh[q]);
    }
}

// ---------------------------------------------------------------------------
// K2: cos GEMM via MFMA bf16 (f32 accum). 64 rows/block, grid 256.
// Fused: row-norm, softmax over batch, c_wr/c_wu, min/argmin partials,
// and c_ww bf16 A-frag production for k_update (bitwise-identical cww).
// ---------------------------------------------------------------------------
__global__ __launch_bounds__(256) void k_cos(
    const float* __restrict__ m_tm1, const unsigned short* __restrict__ nkf,
    const float* __restrict__ cwr_tm1, const float* __restrict__ cwlu_tm1,
    const float* __restrict__ cwu_tm1, const float* __restrict__ wgp,
    float* out, float* __restrict__ pmin, int* __restrict__ pidx,
    unsigned short* __restrict__ cwwf)
{
    __shared__ alignas(16) unsigned short Af[2048 * 8];   // 32 KB (reused for cww frags)
    __shared__ float rn[64];
    __shared__ float pmv[4][64];
    __shared__ int   pmi[4][64];
    const int row0 = blockIdx.x * 64;
    const int tid = threadIdx.x;
    const int w = tid >> 6, lane = tid & 63;
    f32x4 acc[4] = {};
    float ssp[8] = {};

    for (int half = 0; half < 2; ++half) {
        #pragma unroll 2
        for (int i = 0; i < 8; ++i) {
            int r = i * 8 + (tid >> 5);
            int koct = tid & 31;
            const float* src = &m_tm1[(size_t)(row0 + r) * 512 + half * 256 + koct * 8];
            float4 x0 = *(const float4*)src;
            float4 x1 = *(const float4*)&src[4];
            ssp[i] += x0.x*x0.x + x0.y*x0.y + x0.z*x0.z + x0.w*x0.w
                    + x1.x*x1.x + x1.y*x1.y + x1.z*x1.z + x1.w*x1.w;
            int s_l = koct >> 2, rt = r >> 4;
            int ln = ((r & 15) + ((koct & 3) << 4)) ^ (s_l & 7);
            union { unsigned short hx[8]; uint4 v; } pk;
            pk.hx[0] = f2bf(x0.x); pk.hx[1] = f2bf(x0.y);
            pk.hx[2] = f2bf(x0.z); pk.hx[3] = f2bf(x0.w);
            pk.hx[4] = f2bf(x1.x); pk.hx[5] = f2bf(x1.y);
            pk.hx[6] = f2bf(x1.z); pk.hx[7] = f2bf(x1.w);
            *(uint4*)&Af[((s_l * 4 + rt) * 64 + ln) << 3] = pk.v;
        }
        __syncthreads();
        for (int s_l = 0; s_l < 8; ++s_l) {
            int lnx = lane ^ (s_l & 7);
            bf16x8 af = *(const bf16x8*)&Af[((s_l * 4 + w) * 64 + lnx) << 3];
            int s = half * 8 + s_l;
            #pragma unroll
            for (int n = 0; n < 4; ++n) {
                bf16x8 bf = *(const bf16x8*)&nkf[((s * 4 + n) * 64 + lane) << 3];
                acc[n] = __builtin_amdgcn_mfma_f32_16x16x32_bf16(af, bf, acc[n], 0, 0, 0);
            }
        }
        __syncthreads();
    }
    // row sumsq: one reduce per i-slot (both halves accumulated)
    #pragma unroll
    for (int i = 0; i < 8; ++i) {
        float v = ssp[i];
        v += __shfl_xor(v, 1); v += __shfl_xor(v, 2);
        v += __shfl_xor(v, 4); v += __shfl_xor(v, 8);
        v += __shfl_xor(v, 16);
        if ((tid & 31) == 0) rn[i * 8 + (tid >> 5)] = v;
    }
    __syncthreads();

    const float wg = 1.f / (1.f + expf(-wgp[0]));
    const int lhi = lane >> 4, llo = lane & 15;
    float rsq[4];
    #pragma unroll
    for (int reg = 0; reg < 4; ++reg) {
        int rl = w * 16 + lhi * 4 + reg;
        rsq[reg] = rsqrtf(fmaxf(rn[rl], 1e-12f));
    }
    float bmv[4] = { INFINITY, INFINITY, INFINITY, INFINITY };
    int   bmi[4] = { 0x7fffffff, 0x7fffffff, 0x7fffffff, 0x7fffffff };
    #pragma unroll
    for (int reg = 0; reg < 4; ++reg) {
        int r = row0 + w * 16 + lhi * 4 + reg;
        float c0 = acc[0][reg] * rsq[reg];
        float c1 = acc[1][reg] * rsq[reg];
        float c2 = acc[2][reg] * rsq[reg];
        float c3 = acc[3][reg] * rsq[reg];
        float mx = fmaxf(fmaxf(c0, c1), fmaxf(c2, c3));
        mx = fmaxf(mx, __shfl_xor(mx, 1));
        mx = fmaxf(mx, __shfl_xor(mx, 2));
        mx = fmaxf(mx, __shfl_xor(mx, 4));
        mx = fmaxf(mx, __shfl_xor(mx, 8));
        float e0 = expf(c0 - mx), e1 = expf(c1 - mx);
        float e2 = expf(c2 - mx), e3 = expf(c3 - mx);
        float sm = e0 + e1 + e2 + e3;
        sm += __shfl_xor(sm, 1);
        sm += __shfl_xor(sm, 2);
        sm += __shfl_xor(sm, 4);
        sm += __shfl_xor(sm, 8);
        float inv = 1.f / sm;
        float pv[4] = { e0 * inv, e1 * inv, e2 * inv, e3 * inv };
        #pragma unroll
        for (int n = 0; n < 4; ++n) {
            int g = r * 64 + n * 16 + llo;
            float p = pv[n];
            out[OUT_CWR + g] = p;
            float wr = cwr_tm1[g], wl = cwlu_tm1[g], wu = cwu_tm1[g];
            float cww = wg * wr + (1.f - wg) + wl;
            float cwu = 0.95f * wu + p + cww;
            out[OUT_CWU + g] = cwu;
            // c_ww A-frag for k_update: A[row=w*16+(lhi*4+reg)][k=b=n*16+llo]
            {
                int rowl16 = lhi * 4 + reg;
                int s2 = n >> 1;
                int l2 = rowl16 + 16 * (((n & 1) << 1) + (llo >> 3));
                Af[(((s2 * 4 + w) * 64 + l2) << 3) + (llo & 7)] = f2bf(cww);
            }
            if (cwu < bmv[n]) { bmv[n] = cwu; bmi[n] = r; }
        }
    }
    #pragma unroll
    for (int n = 0; n < 4; ++n) {
        #pragma unroll
        for (int mk = 16; mk <= 32; mk <<= 1) {
            float ov = __shfl_xor(bmv[n], mk);
            int   oi = __shfl_xor(bmi[n], mk);
            if (ov < bmv[n] || (ov == bmv[n] && oi < bmi[n])) { bmv[n] = ov; bmi[n] = oi; }
        }
    }
    if (lhi == 0) {
        #pragma unroll
        for (int n = 0; n < 4; ++n) { pmv[w][n * 16 + llo] = bmv[n]; pmi[w][n * 16 + llo] = bmi[n]; }
    }
    __syncthreads();
    // copy the 4096-ushort cww frag block out (coalesced uint4)
    {
        uint4* dst = (uint4*)&cwwf[(size_t)blockIdx.x * 4096];
        const uint4* srcp = (const uint4*)Af;
        dst[tid] = srcp[tid];
        dst[tid + 256] = srcp[tid + 256];
    }
    if (tid < 64) {
        float bv = pmv[0][tid]; int bi = pmi[0][tid];
        #pragma unroll
        for (int q = 1; q < 4; ++q) {
            float v = pmv[q][tid]; int i2 = pmi[q][tid];
            if (v < bv || (v == bv && i2 < bi)) { bv = v; bi = i2; }
        }
        pmin[blockIdx.x * 64 + tid] = bv;
        pidx[blockIdx.x * 64 + tid] = bi;
    }
}

// ---------------------------------------------------------------------------
// K5: read partials via MFMA bf16 + embedded minfinal. (verified round 10)
// grid 512 = 64 row-splits(256 rows) x 8 u-splits(64).
// ---------------------------------------------------------------------------
__global__ __launch_bounds__(256) void k_read_part(
    const float* __restrict__ m_tm1, const float* __restrict__ cwr,
    float* __restrict__ part,
    const float* __restrict__ pmin, const int* __restrict__ pidx,
    float* __restrict__ minf, int* __restrict__ idxf)
{
    __shared__ alignas(16) unsigned short Mf[8192];
    __shared__ alignas(16) unsigned short Cf[8192];
    __shared__ float sv[4]; __shared__ int si[4];
    const int bid = blockIdx.x;
    const int tid = threadIdx.x;
    if (bid < 64) {
        int col = bid;
        float bv = pmin[tid * 64 + col];
        int   bi = pidx[tid * 64 + col];
        for (int mk = 1; mk < 64; mk <<= 1) {
            float ov = __shfl_xor(bv, mk);
            int   oi = __shfl_xor(bi, mk);
            if (ov < bv || (ov == bv && oi < bi)) { bv = ov; bi = oi; }
        }
        if ((tid & 63) == 0) { sv[tid >> 6] = bv; si[tid >> 6] = bi; }
        __syncthreads();
        if (tid == 0) {
            #pragma unroll
            for (int q = 1; q < 4; ++q) {
                if (sv[q] < bv || (sv[q] == bv && si[q] < bi)) { bv = sv[q]; bi = si[q]; }
            }
            minf[col] = bv; idxf[col] = bi;
        }
    }
    const int rs = bid >> 3, us = bid & 7;
    const int row0 = rs * 256, u0 = us * 64;
    const int w = tid >> 6, lane = tid & 63;
    f32x4 acc[4] = {};
    for (int ch = 0; ch < 2; ++ch) {
        const int r0 = row0 + ch * 128;
        __syncthreads();
        #pragma unroll
        for (int q = 0; q < 8; ++q) {
            int idx = q * 1024 + tid * 4;
            int rr = idx >> 6, cc = idx & 63;
            float4 mv = *(const float4*)&m_tm1[(size_t)(r0 + rr) * 512 + u0 + cc];
            float4 cv = *(const float4*)&cwr[(r0 + rr) * 64 + cc];
            int s = rr >> 5, e = rr & 7, lo = 16 * ((rr & 31) >> 3);
            float mvs[4] = { mv.x, mv.y, mv.z, mv.w };
            float cvs[4] = { cv.x, cv.y, cv.z, cv.w };
            #pragma unroll
            for (int i = 0; i < 4; ++i) {
                int col = cc + i;
                int ln = (col & 15) + lo;
                int t4 = col >> 4;
                int slot = (((s * 4 + t4) * 64 + ln) << 3) + e;
                Mf[slot] = f2bf(mvs[i]);
                Cf[slot] = f2bf(cvs[i]);
            }
        }
        __syncthreads();
        #pragma unroll
        for (int s = 0; s < 4; ++s) {
            bf16x8 bf = *(const bf16x8*)&Mf[((s * 4 + w) * 64 + lane) << 3];
            #pragma unroll
            for (int tb = 0; tb < 4; ++tb) {
                bf16x8 af = *(const bf16x8*)&Cf[((s * 4 + tb) * 64 + lane) << 3];
                acc[tb] = __builtin_amdgcn_mfma_f32_16x16x32_bf16(af, bf, acc[tb], 0, 0, 0);
            }
        }
    }
    const int lhi = lane >> 4, llo = lane & 15;
    #pragma unroll
    for (int tb = 0; tb < 4; ++tb) {
        #pragma unroll
        for (int reg = 0; reg < 4; ++reg) {
            int b = tb * 16 + lhi * 4 + reg;
            part[(size_t)rs * 32768 + b * 512 + u0 + w * 16 + llo] = acc[tb][reg];
        }
    }
}

// ---------------------------------------------------------------------------
// K4: c_wlu compare + keep mask + m = m_tm1*keep + c_ww @ h via MFMA bf16.
// A-frags (c_ww) pre-packed by k_cos; embedded read-final (us==1 blocks).
// grid 1024 = 256 row-blocks(64) x 4 u-splits(128).
// ---------------------------------------------------------------------------
__global__ __launch_bounds__(256) void k_update(
    const float* __restrict__ m_tm1, const unsigned short* __restrict__ cwwf,
    const unsigned short* __restrict__ hbf,
    const float* __restrict__ minf, const int* __restrict__ idxf,
    const float* __restrict__ rpart, float* out)
{
    __shared__ float keepf[64];
    __shared__ float minS[64];
    __shared__ int   idxS[64];
    const int rb = blockIdx.x >> 2, us = blockIdx.x & 3;
    const int row0 = rb * 64, u0 = us * 128;
    const int tid = threadIdx.x;
    const int w = tid >> 6, lane = tid & 63;
    const int lhi = lane >> 4, llo = lane & 15;
    if (tid < 64) { idxS[tid] = idxf[tid]; minS[tid] = minf[tid]; }
    __syncthreads();
    if (tid < 64) {
        int gr = row0 + tid;
        float f = 1.f;
        #pragma unroll
        for (int b = 0; b < 64; ++b) if (idxS[b] == gr) f = 0.f;
        keepf[tid] = f;
    }
    __syncthreads();
    if (us == 0) {
        #pragma unroll
        for (int q = 0; q < 4; ++q) {
            int idx = q * 1024 + tid * 4;
            int r = idx >> 6, b = idx & 63;
            int g = (row0 + r) * 64 + b;
            float4 cu = *(const float4*)&out[OUT_CWU + g];
            float4 res;
            res.x = (cu.x <= minS[b + 0]) ? 1.f : 0.f;
            res.y = (cu.y <= minS[b + 1]) ? 1.f : 0.f;
            res.z = (cu.z <= minS[b + 2]) ? 1.f : 0.f;
            res.w = (cu.w <= minS[b + 3]) ? 1.f : 0.f;
            *(float4*)&out[OUT_CWLU + g] = res;
        }
    } else if (us == 1) {
        if (tid < 128) {
            int gid = rb * 128 + tid;
            float s = 0.f;
            #pragma unroll 8
            for (int rs = 0; rs < 64; ++rs) s += rpart[(size_t)rs * 32768 + gid];
            out[OUT_READ + gid] = s;
        }
    }
    f32x4 acc[8];
    #pragma unroll
    for (int nt = 0; nt < 8; ++nt) {
        #pragma unroll
        for (int reg = 0; reg < 4; ++reg) {
            int rowl = w * 16 + lhi * 4 + reg;
            acc[nt][reg] = m_tm1[(size_t)(row0 + rowl) * 512 + u0 + nt * 16 + llo]
                         * keepf[rowl];
        }
    }
    #pragma unroll
    for (int s = 0; s < 2; ++s) {
        bf16x8 af = *(const bf16x8*)&cwwf[(size_t)rb * 4096 + (((s * 4 + w) * 64 + lane) << 3)];
        #pragma unroll
        for (int nt = 0; nt < 8; ++nt) {
            int N = (u0 >> 4) + nt;
            bf16x8 bf = *(const bf16x8*)&hbf[((s * 32 + N) * 64 + lane) << 3];
            acc[nt] = __builtin_amdgcn_mfma_f32_16x16x32_bf16(af, bf, acc[nt], 0, 0, 0);
        }
    }
    #pragma unroll
    for (int nt = 0; nt < 8; ++nt) {
        #pragma unroll
        for (int reg = 0; reg < 4; ++reg) {
            int rowl = w * 16 + lhi * 4 + reg;
            out[OUT_M + (size_t)(row0 + rowl) * 512 + u0 + nt * 16 + llo] = acc[nt][reg];
        }
    }
}

extern "C" void kernel_launch(void* const* d_in, const int* in_sizes, int n_in,
                              void* d_out, int out_size, void* d_ws, size_t ws_size,
                              hipStream_t stream)
{
    const float* inputs    = (const float*)d_in[0];
    const float* h_tm1     = (const float*)d_in[1];
    const float* c_tm1     = (const float*)d_in[2];
    const float* r_tm1     = (const float*)d_in[3];
    const float* m_tm1     = (const float*)d_in[4];
    const float* c_wu_tm1  = (const float*)d_in[5];
    const float* c_wlu_tm1 = (const float*)d_in[6];
    const float* c_wr_tm1  = (const float*)d_in[7];
    const float* wk        = (const float*)d_in[8];
    const float* rk        = (const float*)d_in[9];
    const float* bias      = (const float*)d_in[10];
    const float* wgate     = (const float*)d_in[11];
    float* out = (float*)d_out;
    float* ws  = (float*)d_ws;
    float* pre = out + OUT_M;   // scratch in OUT_M region; consumed by k_gates
    unsigned short* nkf  = (unsigned short*)(ws + WS_NKF);
    unsigned short* hbf  = (unsigned short*)(ws + WS_HBF);
    unsigned short* cwwf = (unsigned short*)(ws + WS_CWWF);
    float* rpart = ws + WS_RPART;

    k_preact<<<288, 256, 0, stream>>>(inputs, h_tm1, r_tm1, wk, rk, pre);
    k_gates<<<64, 256, 0, stream>>>(pre, bias, c_tm1, out, nkf, hbf);
    k_cos<<<256, 256, 0, stream>>>(m_tm1, nkf, c_wr_tm1, c_wlu_tm1,
                                   c_wu_tm1, wgate, out, ws + WS_PMIN,
                                   (int*)(ws + WS_PIDX), cwwf);
    k_read_part<<<512, 256, 0, stream>>>(m_tm1, out + OUT_CWR, rpart,
                                         ws + WS_PMIN, (const int*)(ws + WS_PIDX),
                                         ws + WS_MINF, (int*)(ws + WS_IDXF));
    k_update<<<1024, 256, 0, stream>>>(m_tm1, cwwf, hbf,
                                       ws + WS_MINF, (const int*)(ws + WS_IDXF),
                                       rpart, out);
}

// Round 14
// 66.284 us; speedup vs baseline: 2.1100x; 1.0038x over previous
//
#include <hip/hip_runtime.h>
#include <math.h>

// Problem dims: UNITS=512, MEM=16384, BATCH=64
// d_out offsets (floats): h, c, read, m, c_wu, c_wlu, c_wr
#define OUT_H    0
#define OUT_C    32768
#define OUT_READ 65536
#define OUT_M    98304
#define OUT_CWU  8486912
#define OUT_CWLU 9535488
#define OUT_CWR  10584064

// preact scratch (4*294912 floats) lives in OUT_M region, consumed by k_gates
// before k_update overwrites m. Everything else in d_ws (ws_size ~268MB).
// ws offsets (floats) — ushort buffers: floats = ushort_count/2 (CHECKED):
//   nkf  32768 ush = 16384 fl: [0,16384)
//   hbf  32768 ush = 16384 fl: [16384,32768)
//   cwwf 256*4096 ush = 524288 fl: [65664,589952)
//   cwrf 256*4096 ush = 524288 fl: [589952,1114240)
//   rpart 2M fl: [1114240,3211520)
#define WS_NKF   0
#define WS_HBF   16384
#define WS_PMIN  32768      // 256*64 partial min values
#define WS_PIDX  49152      // 256*64 partial min indices (int)
#define WS_MINF  65536      // 64 final min
#define WS_IDXF  65600      // 64 final argmin (int)
#define WS_CWWF  65664
#define WS_CWRF  589952
#define WS_RPART 1114240

typedef short bf16x8 __attribute__((ext_vector_type(8)));
typedef float f32x4  __attribute__((ext_vector_type(4)));

__device__ __forceinline__ float hsig(float x) {
    return fminf(fmaxf(0.2f * x + 0.5f, 0.f), 1.f);
}
__device__ __forceinline__ unsigned short f2bf(float x) {
    unsigned u = __float_as_uint(x);
    return (unsigned short)((u + 0x7fffu + ((u >> 16) & 1u)) >> 16);
}

// ---------------------------------------------------------------------------
// K1: preactivations. Virtual col space 4608 = [x:2048 | hk:2048 | r_i:512]
// grid 288 = 72 col-tiles(64) x 4 K-quarters(128). Block 256, thread 4r x 4c.
// ---------------------------------------------------------------------------
__global__ __launch_bounds__(256) void k_preact(
    const float* __restrict__ inputs, const float* __restrict__ h_tm1,
    const float* __restrict__ r_tm1, const float* __restrict__ wk,
    const float* __restrict__ rk, float* __restrict__ pre)
{
    __shared__ alignas(16) float Ast[32][68];   // [k][row 0..63 + pad]
    __shared__ alignas(16) float Bs[32][72];    // [k][col]
    const int cb = blockIdx.x % 72, kh = blockIdx.x / 72;
    const int vcol0 = cb * 64;
    const float* A; const float* W; int wstride, wcol0;
    if (vcol0 < 2048)      { A = inputs; W = wk; wstride = 2048; wcol0 = vcol0; }
    else if (vcol0 < 4096) { A = h_tm1;  W = rk; wstride = 2560; wcol0 = vcol0 - 2048; }
    else                   { A = r_tm1;  W = rk; wstride = 2560; wcol0 = 2048 + (vcol0 - 4096); }
    const int tid = threadIdx.x;
    const int rgrp = tid >> 4, cgrp = tid & 15;
    const int srow = tid >> 2, sk = (tid & 3) * 4;
    const int skk = tid >> 3, sc = (tid & 7) * 4;
    float acc[4][4] = {};
    for (int t = 0; t < 4; ++t) {
        const int k0 = kh * 128 + t * 32;
        float4 a0 = *(const float4*)&A[srow * 512 + k0 + sk];
        float4 a1 = *(const float4*)&A[srow * 512 + k0 + 16 + sk];
        float4 w0 = *(const float4*)&W[(size_t)(k0 + skk) * wstride + wcol0 + sc];
        float4 w1 = *(const float4*)&W[(size_t)(k0 + skk) * wstride + wcol0 + 32 + sc];
        Ast[sk + 0][srow] = a0.x; Ast[sk + 1][srow] = a0.y;
        Ast[sk + 2][srow] = a0.z; Ast[sk + 3][srow] = a0.w;
        Ast[16 + sk + 0][srow] = a1.x; Ast[16 + sk + 1][srow] = a1.y;
        Ast[16 + sk + 2][srow] = a1.z; Ast[16 + sk + 3][srow] = a1.w;
        Bs[skk][sc + 0] = w0.x; Bs[skk][sc + 1] = w0.y;
        Bs[skk][sc + 2] = w0.z; Bs[skk][sc + 3] = w0.w;
        Bs[skk][32 + sc + 0] = w1.x; Bs[skk][32 + sc + 1] = w1.y;
        Bs[skk][32 + sc + 2] = w1.z; Bs[skk][32 + sc + 3] = w1.w;
        __syncthreads();
        #pragma unroll
        for (int kk = 0; kk < 32; ++kk) {
            float4 av = *(const float4*)&Ast[kk][rgrp * 4];
            float4 bv = *(const float4*)&Bs[kk][cgrp * 4];
            acc[0][0] += av.x * bv.x; acc[0][1] += av.x * bv.y; acc[0][2] += av.x * bv.z; acc[0][3] += av.x * bv.w;
            acc[1][0] += av.y * bv.x; acc[1][1] += av.y * bv.y; acc[1][2] += av.y * bv.z; acc[1][3] += av.y * bv.w;
            acc[2][0] += av.z * bv.x; acc[2][1] += av.z * bv.y; acc[2][2] += av.z * bv.z; acc[2][3] += av.z * bv.w;
            acc[3][0] += av.w * bv.x; acc[3][1] += av.w * bv.y; acc[3][2] += av.w * bv.z; acc[3][3] += av.w * bv.w;
        }
        __syncthreads();
    }
    float* dst = pre + (size_t)kh * 294912;
    #pragma unroll
    for (int i = 0; i < 4; ++i) {
        float4 v = { acc[i][0], acc[i][1], acc[i][2], acc[i][3] };
        *(float4*)&dst[(rgrp * 4 + i) * 4608 + vcol0 + cgrp * 4] = v;
    }
}

// ---------------------------------------------------------------------------
// K1c: gate fusion (sums 4 K-quarters) -> h, c; fused L2-norm + bf16 packing.
// grid 64 (one block per batch column b), 256 threads, 2 u per thread.
// ---------------------------------------------------------------------------
__global__ __launch_bounds__(256) void k_gates(
    const float* __restrict__ pre, const float* __restrict__ bias,
    const float* __restrict__ c_tm1, float* __restrict__ out,
    unsigned short* __restrict__ nkf, unsigned short* __restrict__ hbf)
{
    int b = blockIdx.x, t = threadIdx.x;
    const float* p0 = pre + b * 4608;
    const float* p1 = pre + 294912 + b * 4608;
    const float* p2 = pre + 2 * 294912 + b * 4608;
    const float* p3 = pre + 3 * 294912 + b * 4608;
    float hh[2], cc[2];
    #pragma unroll
    for (int q = 0; q < 2; ++q) {
        int u = t + q * 256;
        #define S4(o) (p0[o] + p1[o] + p2[o] + p3[o])
        float xi = S4(u)        + bias[u];
        float xf = S4(512 + u)  + bias[512 + u];
        float xc = S4(1024 + u) + bias[1024 + u];
        float xo = S4(1536 + u) + bias[1536 + u];
        float hi = S4(2048 + u);
        float hf = S4(2560 + u);
        float hc = S4(3072 + u);
        float ho = S4(3584 + u);
        float ri = S4(4096 + u);
        #undef S4
        float ig = hsig(xi + hi + ri);
        float fg = hsig(xf + hf);
        cc[q] = fg * c_tm1[b * 512 + u] + ig * tanhf(xc + hc);
        float og = hsig(xo + ho);
        hh[q] = og * tanhf(cc[q]);
        out[OUT_H + b * 512 + u] = hh[q];
        out[OUT_C + b * 512 + u] = cc[q];
    }
    float ss = hh[0] * hh[0] + hh[1] * hh[1];
    __shared__ float red[4];
    for (int m = 1; m < 64; m <<= 1) ss += __shfl_xor(ss, m);
    if ((t & 63) == 0) red[t >> 6] = ss;
    __syncthreads();
    float tot = red[0] + red[1] + red[2] + red[3];
    float rn = rsqrtf(fmaxf(tot, 1e-12f));
    #pragma unroll
    for (int q = 0; q < 2; ++q) {
        int u = t + q * 256;
        int s = u >> 5, n = b >> 4;
        int lane = (b & 15) + 16 * ((u & 31) >> 3);
        int e = u & 7;
        nkf[(((s * 4 + n) * 64 + lane) << 3) + e] = f2bf(hh[q] * rn);
        int s2 = b >> 5, N = u >> 4;
        int l2 = (u & 15) + 16 * ((b & 31) >> 3);
        int e2 = b & 7;
        hbf[(((s2 * 32 + N) * 64 + l2) << 3) + e2] = f2bf(hh[q]);
    }
}

// ---------------------------------------------------------------------------
// K2: cos GEMM via MFMA bf16 (f32 accum). 64 rows/block, grid 256.
// Fused: row-norm, softmax over batch, c_wr/c_wu, min/argmin partials,
// c_ww A-frags (for k_update) AND c_wr A-frags (for k_read_part).
// ---------------------------------------------------------------------------
__global__ __launch_bounds__(256) void k_cos(
    const float* __restrict__ m_tm1, const unsigned short* __restrict__ nkf,
    const float* __restrict__ cwr_tm1, const float* __restrict__ cwlu_tm1,
    const float* __restrict__ cwu_tm1, const float* __restrict__ wgp,
    float* out, float* __restrict__ pmin, int* __restrict__ pidx,
    unsigned short* __restrict__ cwwf, unsigned short* __restrict__ cwrf)
{
    __shared__ alignas(16) unsigned short Af[2048 * 8];   // 32 KB (reused: [0,4096)=cww frags, [4096,8192)=cwr frags)
    __shared__ float rn[64];
    __shared__ float pmv[4][64];
    __shared__ int   pmi[4][64];
    const int row0 = blockIdx.x * 64;
    const int tid = threadIdx.x;
    const int w = tid >> 6, lane = tid & 63;
    f32x4 acc[4] = {};
    float ssp[8] = {};

    for (int half = 0; half < 2; ++half) {
        #pragma unroll 2
        for (int i = 0; i < 8; ++i) {
            int r = i * 8 + (tid >> 5);
            int koct = tid & 31;
            const float* src = &m_tm1[(size_t)(row0 + r) * 512 + half * 256 + koct * 8];
            float4 x0 = *(const float4*)src;
            float4 x1 = *(const float4*)&src[4];
            ssp[i] += x0.x*x0.x + x0.y*x0.y + x0.z*x0.z + x0.w*x0.w
                    + x1.x*x1.x + x1.y*x1.y + x1.z*x1.z + x1.w*x1.w;
            int s_l = koct >> 2, rt = r >> 4;
            int ln = ((r & 15) + ((koct & 3) << 4)) ^ (s_l & 7);
            union { unsigned short hx[8]; uint4 v; } pk;
            pk.hx[0] = f2bf(x0.x); pk.hx[1] = f2bf(x0.y);
            pk.hx[2] = f2bf(x0.z); pk.hx[3] = f2bf(x0.w);
            pk.hx[4] = f2bf(x1.x); pk.hx[5] = f2bf(x1.y);
            pk.hx[6] = f2bf(x1.z); pk.hx[7] = f2bf(x1.w);
            *(uint4*)&Af[((s_l * 4 + rt) * 64 + ln) << 3] = pk.v;
        }
        __syncthreads();
        for (int s_l = 0; s_l < 8; ++s_l) {
            int lnx = lane ^ (s_l & 7);
            bf16x8 af = *(const bf16x8*)&Af[((s_l * 4 + w) * 64 + lnx) << 3];
            int s = half * 8 + s_l;
            #pragma unroll
            for (int n = 0; n < 4; ++n) {
                bf16x8 bf = *(const bf16x8*)&nkf[((s * 4 + n) * 64 + lane) << 3];
                acc[n] = __builtin_amdgcn_mfma_f32_16x16x32_bf16(af, bf, acc[n], 0, 0, 0);
            }
        }
        __syncthreads();
    }
    // row sumsq: one reduce per i-slot (both halves accumulated)
    #pragma unroll
    for (int i = 0; i < 8; ++i) {
        float v = ssp[i];
        v += __shfl_xor(v, 1); v += __shfl_xor(v, 2);
        v += __shfl_xor(v, 4); v += __shfl_xor(v, 8);
        v += __shfl_xor(v, 16);
        if ((tid & 31) == 0) rn[i * 8 + (tid >> 5)] = v;
    }
    __syncthreads();

    const float wg = 1.f / (1.f + expf(-wgp[0]));
    const int lhi = lane >> 4, llo = lane & 15;
    float rsq[4];
    #pragma unroll
    for (int reg = 0; reg < 4; ++reg) {
        int rl = w * 16 + lhi * 4 + reg;
        rsq[reg] = rsqrtf(fmaxf(rn[rl], 1e-12f));
    }
    float bmv[4] = { INFINITY, INFINITY, INFINITY, INFINITY };
    int   bmi[4] = { 0x7fffffff, 0x7fffffff, 0x7fffffff, 0x7fffffff };
    #pragma unroll
    for (int reg = 0; reg < 4; ++reg) {
        int rl = w * 16 + lhi * 4 + reg;   // r_local in [0,64)
        int r = row0 + rl;
        float c0 = acc[0][reg] * rsq[reg];
        float c1 = acc[1][reg] * rsq[reg];
        float c2 = acc[2][reg] * rsq[reg];
        float c3 = acc[3][reg] * rsq[reg];
        float mx = fmaxf(fmaxf(c0, c1), fmaxf(c2, c3));
        mx = fmaxf(mx, __shfl_xor(mx, 1));
        mx = fmaxf(mx, __shfl_xor(mx, 2));
        mx = fmaxf(mx, __shfl_xor(mx, 4));
        mx = fmaxf(mx, __shfl_xor(mx, 8));
        float e0 = expf(c0 - mx), e1 = expf(c1 - mx);
        float e2 = expf(c2 - mx), e3 = expf(c3 - mx);
        float sm = e0 + e1 + e2 + e3;
        sm += __shfl_xor(sm, 1);
        sm += __shfl_xor(sm, 2);
        sm += __shfl_xor(sm, 4);
        sm += __shfl_xor(sm, 8);
        float inv = 1.f / sm;
        float pv[4] = { e0 * inv, e1 * inv, e2 * inv, e3 * inv };
        #pragma unroll
        for (int n = 0; n < 4; ++n) {
            int g = r * 64 + n * 16 + llo;
            float p = pv[n];
            out[OUT_CWR + g] = p;
            float wr = cwr_tm1[g], wl = cwlu_tm1[g], wu = cwu_tm1[g];
            float cww = wg * wr + (1.f - wg) + wl;
            float cwu = 0.95f * wu + p + cww;
            out[OUT_CWU + g] = cwu;
            // c_ww A-frag for k_update: A[row=rl][k=b=n*16+llo]
            {
                int rowl16 = lhi * 4 + reg;
                int s2 = n >> 1;
                int l2 = rowl16 + 16 * (((n & 1) << 1) + (llo >> 3));
                Af[(((s2 * 4 + w) * 64 + l2) << 3) + (llo & 7)] = f2bf(cww);
            }
            // c_wr A-frag for k_read_part: A[row=b=n*16+llo][k=rl]
            {
                int sA = rl >> 5;
                int lf = llo + 16 * ((rl & 31) >> 3);
                Af[4096 + (((sA * 4 + n) * 64 + lf) << 3) + (rl & 7)] = f2bf(p);
            }
            if (cwu < bmv[n]) { bmv[n] = cwu; bmi[n] = r; }
        }
    }
    #pragma unroll
    for (int n = 0; n < 4; ++n) {
        #pragma unroll
        for (int mk = 16; mk <= 32; mk <<= 1) {
            float ov = __shfl_xor(bmv[n], mk);
            int   oi = __shfl_xor(bmi[n], mk);
            if (ov < bmv[n] || (ov == bmv[n] && oi < bmi[n])) { bmv[n] = ov; bmi[n] = oi; }
        }
    }
    if (lhi == 0) {
        #pragma unroll
        for (int n = 0; n < 4; ++n) { pmv[w][n * 16 + llo] = bmv[n]; pmi[w][n * 16 + llo] = bmi[n]; }
    }
    __syncthreads();
    // copy both 4096-ushort frag blocks out (coalesced uint4)
    {
        uint4* dstW = (uint4*)&cwwf[(size_t)blockIdx.x * 4096];
        uint4* dstR = (uint4*)&cwrf[(size_t)blockIdx.x * 4096];
        const uint4* srcp = (const uint4*)Af;
        dstW[tid]       = srcp[tid];
        dstW[tid + 256] = srcp[tid + 256];
        dstR[tid]       = srcp[512 + tid];
        dstR[tid + 256] = srcp[512 + tid + 256];
    }
    if (tid < 64) {
        float bv = pmv[0][tid]; int bi = pmi[0][tid];
        #pragma unroll
        for (int q = 1; q < 4; ++q) {
            float v = pmv[q][tid]; int i2 = pmi[q][tid];
            if (v < bv || (v == bv && i2 < bi)) { bv = v; bi = i2; }
        }
        pmin[blockIdx.x * 64 + tid] = bv;
        pidx[blockIdx.x * 64 + tid] = bi;
    }
}

// ---------------------------------------------------------------------------
// K5: read partials via MFMA bf16 + embedded minfinal.
// grid 512 = 64 row-splits(256 rows) x 8 u-splits(64).
// A-frags (cwr) pre-packed by k_cos (cwrf, L2-hot); only m staged in LDS.
// ---------------------------------------------------------------------------
__global__ __launch_bounds__(256) void k_read_part(
    const float* __restrict__ m_tm1, const unsigned short* __restrict__ cwrf,
    float* __restrict__ part,
    const float* __restrict__ pmin, const int* __restrict__ pidx,
    float* __restrict__ minf, int* __restrict__ idxf)
{
    __shared__ alignas(16) unsigned short Mf[8192];   // 16 KB: m B-frags
    __shared__ float sv[4]; __shared__ int si[4];
    const int bid = blockIdx.x;
    const int tid = threadIdx.x;
    if (bid < 64) {   // embedded minfinal (block-uniform branch)
        int col = bid;
        float bv = pmin[tid * 64 + col];
        int   bi = pidx[tid * 64 + col];
        for (int mk = 1; mk < 64; mk <<= 1) {
            float ov = __shfl_xor(bv, mk);
            int   oi = __shfl_xor(bi, mk);
            if (ov < bv || (ov == bv && oi < bi)) { bv = ov; bi = oi; }
        }
        if ((tid & 63) == 0) { sv[tid >> 6] = bv; si[tid >> 6] = bi; }
        __syncthreads();
        if (tid == 0) {
            #pragma unroll
            for (int q = 1; q < 4; ++q) {
                if (sv[q] < bv || (sv[q] == bv && si[q] < bi)) { bv = sv[q]; bi = si[q]; }
            }
            minf[col] = bv; idxf[col] = bi;
        }
    }
    const int rs = bid >> 3, us = bid & 7;
    const int row0 = rs * 256, u0 = us * 64;
    const int w = tid >> 6, lane = tid & 63;
    f32x4 acc[4] = {};
    for (int ch = 0; ch < 2; ++ch) {
        const int r0 = row0 + ch * 128;
        __syncthreads();
        #pragma unroll
        for (int q = 0; q < 8; ++q) {
            int idx = q * 1024 + tid * 4;
            int rr = idx >> 6, cc = idx & 63;
            float4 mv = *(const float4*)&m_tm1[(size_t)(r0 + rr) * 512 + u0 + cc];
            int s = rr >> 5, e = rr & 7, lo = 16 * ((rr & 31) >> 3);
            float mvs[4] = { mv.x, mv.y, mv.z, mv.w };
            #pragma unroll
            for (int i = 0; i < 4; ++i) {
                int col = cc + i;
                int ln = (col & 15) + lo;
                int t4 = col >> 4;
                Mf[(((s * 4 + t4) * 64 + ln) << 3) + e] = f2bf(mvs[i]);
            }
        }
        __syncthreads();
        const int sgbase = rs * 8 + ch * 4;
        #pragma unroll
        for (int s = 0; s < 4; ++s) {
            bf16x8 bf = *(const bf16x8*)&Mf[((s * 4 + w) * 64 + lane) << 3];
            #pragma unroll
            for (int tb = 0; tb < 4; ++tb) {
                bf16x8 af = *(const bf16x8*)&cwrf[(size_t)((((sgbase + s) * 4 + tb) * 64 + lane)) << 3];
                acc[tb] = __builtin_amdgcn_mfma_f32_16x16x32_bf16(af, bf, acc[tb], 0, 0, 0);
            }
        }
    }
    const int lhi = lane >> 4, llo = lane & 15;
    #pragma unroll
    for (int tb = 0; tb < 4; ++tb) {
        #pragma unroll
        for (int reg = 0; reg < 4; ++reg) {
            int b = tb * 16 + lhi * 4 + reg;
            part[(size_t)rs * 32768 + b * 512 + u0 + w * 16 + llo] = acc[tb][reg];
        }
    }
}

// ---------------------------------------------------------------------------
// K4: c_wlu compare + keep mask + m = m_tm1*keep + c_ww @ h via MFMA bf16.
// A-frags (c_ww) pre-packed by k_cos; embedded read-final (us==1 blocks).
// grid 1024 = 256 row-blocks(64) x 4 u-splits(128).
// ---------------------------------------------------------------------------
__global__ __launch_bounds__(256) void k_update(
    const float* __restrict__ m_tm1, const unsigned short* __restrict__ cwwf,
    const unsigned short* __restrict__ hbf,
    const float* __restrict__ minf, const int* __restrict__ idxf,
    const float* __restrict__ rpart, float* out)
{
    __shared__ float keepf[64];
    __shared__ float minS[64];
    __shared__ int   idxS[64];
    const int rb = blockIdx.x >> 2, us = blockIdx.x & 3;
    const int row0 = rb * 64, u0 = us * 128;
    const int tid = threadIdx.x;
    const int w = tid >> 6, lane = tid & 63;
    const int lhi = lane >> 4, llo = lane & 15;
    if (tid < 64) { idxS[tid] = idxf[tid]; minS[tid] = minf[tid]; }
    __syncthreads();
    if (tid < 64) {
        int gr = row0 + tid;
        float f = 1.f;
        #pragma unroll
        for (int b = 0; b < 64; ++b) if (idxS[b] == gr) f = 0.f;
        keepf[tid] = f;
    }
    __syncthreads();
    if (us == 0) {
        #pragma unroll
        for (int q = 0; q < 4; ++q) {
            int idx = q * 1024 + tid * 4;
            int r = idx >> 6, b = idx & 63;
            int g = (row0 + r) * 64 + b;
            float4 cu = *(const float4*)&out[OUT_CWU + g];
            float4 res;
            res.x = (cu.x <= minS[b + 0]) ? 1.f : 0.f;
            res.y = (cu.y <= minS[b + 1]) ? 1.f : 0.f;
            res.z = (cu.z <= minS[b + 2]) ? 1.f : 0.f;
            res.w = (cu.w <= minS[b + 3]) ? 1.f : 0.f;
            *(float4*)&out[OUT_CWLU + g] = res;
        }
    } else if (us == 1) {
        if (tid < 128) {
            int gid = rb * 128 + tid;
            float s = 0.f;
            #pragma unroll 8
            for (int rs = 0; rs < 64; ++rs) s += rpart[(size_t)rs * 32768 + gid];
            out[OUT_READ + gid] = s;
        }
    }
    f32x4 acc[8];
    #pragma unroll
    for (int nt = 0; nt < 8; ++nt) {
        #pragma unroll
        for (int reg = 0; reg < 4; ++reg) {
            int rowl = w * 16 + lhi * 4 + reg;
            acc[nt][reg] = m_tm1[(size_t)(row0 + rowl) * 512 + u0 + nt * 16 + llo]
                         * keepf[rowl];
        }
    }
    #pragma unroll
    for (int s = 0; s < 2; ++s) {
        bf16x8 af = *(const bf16x8*)&cwwf[(size_t)rb * 4096 + (((s * 4 + w) * 64 + lane) << 3)];
        #pragma unroll
        for (int nt = 0; nt < 8; ++nt) {
            int N = (u0 >> 4) + nt;
            bf16x8 bf = *(const bf16x8*)&hbf[((s * 32 + N) * 64 + lane) << 3];
            acc[nt] = __builtin_amdgcn_mfma_f32_16x16x32_bf16(af, bf, acc[nt], 0, 0, 0);
        }
    }
    #pragma unroll
    for (int nt = 0; nt < 8; ++nt) {
        #pragma unroll
        for (int reg = 0; reg < 4; ++reg) {
            int rowl = w * 16 + lhi * 4 + reg;
            out[OUT_M + (size_t)(row0 + rowl) * 512 + u0 + nt * 16 + llo] = acc[nt][reg];
        }
    }
}

extern "C" void kernel_launch(void* const* d_in, const int* in_sizes, int n_in,
                              void* d_out, int out_size, void* d_ws, size_t ws_size,
                              hipStream_t stream)
{
    const float* inputs    = (const float*)d_in[0];
    const float* h_tm1     = (const float*)d_in[1];
    const float* c_tm1     = (const float*)d_in[2];
    const float* r_tm1     = (const float*)d_in[3];
    const float* m_tm1     = (const float*)d_in[4];
    const float* c_wu_tm1  = (const float*)d_in[5];
    const float* c_wlu_tm1 = (const float*)d_in[6];
    const float* c_wr_tm1  = (const float*)d_in[7];
    const float* wk        = (const float*)d_in[8];
    const float* rk        = (const float*)d_in[9];
    const float* bias      = (const float*)d_in[10];
    const float* wgate     = (const float*)d_in[11];
    float* out = (float*)d_out;
    float* ws  = (float*)d_ws;
    float* pre = out + OUT_M;   // scratch in OUT_M region; consumed by k_gates
    unsigned short* nkf  = (unsigned short*)(ws + WS_NKF);
    unsigned short* hbf  = (unsigned short*)(ws + WS_HBF);
    unsigned short* cwwf = (unsigned short*)(ws + WS_CWWF);
    unsigned short* cwrf = (unsigned short*)(ws + WS_CWRF);
    float* rpart = ws + WS_RPART;

    k_preact<<<288, 256, 0, stream>>>(inputs, h_tm1, r_tm1, wk, rk, pre);
    k_gates<<<64, 256, 0, stream>>>(pre, bias, c_tm1, out, nkf, hbf);
    k_cos<<<256, 256, 0, stream>>>(m_tm1, nkf, c_wr_tm1, c_wlu_tm1,
                                   c_wu_tm1, wgate, out, ws + WS_PMIN,
                                   (int*)(ws + WS_PIDX), cwwf, cwrf);
    k_read_part<<<512, 256, 0, stream>>>(m_tm1, cwrf, rpart,
                                         ws + WS_PMIN, (const int*)(ws + WS_PIDX),
                                         ws + WS_MINF, (int*)(ws + WS_IDXF));
    k_update<<<1024, 256, 0, stream>>>(m_tm1, cwwf, hbf,
                                       ws + WS_MINF, (const int*)(ws + WS_IDXF),
                                       rpart, out);
}

// Round 15
// 62.384 us; speedup vs baseline: 2.2419x; 1.0625x over previous
//
#include <hip/hip_runtime.h>
#include <math.h>

// Problem dims: UNITS=512, MEM=16384, BATCH=64
// d_out offsets (floats): h, c, read, m, c_wu, c_wlu, c_wr
#define OUT_H    0
#define OUT_C    32768
#define OUT_READ 65536
#define OUT_M    98304
#define OUT_CWU  8486912
#define OUT_CWLU 9535488
#define OUT_CWR  10584064

// preact scratch (4*294912 floats) lives in OUT_M region, consumed by k_gates
// before k_update overwrites m. Everything else in d_ws (ws_size ~268MB).
// ws offsets (floats) — ushort buffers: floats = ushort_count/2 (CHECKED):
//   nkf  32768 ush = 16384 fl: [0,16384)
//   hbf  32768 ush = 16384 fl: [16384,32768)
//   cwwf 256*4096 ush = 524288 fl: [65664,589952)
//   cwrf 256*4096 ush = 524288 fl: [589952,1114240)
//   rpart 2M fl: [1114240,3211520)
#define WS_NKF   0
#define WS_HBF   16384
#define WS_PMIN  32768      // 256*64 partial min values
#define WS_PIDX  49152      // 256*64 partial min indices (int)
#define WS_MINF  65536      // 64 final min
#define WS_IDXF  65600      // 64 final argmin (int)
#define WS_CWWF  65664
#define WS_CWRF  589952
#define WS_RPART 1114240

typedef short bf16x8 __attribute__((ext_vector_type(8)));
typedef float f32x4  __attribute__((ext_vector_type(4)));

__device__ __forceinline__ float hsig(float x) {
    return fminf(fmaxf(0.2f * x + 0.5f, 0.f), 1.f);
}
__device__ __forceinline__ unsigned short f2bf(float x) {
    unsigned u = __float_as_uint(x);
    return (unsigned short)((u + 0x7fffu + ((u >> 16) & 1u)) >> 16);
}

// ---------------------------------------------------------------------------
// K1: preactivations via MFMA bf16. Virtual col space 4608 =
// [x:2048 | hk:2048 | r_i:512]. grid 288 = 72 col-tiles(64) x 4 K-quarters(128).
// Block: D[b:64][col:64], K=128. Wave w owns row-tile w (16 b-rows).
// A = activations (bf16 A-frags), B = weights (bf16 B-frags), both LDS-staged.
// ---------------------------------------------------------------------------
__global__ __launch_bounds__(256) void k_preact(
    const float* __restrict__ inputs, const float* __restrict__ h_tm1,
    const float* __restrict__ r_tm1, const float* __restrict__ wk,
    const float* __restrict__ rk, float* __restrict__ pre)
{
    __shared__ alignas(16) unsigned short Afr[8192];   // 16 KB [s4][tr4][lane64][e8]
    __shared__ alignas(16) unsigned short Bfr[8192];   // 16 KB [s4][tc4][lane64][e8]
    const int cb = blockIdx.x % 72, kh = blockIdx.x / 72;
    const int vcol0 = cb * 64;
    const float* A; const float* W; int wstride, wcol0;
    if (vcol0 < 2048)      { A = inputs; W = wk; wstride = 2048; wcol0 = vcol0; }
    else if (vcol0 < 4096) { A = h_tm1;  W = rk; wstride = 2560; wcol0 = vcol0 - 2048; }
    else                   { A = r_tm1;  W = rk; wstride = 2560; wcol0 = 2048 + (vcol0 - 4096); }
    const int tid = threadIdx.x;
    const int w = tid >> 6, lane = tid & 63;
    const int lhi = lane >> 4, llo = lane & 15;

    // --- stage A: 64 rows x 128 k (this quarter) -> A-frags ---
    {
        const int koct = tid & 15;                 // k-octet 0..15 (128 k)
        const int s = koct >> 2;                   // k-step
        #pragma unroll
        for (int i = 0; i < 4; ++i) {
            int row = i * 16 + (tid >> 4);
            const float* src = &A[row * 512 + kh * 128 + koct * 8];
            float4 x0 = *(const float4*)src;
            float4 x1 = *(const float4*)&src[4];
            int ln = (row & 15) + 16 * (koct & 3);
            int rt = row >> 4;
            union { unsigned short hx[8]; uint4 v; } pk;
            pk.hx[0] = f2bf(x0.x); pk.hx[1] = f2bf(x0.y);
            pk.hx[2] = f2bf(x0.z); pk.hx[3] = f2bf(x0.w);
            pk.hx[4] = f2bf(x1.x); pk.hx[5] = f2bf(x1.y);
            pk.hx[6] = f2bf(x1.z); pk.hx[7] = f2bf(x1.w);
            *(uint4*)&Afr[((s * 4 + rt) * 64 + ln) << 3] = pk.v;
        }
    }
    // --- stage B: 128 k x 64 cols -> B-frags ---
    #pragma unroll
    for (int q = 0; q < 8; ++q) {
        int idx = q * 256 + tid;                   // 2048 float4 slots
        int krow = idx >> 4;                       // 0..127
        int c4 = (idx & 15) * 4;                   // col base 0..60
        float4 wv = *(const float4*)&W[(size_t)(kh * 128 + krow) * wstride + wcol0 + c4];
        int s = krow >> 5, lh = (krow & 31) >> 3, e = krow & 7;
        float ws4[4] = { wv.x, wv.y, wv.z, wv.w };
        #pragma unroll
        for (int j = 0; j < 4; ++j) {
            int col = c4 + j;
            int tc = col >> 4;
            int ln = (col & 15) + 16 * lh;
            Bfr[(((s * 4 + tc) * 64 + ln) << 3) + e] = f2bf(ws4[j]);
        }
    }
    __syncthreads();

    // --- MFMA: wave w = row-tile w; 4 k-steps x 4 col-tiles ---
    f32x4 acc[4] = {};
    #pragma unroll
    for (int s = 0; s < 4; ++s) {
        bf16x8 af = *(const bf16x8*)&Afr[((s * 4 + w) * 64 + lane) << 3];
        #pragma unroll
        for (int tc = 0; tc < 4; ++tc) {
            bf16x8 bf = *(const bf16x8*)&Bfr[((s * 4 + tc) * 64 + lane) << 3];
            acc[tc] = __builtin_amdgcn_mfma_f32_16x16x32_bf16(af, bf, acc[tc], 0, 0, 0);
        }
    }

    float* dst = pre + (size_t)kh * 294912;
    #pragma unroll
    for (int tc = 0; tc < 4; ++tc) {
        #pragma unroll
        for (int reg = 0; reg < 4; ++reg) {
            int row = w * 16 + lhi * 4 + reg;
            dst[row * 4608 + vcol0 + tc * 16 + llo] = acc[tc][reg];
        }
    }
}

// ---------------------------------------------------------------------------
// K1c: gate fusion (sums 4 K-quarters) -> h, c; fused L2-norm + bf16 packing.
// grid 64 (one block per batch column b), 256 threads, 2 u per thread.
// ---------------------------------------------------------------------------
__global__ __launch_bounds__(256) void k_gates(
    const float* __restrict__ pre, const float* __restrict__ bias,
    const float* __restrict__ c_tm1, float* __restrict__ out,
    unsigned short* __restrict__ nkf, unsigned short* __restrict__ hbf)
{
    int b = blockIdx.x, t = threadIdx.x;
    const float* p0 = pre + b * 4608;
    const float* p1 = pre + 294912 + b * 4608;
    const float* p2 = pre + 2 * 294912 + b * 4608;
    const float* p3 = pre + 3 * 294912 + b * 4608;
    float hh[2], cc[2];
    #pragma unroll
    for (int q = 0; q < 2; ++q) {
        int u = t + q * 256;
        #define S4(o) (p0[o] + p1[o] + p2[o] + p3[o])
        float xi = S4(u)        + bias[u];
        float xf = S4(512 + u)  + bias[512 + u];
        float xc = S4(1024 + u) + bias[1024 + u];
        float xo = S4(1536 + u) + bias[1536 + u];
        float hi = S4(2048 + u);
        float hf = S4(2560 + u);
        float hc = S4(3072 + u);
        float ho = S4(3584 + u);
        float ri = S4(4096 + u);
        #undef S4
        float ig = hsig(xi + hi + ri);
        float fg = hsig(xf + hf);
        cc[q] = fg * c_tm1[b * 512 + u] + ig * tanhf(xc + hc);
        float og = hsig(xo + ho);
        hh[q] = og * tanhf(cc[q]);
        out[OUT_H + b * 512 + u] = hh[q];
        out[OUT_C + b * 512 + u] = cc[q];
    }
    float ss = hh[0] * hh[0] + hh[1] * hh[1];
    __shared__ float red[4];
    for (int m = 1; m < 64; m <<= 1) ss += __shfl_xor(ss, m);
    if ((t & 63) == 0) red[t >> 6] = ss;
    __syncthreads();
    float tot = red[0] + red[1] + red[2] + red[3];
    float rn = rsqrtf(fmaxf(tot, 1e-12f));
    #pragma unroll
    for (int q = 0; q < 2; ++q) {
        int u = t + q * 256;
        int s = u >> 5, n = b >> 4;
        int lane = (b & 15) + 16 * ((u & 31) >> 3);
        int e = u & 7;
        nkf[(((s * 4 + n) * 64 + lane) << 3) + e] = f2bf(hh[q] * rn);
        int s2 = b >> 5, N = u >> 4;
        int l2 = (u & 15) + 16 * ((b & 31) >> 3);
        int e2 = b & 7;
        hbf[(((s2 * 32 + N) * 64 + l2) << 3) + e2] = f2bf(hh[q]);
    }
}

// ---------------------------------------------------------------------------
// K2: cos GEMM via MFMA bf16 (f32 accum). 64 rows/block, grid 256.
// Fused: row-norm, softmax over batch, c_wr/c_wu, min/argmin partials,
// c_ww A-frags (for k_update) AND c_wr A-frags (for k_read_part).
// ---------------------------------------------------------------------------
__global__ __launch_bounds__(256) void k_cos(
    const float* __restrict__ m_tm1, const unsigned short* __restrict__ nkf,
    const float* __restrict__ cwr_tm1, const float* __restrict__ cwlu_tm1,
    const float* __restrict__ cwu_tm1, const float* __restrict__ wgp,
    float* out, float* __restrict__ pmin, int* __restrict__ pidx,
    unsigned short* __restrict__ cwwf, unsigned short* __restrict__ cwrf)
{
    __shared__ alignas(16) unsigned short Af[2048 * 8];   // 32 KB (reused: [0,4096)=cww frags, [4096,8192)=cwr frags)
    __shared__ float rn[64];
    __shared__ float pmv[4][64];
    __shared__ int   pmi[4][64];
    const int row0 = blockIdx.x * 64;
    const int tid = threadIdx.x;
    const int w = tid >> 6, lane = tid & 63;
    f32x4 acc[4] = {};
    float ssp[8] = {};

    for (int half = 0; half < 2; ++half) {
        #pragma unroll 2
        for (int i = 0; i < 8; ++i) {
            int r = i * 8 + (tid >> 5);
            int koct = tid & 31;
            const float* src = &m_tm1[(size_t)(row0 + r) * 512 + half * 256 + koct * 8];
            float4 x0 = *(const float4*)src;
            float4 x1 = *(const float4*)&src[4];
            ssp[i] += x0.x*x0.x + x0.y*x0.y + x0.z*x0.z + x0.w*x0.w
                    + x1.x*x1.x + x1.y*x1.y + x1.z*x1.z + x1.w*x1.w;
            int s_l = koct >> 2, rt = r >> 4;
            int ln = ((r & 15) + ((koct & 3) << 4)) ^ (s_l & 7);
            union { unsigned short hx[8]; uint4 v; } pk;
            pk.hx[0] = f2bf(x0.x); pk.hx[1] = f2bf(x0.y);
            pk.hx[2] = f2bf(x0.z); pk.hx[3] = f2bf(x0.w);
            pk.hx[4] = f2bf(x1.x); pk.hx[5] = f2bf(x1.y);
            pk.hx[6] = f2bf(x1.z); pk.hx[7] = f2bf(x1.w);
            *(uint4*)&Af[((s_l * 4 + rt) * 64 + ln) << 3] = pk.v;
        }
        __syncthreads();
        for (int s_l = 0; s_l < 8; ++s_l) {
            int lnx = lane ^ (s_l & 7);
            bf16x8 af = *(const bf16x8*)&Af[((s_l * 4 + w) * 64 + lnx) << 3];
            int s = half * 8 + s_l;
            #pragma unroll
            for (int n = 0; n < 4; ++n) {
                bf16x8 bf = *(const bf16x8*)&nkf[((s * 4 + n) * 64 + lane) << 3];
                acc[n] = __builtin_amdgcn_mfma_f32_16x16x32_bf16(af, bf, acc[n], 0, 0, 0);
            }
        }
        __syncthreads();
    }
    // row sumsq: one reduce per i-slot (both halves accumulated)
    #pragma unroll
    for (int i = 0; i < 8; ++i) {
        float v = ssp[i];
        v += __shfl_xor(v, 1); v += __shfl_xor(v, 2);
        v += __shfl_xor(v, 4); v += __shfl_xor(v, 8);
        v += __shfl_xor(v, 16);
        if ((tid & 31) == 0) rn[i * 8 + (tid >> 5)] = v;
    }
    __syncthreads();

    const float wg = 1.f / (1.f + expf(-wgp[0]));
    const int lhi = lane >> 4, llo = lane & 15;
    float rsq[4];
    #pragma unroll
    for (int reg = 0; reg < 4; ++reg) {
        int rl = w * 16 + lhi * 4 + reg;
        rsq[reg] = rsqrtf(fmaxf(rn[rl], 1e-12f));
    }
    float bmv[4] = { INFINITY, INFINITY, INFINITY, INFINITY };
    int   bmi[4] = { 0x7fffffff, 0x7fffffff, 0x7fffffff, 0x7fffffff };
    #pragma unroll
    for (int reg = 0; reg < 4; ++reg) {
        int rl = w * 16 + lhi * 4 + reg;   // r_local in [0,64)
        int r = row0 + rl;
        float c0 = acc[0][reg] * rsq[reg];
        float c1 = acc[1][reg] * rsq[reg];
        float c2 = acc[2][reg] * rsq[reg];
        float c3 = acc[3][reg] * rsq[reg];
        float mx = fmaxf(fmaxf(c0, c1), fmaxf(c2, c3));
        mx = fmaxf(mx, __shfl_xor(mx, 1));
        mx = fmaxf(mx, __shfl_xor(mx, 2));
        mx = fmaxf(mx, __shfl_xor(mx, 4));
        mx = fmaxf(mx, __shfl_xor(mx, 8));
        float e0 = expf(c0 - mx), e1 = expf(c1 - mx);
        float e2 = expf(c2 - mx), e3 = expf(c3 - mx);
        float sm = e0 + e1 + e2 + e3;
        sm += __shfl_xor(sm, 1);
        sm += __shfl_xor(sm, 2);
        sm += __shfl_xor(sm, 4);
        sm += __shfl_xor(sm, 8);
        float inv = 1.f / sm;
        float pv[4] = { e0 * inv, e1 * inv, e2 * inv, e3 * inv };
        #pragma unroll
        for (int n = 0; n < 4; ++n) {
            int g = r * 64 + n * 16 + llo;
            float p = pv[n];
            out[OUT_CWR + g] = p;
            float wr = cwr_tm1[g], wl = cwlu_tm1[g], wu = cwu_tm1[g];
            float cww = wg * wr + (1.f - wg) + wl;
            float cwu = 0.95f * wu + p + cww;
            out[OUT_CWU + g] = cwu;
            // c_ww A-frag for k_update: A[row=rl][k=b=n*16+llo]
            {
                int rowl16 = lhi * 4 + reg;
                int s2 = n >> 1;
                int l2 = rowl16 + 16 * (((n & 1) << 1) + (llo >> 3));
                Af[(((s2 * 4 + w) * 64 + l2) << 3) + (llo & 7)] = f2bf(cww);
            }
            // c_wr A-frag for k_read_part: A[row=b=n*16+llo][k=rl]
            {
                int sA = rl >> 5;
                int lf = llo + 16 * ((rl & 31) >> 3);
                Af[4096 + (((sA * 4 + n) * 64 + lf) << 3) + (rl & 7)] = f2bf(p);
            }
            if (cwu < bmv[n]) { bmv[n] = cwu; bmi[n] = r; }
        }
    }
    #pragma unroll
    for (int n = 0; n < 4; ++n) {
        #pragma unroll
        for (int mk = 16; mk <= 32; mk <<= 1) {
            float ov = __shfl_xor(bmv[n], mk);
            int   oi = __shfl_xor(bmi[n], mk);
            if (ov < bmv[n] || (ov == bmv[n] && oi < bmi[n])) { bmv[n] = ov; bmi[n] = oi; }
        }
    }
    if (lhi == 0) {
        #pragma unroll
        for (int n = 0; n < 4; ++n) { pmv[w][n * 16 + llo] = bmv[n]; pmi[w][n * 16 + llo] = bmi[n]; }
    }
    __syncthreads();
    // copy both 4096-ushort frag blocks out (coalesced uint4)
    {
        uint4* dstW = (uint4*)&cwwf[(size_t)blockIdx.x * 4096];
        uint4* dstR = (uint4*)&cwrf[(size_t)blockIdx.x * 4096];
        const uint4* srcp = (const uint4*)Af;
        dstW[tid]       = srcp[tid];
        dstW[tid + 256] = srcp[tid + 256];
        dstR[tid]       = srcp[512 + tid];
        dstR[tid + 256] = srcp[512 + tid + 256];
    }
    if (tid < 64) {
        float bv = pmv[0][tid]; int bi = pmi[0][tid];
        #pragma unroll
        for (int q = 1; q < 4; ++q) {
            float v = pmv[q][tid]; int i2 = pmi[q][tid];
            if (v < bv || (v == bv && i2 < bi)) { bv = v; bi = i2; }
        }
        pmin[blockIdx.x * 64 + tid] = bv;
        pidx[blockIdx.x * 64 + tid] = bi;
    }
}

// ---------------------------------------------------------------------------
// K5: read partials via MFMA bf16 + embedded minfinal.
// grid 512 = 64 row-splits(256 rows) x 8 u-splits(64).
// A-frags (cwr) pre-packed by k_cos (cwrf, L2-hot); only m staged in LDS.
// ---------------------------------------------------------------------------
__global__ __launch_bounds__(256) void k_read_part(
    const float* __restrict__ m_tm1, const unsigned short* __restrict__ cwrf,
    float* __restrict__ part,
    const float* __restrict__ pmin, const int* __restrict__ pidx,
    float* __restrict__ minf, int* __restrict__ idxf)
{
    __shared__ alignas(16) unsigned short Mf[8192];   // 16 KB: m B-frags
    __shared__ float sv[4]; __shared__ int si[4];
    const int bid = blockIdx.x;
    const int tid = threadIdx.x;
    if (bid < 64) {   // embedded minfinal (block-uniform branch)
        int col = bid;
        float bv = pmin[tid * 64 + col];
        int   bi = pidx[tid * 64 + col];
        for (int mk = 1; mk < 64; mk <<= 1) {
            float ov = __shfl_xor(bv, mk);
            int   oi = __shfl_xor(bi, mk);
            if (ov < bv || (ov == bv && oi < bi)) { bv = ov; bi = oi; }
        }
        if ((tid & 63) == 0) { sv[tid >> 6] = bv; si[tid >> 6] = bi; }
        __syncthreads();
        if (tid == 0) {
            #pragma unroll
            for (int q = 1; q < 4; ++q) {
                if (sv[q] < bv || (sv[q] == bv && si[q] < bi)) { bv = sv[q]; bi = si[q]; }
            }
            minf[col] = bv; idxf[col] = bi;
        }
    }
    const int rs = bid >> 3, us = bid & 7;
    const int row0 = rs * 256, u0 = us * 64;
    const int w = tid >> 6, lane = tid & 63;
    f32x4 acc[4] = {};
    for (int ch = 0; ch < 2; ++ch) {
        const int r0 = row0 + ch * 128;
        __syncthreads();
        #pragma unroll
        for (int q = 0; q < 8; ++q) {
            int idx = q * 1024 + tid * 4;
            int rr = idx >> 6, cc = idx & 63;
            float4 mv = *(const float4*)&m_tm1[(size_t)(r0 + rr) * 512 + u0 + cc];
            int s = rr >> 5, e = rr & 7, lo = 16 * ((rr & 31) >> 3);
            float mvs[4] = { mv.x, mv.y, mv.z, mv.w };
            #pragma unroll
            for (int i = 0; i < 4; ++i) {
                int col = cc + i;
                int ln = (col & 15) + lo;
                int t4 = col >> 4;
                Mf[(((s * 4 + t4) * 64 + ln) << 3) + e] = f2bf(mvs[i]);
            }
        }
        __syncthreads();
        const int sgbase = rs * 8 + ch * 4;
        #pragma unroll
        for (int s = 0; s < 4; ++s) {
            bf16x8 bf = *(const bf16x8*)&Mf[((s * 4 + w) * 64 + lane) << 3];
            #pragma unroll
            for (int tb = 0; tb < 4; ++tb) {
                bf16x8 af = *(const bf16x8*)&cwrf[(size_t)((((sgbase + s) * 4 + tb) * 64 + lane)) << 3];
                acc[tb] = __builtin_amdgcn_mfma_f32_16x16x32_bf16(af, bf, acc[tb], 0, 0, 0);
            }
        }
    }
    const int lhi = lane >> 4, llo = lane & 15;
    #pragma unroll
    for (int tb = 0; tb < 4; ++tb) {
        #pragma unroll
        for (int reg = 0; reg < 4; ++reg) {
            int b = tb * 16 + lhi * 4 + reg;
            part[(size_t)rs * 32768 + b * 512 + u0 + w * 16 + llo] = acc[tb][reg];
        }
    }
}

// ---------------------------------------------------------------------------
// K4: c_wlu compare + keep mask + m = m_tm1*keep + c_ww @ h via MFMA bf16.
// A-frags (c_ww) pre-packed by k_cos; embedded read-final (us==1 blocks).
// grid 1024 = 256 row-blocks(64) x 4 u-splits(128).
// ---------------------------------------------------------------------------
__global__ __launch_bounds__(256) void k_update(
    const float* __restrict__ m_tm1, const unsigned short* __restrict__ cwwf,
    const unsigned short* __restrict__ hbf,
    const float* __restrict__ minf, const int* __restrict__ idxf,
    const float* __restrict__ rpart, float* out)
{
    __shared__ float keepf[64];
    __shared__ float minS[64];
    __shared__ int   idxS[64];
    const int rb = blockIdx.x >> 2, us = blockIdx.x & 3;
    const int row0 = rb * 64, u0 = us * 128;
    const int tid = threadIdx.x;
    const int w = tid >> 6, lane = tid & 63;
    const int lhi = lane >> 4, llo = lane & 15;
    if (tid < 64) { idxS[tid] = idxf[tid]; minS[tid] = minf[tid]; }
    __syncthreads();
    if (tid < 64) {
        int gr = row0 + tid;
        float f = 1.f;
        #pragma unroll
        for (int b = 0; b < 64; ++b) if (idxS[b] == gr) f = 0.f;
        keepf[tid] = f;
    }
    __syncthreads();
    if (us == 0) {
        #pragma unroll
        for (int q = 0; q < 4; ++q) {
            int idx = q * 1024 + tid * 4;
            int r = idx >> 6, b = idx & 63;
            int g = (row0 + r) * 64 + b;
            float4 cu = *(const float4*)&out[OUT_CWU + g];
            float4 res;
            res.x = (cu.x <= minS[b + 0]) ? 1.f : 0.f;
            res.y = (cu.y <= minS[b + 1]) ? 1.f : 0.f;
            res.z = (cu.z <= minS[b + 2]) ? 1.f : 0.f;
            res.w = (cu.w <= minS[b + 3]) ? 1.f : 0.f;
            *(float4*)&out[OUT_CWLU + g] = res;
        }
    } else if (us == 1) {
        if (tid < 128) {
            int gid = rb * 128 + tid;
            float s = 0.f;
            #pragma unroll 8
            for (int rs = 0; rs < 64; ++rs) s += rpart[(size_t)rs * 32768 + gid];
            out[OUT_READ + gid] = s;
        }
    }
    f32x4 acc[8];
    #pragma unroll
    for (int nt = 0; nt < 8; ++nt) {
        #pragma unroll
        for (int reg = 0; reg < 4; ++reg) {
            int rowl = w * 16 + lhi * 4 + reg;
            acc[nt][reg] = m_tm1[(size_t)(row0 + rowl) * 512 + u0 + nt * 16 + llo]
                         * keepf[rowl];
        }
    }
    #pragma unroll
    for (int s = 0; s < 2; ++s) {
        bf16x8 af = *(const bf16x8*)&cwwf[(size_t)rb * 4096 + (((s * 4 + w) * 64 + lane) << 3)];
        #pragma unroll
        for (int nt = 0; nt < 8; ++nt) {
            int N = (u0 >> 4) + nt;
            bf16x8 bf = *(const bf16x8*)&hbf[((s * 32 + N) * 64 + lane) << 3];
            acc[nt] = __builtin_amdgcn_mfma_f32_16x16x32_bf16(af, bf, acc[nt], 0, 0, 0);
        }
    }
    #pragma unroll
    for (int nt = 0; nt < 8; ++nt) {
        #pragma unroll
        for (int reg = 0; reg < 4; ++reg) {
            int rowl = w * 16 + lhi * 4 + reg;
            out[OUT_M + (size_t)(row0 + rowl) * 512 + u0 + nt * 16 + llo] = acc[nt][reg];
        }
    }
}

extern "C" void kernel_launch(void* const* d_in, const int* in_sizes, int n_in,
                              void* d_out, int out_size, void* d_ws, size_t ws_size,
                              hipStream_t stream)
{
    const float* inputs    = (const float*)d_in[0];
    const float* h_tm1     = (const float*)d_in[1];
    const float* c_tm1     = (const float*)d_in[2];
    const float* r_tm1     = (const float*)d_in[3];
    const float* m_tm1     = (const float*)d_in[4];
    const float* c_wu_tm1  = (const float*)d_in[5];
    const float* c_wlu_tm1 = (const float*)d_in[6];
    const float* c_wr_tm1  = (const float*)d_in[7];
    const float* wk        = (const float*)d_in[8];
    const float* rk        = (const float*)d_in[9];
    const float* bias      = (const float*)d_in[10];
    const float* wgate     = (const float*)d_in[11];
    float* out = (float*)d_out;
    float* ws  = (float*)d_ws;
    float* pre = out + OUT_M;   // scratch in OUT_M region; consumed by k_gates
    unsigned short* nkf  = (unsigned short*)(ws + WS_NKF);
    unsigned short* hbf  = (unsigned short*)(ws + WS_HBF);
    unsigned short* cwwf = (unsigned short*)(ws + WS_CWWF);
    unsigned short* cwrf = (unsigned short*)(ws + WS_CWRF);
    float* rpart = ws + WS_RPART;

    k_preact<<<288, 256, 0, stream>>>(inputs, h_tm1, r_tm1, wk, rk, pre);
    k_gates<<<64, 256, 0, stream>>>(pre, bias, c_tm1, out, nkf, hbf);
    k_cos<<<256, 256, 0, stream>>>(m_tm1, nkf, c_wr_tm1, c_wlu_tm1,
                                   c_wu_tm1, wgate, out, ws + WS_PMIN,
                                   (int*)(ws + WS_PIDX), cwwf, cwrf);
    k_read_part<<<512, 256, 0, stream>>>(m_tm1, cwrf, rpart,
                                         ws + WS_PMIN, (const int*)(ws + WS_PIDX),
                                         ws + WS_MINF, (int*)(ws + WS_IDXF));
    k_update<<<1024, 256, 0, stream>>>(m_tm1, cwwf, hbf,
                                       ws + WS_MINF, (const int*)(ws + WS_IDXF),
                                       rpart, out);
}

// Round 16
// 59.492 us; speedup vs baseline: 2.3508x; 1.0486x over previous
//
#include <hip/hip_runtime.h>
#include <math.h>

// Problem dims: UNITS=512, MEM=16384, BATCH=64
// d_out offsets (floats): h, c, read, m, c_wu, c_wlu, c_wr
#define OUT_H    0
#define OUT_C    32768
#define OUT_READ 65536
#define OUT_M    98304
#define OUT_CWU  8486912
#define OUT_CWLU 9535488
#define OUT_CWR  10584064

// preact scratch (4*294912 floats) lives in OUT_M region, consumed by k_gates
// before k_update overwrites m. Everything else in d_ws (ws_size ~268MB).
// ws offsets (floats) — ushort buffers: floats = ushort_count/2 (CHECKED):
//   nkf  32768 ush = 16384 fl: [0,16384)
//   hbf  32768 ush = 16384 fl: [16384,32768)
//   cwwf 256*4096 ush = 524288 fl: [65664,589952)
//   cwrf 256*4096 ush = 524288 fl: [589952,1114240)
//   rpart 2M fl: [1114240,3211520)
#define WS_NKF   0
#define WS_HBF   16384
#define WS_PMIN  32768      // 256*64 partial min values
#define WS_PIDX  49152      // 256*64 partial min indices (int)
#define WS_MINF  65536      // 64 final min
#define WS_IDXF  65600      // 64 final argmin (int)
#define WS_CWWF  65664
#define WS_CWRF  589952
#define WS_RPART 1114240

typedef short bf16x8 __attribute__((ext_vector_type(8)));
typedef float f32x4  __attribute__((ext_vector_type(4)));

__device__ __forceinline__ float hsig(float x) {
    return fminf(fmaxf(0.2f * x + 0.5f, 0.f), 1.f);
}
__device__ __forceinline__ unsigned short f2bf(float x) {
    unsigned u = __float_as_uint(x);
    return (unsigned short)((u + 0x7fffu + ((u >> 16) & 1u)) >> 16);
}

// ---------------------------------------------------------------------------
// K1: preactivations via MFMA bf16. (verified round 15)
// grid 288 = 72 col-tiles(64) x 4 K-quarters(128). Block 256.
// ---------------------------------------------------------------------------
__global__ __launch_bounds__(256) void k_preact(
    const float* __restrict__ inputs, const float* __restrict__ h_tm1,
    const float* __restrict__ r_tm1, const float* __restrict__ wk,
    const float* __restrict__ rk, float* __restrict__ pre)
{
    __shared__ alignas(16) unsigned short Afr[8192];   // 16 KB
    __shared__ alignas(16) unsigned short Bfr[8192];   // 16 KB
    const int cb = blockIdx.x % 72, kh = blockIdx.x / 72;
    const int vcol0 = cb * 64;
    const float* A; const float* W; int wstride, wcol0;
    if (vcol0 < 2048)      { A = inputs; W = wk; wstride = 2048; wcol0 = vcol0; }
    else if (vcol0 < 4096) { A = h_tm1;  W = rk; wstride = 2560; wcol0 = vcol0 - 2048; }
    else                   { A = r_tm1;  W = rk; wstride = 2560; wcol0 = 2048 + (vcol0 - 4096); }
    const int tid = threadIdx.x;
    const int w = tid >> 6, lane = tid & 63;
    const int lhi = lane >> 4, llo = lane & 15;

    {
        const int koct = tid & 15;
        const int s = koct >> 2;
        #pragma unroll
        for (int i = 0; i < 4; ++i) {
            int row = i * 16 + (tid >> 4);
            const float* src = &A[row * 512 + kh * 128 + koct * 8];
            float4 x0 = *(const float4*)src;
            float4 x1 = *(const float4*)&src[4];
            int ln = (row & 15) + 16 * (koct & 3);
            int rt = row >> 4;
            union { unsigned short hx[8]; uint4 v; } pk;
            pk.hx[0] = f2bf(x0.x); pk.hx[1] = f2bf(x0.y);
            pk.hx[2] = f2bf(x0.z); pk.hx[3] = f2bf(x0.w);
            pk.hx[4] = f2bf(x1.x); pk.hx[5] = f2bf(x1.y);
            pk.hx[6] = f2bf(x1.z); pk.hx[7] = f2bf(x1.w);
            *(uint4*)&Afr[((s * 4 + rt) * 64 + ln) << 3] = pk.v;
        }
    }
    #pragma unroll
    for (int q = 0; q < 8; ++q) {
        int idx = q * 256 + tid;
        int krow = idx >> 4;
        int c4 = (idx & 15) * 4;
        float4 wv = *(const float4*)&W[(size_t)(kh * 128 + krow) * wstride + wcol0 + c4];
        int s = krow >> 5, lh = (krow & 31) >> 3, e = krow & 7;
        float ws4[4] = { wv.x, wv.y, wv.z, wv.w };
        #pragma unroll
        for (int j = 0; j < 4; ++j) {
            int col = c4 + j;
            int tc = col >> 4;
            int ln = (col & 15) + 16 * lh;
            Bfr[(((s * 4 + tc) * 64 + ln) << 3) + e] = f2bf(ws4[j]);
        }
    }
    __syncthreads();

    f32x4 acc[4] = {};
    #pragma unroll
    for (int s = 0; s < 4; ++s) {
        bf16x8 af = *(const bf16x8*)&Afr[((s * 4 + w) * 64 + lane) << 3];
        #pragma unroll
        for (int tc = 0; tc < 4; ++tc) {
            bf16x8 bf = *(const bf16x8*)&Bfr[((s * 4 + tc) * 64 + lane) << 3];
            acc[tc] = __builtin_amdgcn_mfma_f32_16x16x32_bf16(af, bf, acc[tc], 0, 0, 0);
        }
    }

    float* dst = pre + (size_t)kh * 294912;
    #pragma unroll
    for (int tc = 0; tc < 4; ++tc) {
        #pragma unroll
        for (int reg = 0; reg < 4; ++reg) {
            int row = w * 16 + lhi * 4 + reg;
            dst[row * 4608 + vcol0 + tc * 16 + llo] = acc[tc][reg];
        }
    }
}

// ---------------------------------------------------------------------------
// K1c: gate fusion (sums 4 K-quarters) -> h, c; fused L2-norm + bf16 packing.
// grid 64 (one block per batch column b), 256 threads, 2 u per thread.
// ---------------------------------------------------------------------------
__global__ __launch_bounds__(256) void k_gates(
    const float* __restrict__ pre, const float* __restrict__ bias,
    const float* __restrict__ c_tm1, float* __restrict__ out,
    unsigned short* __restrict__ nkf, unsigned short* __restrict__ hbf)
{
    int b = blockIdx.x, t = threadIdx.x;
    const float* p0 = pre + b * 4608;
    const float* p1 = pre + 294912 + b * 4608;
    const float* p2 = pre + 2 * 294912 + b * 4608;
    const float* p3 = pre + 3 * 294912 + b * 4608;
    float hh[2], cc[2];
    #pragma unroll
    for (int q = 0; q < 2; ++q) {
        int u = t + q * 256;
        #define S4(o) (p0[o] + p1[o] + p2[o] + p3[o])
        float xi = S4(u)        + bias[u];
        float xf = S4(512 + u)  + bias[512 + u];
        float xc = S4(1024 + u) + bias[1024 + u];
        float xo = S4(1536 + u) + bias[1536 + u];
        float hi = S4(2048 + u);
        float hf = S4(2560 + u);
        float hc = S4(3072 + u);
        float ho = S4(3584 + u);
        float ri = S4(4096 + u);
        #undef S4
        float ig = hsig(xi + hi + ri);
        float fg = hsig(xf + hf);
        cc[q] = fg * c_tm1[b * 512 + u] + ig * tanhf(xc + hc);
        float og = hsig(xo + ho);
        hh[q] = og * tanhf(cc[q]);
        out[OUT_H + b * 512 + u] = hh[q];
        out[OUT_C + b * 512 + u] = cc[q];
    }
    float ss = hh[0] * hh[0] + hh[1] * hh[1];
    __shared__ float red[4];
    for (int m = 1; m < 64; m <<= 1) ss += __shfl_xor(ss, m);
    if ((t & 63) == 0) red[t >> 6] = ss;
    __syncthreads();
    float tot = red[0] + red[1] + red[2] + red[3];
    float rn = rsqrtf(fmaxf(tot, 1e-12f));
    #pragma unroll
    for (int q = 0; q < 2; ++q) {
        int u = t + q * 256;
        int s = u >> 5, n = b >> 4;
        int lane = (b & 15) + 16 * ((u & 31) >> 3);
        int e = u & 7;
        nkf[(((s * 4 + n) * 64 + lane) << 3) + e] = f2bf(hh[q] * rn);
        int s2 = b >> 5, N = u >> 4;
        int l2 = (u & 15) + 16 * ((b & 31) >> 3);
        int e2 = b & 7;
        hbf[(((s2 * 32 + N) * 64 + l2) << 3) + e2] = f2bf(hh[q]);
    }
}

// ---------------------------------------------------------------------------
// K2: cos GEMM via MFMA bf16, 512 threads (8 waves = 2 waves/SIMD).
// 64 rows/block, grid 256. Wave w: row-tile (w&3), K-half (w>>2); halves
// reduced via LDS. Fused: row-norm, softmax, c_wr/c_wu, min partials,
// c_ww + c_wr A-frag production.
// ---------------------------------------------------------------------------
__global__ __launch_bounds__(512) void k_cos(
    const float* __restrict__ m_tm1, const unsigned short* __restrict__ nkf,
    const float* __restrict__ cwr_tm1, const float* __restrict__ cwlu_tm1,
    const float* __restrict__ cwu_tm1, const float* __restrict__ wgp,
    float* out, float* __restrict__ pmin, int* __restrict__ pidx,
    unsigned short* __restrict__ cwwf, unsigned short* __restrict__ cwrf)
{
    __shared__ alignas(16) unsigned short Af[4096 * 8];   // 64 KB: all 16 k-steps
    __shared__ alignas(16) float redacc[4][4][64][4];     // 16 KB: K-half reduce
    __shared__ float rn[64];
    __shared__ float pmv[4][64];
    __shared__ int   pmi[4][64];
    const int row0 = blockIdx.x * 64;
    const int tid = threadIdx.x;
    const int w = tid >> 6, lane = tid & 63;
    f32x4 acc[4] = {};
    float ssp[8] = {};

    // --- stage all 64 rows x 512 k as bf16 A-frags; wave w stages row i*8+w ---
    #pragma unroll
    for (int i = 0; i < 8; ++i) {
        int r = i * 8 + w;
        int koct = lane;                           // 0..63 k-octets
        const float* src = &m_tm1[(size_t)(row0 + r) * 512 + koct * 8];
        float4 x0 = *(const float4*)src;
        float4 x1 = *(const float4*)&src[4];
        ssp[i] += x0.x*x0.x + x0.y*x0.y + x0.z*x0.z + x0.w*x0.w
                + x1.x*x1.x + x1.y*x1.y + x1.z*x1.z + x1.w*x1.w;
        int s_l = koct >> 2, rt = r >> 4;
        int ln = ((r & 15) + ((koct & 3) << 4)) ^ (s_l & 7);
        union { unsigned short hx[8]; uint4 v; } pk;
        pk.hx[0] = f2bf(x0.x); pk.hx[1] = f2bf(x0.y);
        pk.hx[2] = f2bf(x0.z); pk.hx[3] = f2bf(x0.w);
        pk.hx[4] = f2bf(x1.x); pk.hx[5] = f2bf(x1.y);
        pk.hx[6] = f2bf(x1.z); pk.hx[7] = f2bf(x1.w);
        *(uint4*)&Af[((s_l * 4 + rt) * 64 + ln) << 3] = pk.v;
    }
    // row sumsq: full-wave reduce, lane 0 writes rn[i*8+w]
    #pragma unroll
    for (int i = 0; i < 8; ++i) {
        float v = ssp[i];
        v += __shfl_xor(v, 1); v += __shfl_xor(v, 2);
        v += __shfl_xor(v, 4); v += __shfl_xor(v, 8);
        v += __shfl_xor(v, 16); v += __shfl_xor(v, 32);
        if (lane == 0) rn[i * 8 + w] = v;
    }
    __syncthreads();

    // --- MFMA: wave w = row-tile (w&3), K-half (w>>2): 8 k-steps ---
    {
        const int wt = w & 3, kh2 = w >> 2;
        for (int s_l = 0; s_l < 8; ++s_l) {
            int s = kh2 * 8 + s_l;
            int lnx = lane ^ (s & 7);
            bf16x8 af = *(const bf16x8*)&Af[((s * 4 + wt) * 64 + lnx) << 3];
            #pragma unroll
            for (int n = 0; n < 4; ++n) {
                bf16x8 bf = *(const bf16x8*)&nkf[((s * 4 + n) * 64 + lane) << 3];
                acc[n] = __builtin_amdgcn_mfma_f32_16x16x32_bf16(af, bf, acc[n], 0, 0, 0);
            }
        }
    }
    // --- reduce K-halves: waves 4-7 store, waves 0-3 add ---
    if (w >= 4) {
        #pragma unroll
        for (int n = 0; n < 4; ++n)
            *(f32x4*)&redacc[w - 4][n][lane][0] = acc[n];
    }
    __syncthreads();
    if (w < 4) {
        #pragma unroll
        for (int n = 0; n < 4; ++n) {
            f32x4 o = *(const f32x4*)&redacc[w][n][lane][0];
            acc[n][0] += o[0]; acc[n][1] += o[1]; acc[n][2] += o[2]; acc[n][3] += o[3];
        }
    }

    const float wg = 1.f / (1.f + expf(-wgp[0]));
    const int lhi = lane >> 4, llo = lane & 15;
    if (w < 4) {
        float rsq[4];
        #pragma unroll
        for (int reg = 0; reg < 4; ++reg) {
            int rl = w * 16 + lhi * 4 + reg;
            rsq[reg] = rsqrtf(fmaxf(rn[rl], 1e-12f));
        }
        float bmv[4] = { INFINITY, INFINITY, INFINITY, INFINITY };
        int   bmi[4] = { 0x7fffffff, 0x7fffffff, 0x7fffffff, 0x7fffffff };
        #pragma unroll
        for (int reg = 0; reg < 4; ++reg) {
            int rl = w * 16 + lhi * 4 + reg;   // r_local in [0,64)
            int r = row0 + rl;
            float c0 = acc[0][reg] * rsq[reg];
            float c1 = acc[1][reg] * rsq[reg];
            float c2 = acc[2][reg] * rsq[reg];
            float c3 = acc[3][reg] * rsq[reg];
            float mx = fmaxf(fmaxf(c0, c1), fmaxf(c2, c3));
            mx = fmaxf(mx, __shfl_xor(mx, 1));
            mx = fmaxf(mx, __shfl_xor(mx, 2));
            mx = fmaxf(mx, __shfl_xor(mx, 4));
            mx = fmaxf(mx, __shfl_xor(mx, 8));
            float e0 = expf(c0 - mx), e1 = expf(c1 - mx);
            float e2 = expf(c2 - mx), e3 = expf(c3 - mx);
            float sm = e0 + e1 + e2 + e3;
            sm += __shfl_xor(sm, 1);
            sm += __shfl_xor(sm, 2);
            sm += __shfl_xor(sm, 4);
            sm += __shfl_xor(sm, 8);
            float inv = 1.f / sm;
            float pv[4] = { e0 * inv, e1 * inv, e2 * inv, e3 * inv };
            #pragma unroll
            for (int n = 0; n < 4; ++n) {
                int g = r * 64 + n * 16 + llo;
                float p = pv[n];
                out[OUT_CWR + g] = p;
                float wr = cwr_tm1[g], wl = cwlu_tm1[g], wu = cwu_tm1[g];
                float cww = wg * wr + (1.f - wg) + wl;
                float cwu = 0.95f * wu + p + cww;
                out[OUT_CWU + g] = cwu;
                // c_ww A-frag for k_update: A[row=rl][k=b=n*16+llo]
                {
                    int rowl16 = lhi * 4 + reg;
                    int s2 = n >> 1;
                    int l2 = rowl16 + 16 * (((n & 1) << 1) + (llo >> 3));
                    Af[(((s2 * 4 + w) * 64 + l2) << 3) + (llo & 7)] = f2bf(cww);
                }
                // c_wr A-frag for k_read_part: A[row=b=n*16+llo][k=rl]
                {
                    int sA = rl >> 5;
                    int lf = llo + 16 * ((rl & 31) >> 3);
                    Af[4096 + (((sA * 4 + n) * 64 + lf) << 3) + (rl & 7)] = f2bf(p);
                }
                if (cwu < bmv[n]) { bmv[n] = cwu; bmi[n] = r; }
            }
        }
        #pragma unroll
        for (int n = 0; n < 4; ++n) {
            #pragma unroll
            for (int mk = 16; mk <= 32; mk <<= 1) {
                float ov = __shfl_xor(bmv[n], mk);
                int   oi = __shfl_xor(bmi[n], mk);
                if (ov < bmv[n] || (ov == bmv[n] && oi < bmi[n])) { bmv[n] = ov; bmi[n] = oi; }
            }
        }
        if (lhi == 0) {
            #pragma unroll
            for (int n = 0; n < 4; ++n) { pmv[w][n * 16 + llo] = bmv[n]; pmi[w][n * 16 + llo] = bmi[n]; }
        }
    }
    __syncthreads();
    // copy both 4096-ushort frag blocks out (512 uint4 each; all 512 threads)
    {
        uint4* dstW = (uint4*)&cwwf[(size_t)blockIdx.x * 4096];
        uint4* dstR = (uint4*)&cwrf[(size_t)blockIdx.x * 4096];
        const uint4* srcp = (const uint4*)Af;
        dstW[tid] = srcp[tid];
        dstR[tid] = srcp[512 + tid];
    }
    if (tid < 64) {
        float bv = pmv[0][tid]; int bi = pmi[0][tid];
        #pragma unroll
        for (int q = 1; q < 4; ++q) {
            float v = pmv[q][tid]; int i2 = pmi[q][tid];
            if (v < bv || (v == bv && i2 < bi)) { bv = v; bi = i2; }
        }
        pmin[blockIdx.x * 64 + tid] = bv;
        pidx[blockIdx.x * 64 + tid] = bi;
    }
}

// ---------------------------------------------------------------------------
// K5: read partials via MFMA bf16 + embedded minfinal. (verified round 14)
// grid 512 = 64 row-splits(256 rows) x 8 u-splits(64).
// ---------------------------------------------------------------------------
__global__ __launch_bounds__(256) void k_read_part(
    const float* __restrict__ m_tm1, const unsigned short* __restrict__ cwrf,
    float* __restrict__ part,
    const float* __restrict__ pmin, const int* __restrict__ pidx,
    float* __restrict__ minf, int* __restrict__ idxf)
{
    __shared__ alignas(16) unsigned short Mf[8192];   // 16 KB: m B-frags
    __shared__ float sv[4]; __shared__ int si[4];
    const int bid = blockIdx.x;
    const int tid = threadIdx.x;
    if (bid < 64) {   // embedded minfinal (block-uniform branch)
        int col = bid;
        float bv = pmin[tid * 64 + col];
        int   bi = pidx[tid * 64 + col];
        for (int mk = 1; mk < 64; mk <<= 1) {
            float ov = __shfl_xor(bv, mk);
            int   oi = __shfl_xor(bi, mk);
            if (ov < bv || (ov == bv && oi < bi)) { bv = ov; bi = oi; }
        }
        if ((tid & 63) == 0) { sv[tid >> 6] = bv; si[tid >> 6] = bi; }
        __syncthreads();
        if (tid == 0) {
            #pragma unroll
            for (int q = 1; q < 4; ++q) {
                if (sv[q] < bv || (sv[q] == bv && si[q] < bi)) { bv = sv[q]; bi = si[q]; }
            }
            minf[col] = bv; idxf[col] = bi;
        }
    }
    const int rs = bid >> 3, us = bid & 7;
    const int row0 = rs * 256, u0 = us * 64;
    const int w = tid >> 6, lane = tid & 63;
    f32x4 acc[4] = {};
    for (int ch = 0; ch < 2; ++ch) {
        const int r0 = row0 + ch * 128;
        __syncthreads();
        #pragma unroll
        for (int q = 0; q < 8; ++q) {
            int idx = q * 1024 + tid * 4;
            int rr = idx >> 6, cc = idx & 63;
            float4 mv = *(const float4*)&m_tm1[(size_t)(r0 + rr) * 512 + u0 + cc];
            int s = rr >> 5, e = rr & 7, lo = 16 * ((rr & 31) >> 3);
            float mvs[4] = { mv.x, mv.y, mv.z, mv.w };
            #pragma unroll
            for (int i = 0; i < 4; ++i) {
                int col = cc + i;
                int ln = (col & 15) + lo;
                int t4 = col >> 4;
                Mf[(((s * 4 + t4) * 64 + ln) << 3) + e] = f2bf(mvs[i]);
            }
        }
        __syncthreads();
        const int sgbase = rs * 8 + ch * 4;
        #pragma unroll
        for (int s = 0; s < 4; ++s) {
            bf16x8 bf = *(const bf16x8*)&Mf[((s * 4 + w) * 64 + lane) << 3];
            #pragma unroll
            for (int tb = 0; tb < 4; ++tb) {
                bf16x8 af = *(const bf16x8*)&cwrf[(size_t)((((sgbase + s) * 4 + tb) * 64 + lane)) << 3];
                acc[tb] = __builtin_amdgcn_mfma_f32_16x16x32_bf16(af, bf, acc[tb], 0, 0, 0);
            }
        }
    }
    const int lhi = lane >> 4, llo = lane & 15;
    #pragma unroll
    for (int tb = 0; tb < 4; ++tb) {
        #pragma unroll
        for (int reg = 0; reg < 4; ++reg) {
            int b = tb * 16 + lhi * 4 + reg;
            part[(size_t)rs * 32768 + b * 512 + u0 + w * 16 + llo] = acc[tb][reg];
        }
    }
}

// ---------------------------------------------------------------------------
// K4: c_wlu compare + keep mask + m = m_tm1*keep + c_ww @ h via MFMA bf16.
// A-frags (c_ww) pre-packed by k_cos; embedded read-final (us==1 blocks).
// grid 1024 = 256 row-blocks(64) x 4 u-splits(128).
// ---------------------------------------------------------------------------
__global__ __launch_bounds__(256) void k_update(
    const float* __restrict__ m_tm1, const unsigned short* __restrict__ cwwf,
    const unsigned short* __restrict__ hbf,
    const float* __restrict__ minf, const int* __restrict__ idxf,
    const float* __restrict__ rpart, float* out)
{
    __shared__ float keepf[64];
    __shared__ float minS[64];
    __shared__ int   idxS[64];
    const int rb = blockIdx.x >> 2, us = blockIdx.x & 3;
    const int row0 = rb * 64, u0 = us * 128;
    const int tid = threadIdx.x;
    const int w = tid >> 6, lane = tid & 63;
    const int lhi = lane >> 4, llo = lane & 15;
    if (tid < 64) { idxS[tid] = idxf[tid]; minS[tid] = minf[tid]; }
    __syncthreads();
    if (tid < 64) {
        int gr = row0 + tid;
        float f = 1.f;
        #pragma unroll
        for (int b = 0; b < 64; ++b) if (idxS[b] == gr) f = 0.f;
        keepf[tid] = f;
    }
    __syncthreads();
    if (us == 0) {
        #pragma unroll
        for (int q = 0; q < 4; ++q) {
            int idx = q * 1024 + tid * 4;
            int r = idx >> 6, b = idx & 63;
            int g = (row0 + r) * 64 + b;
            float4 cu = *(const float4*)&out[OUT_CWU + g];
            float4 res;
            res.x = (cu.x <= minS[b + 0]) ? 1.f : 0.f;
            res.y = (cu.y <= minS[b + 1]) ? 1.f : 0.f;
            res.z = (cu.z <= minS[b + 2]) ? 1.f : 0.f;
            res.w = (cu.w <= minS[b + 3]) ? 1.f : 0.f;
            *(float4*)&out[OUT_CWLU + g] = res;
        }
    } else if (us == 1) {
        if (tid < 128) {
            int gid = rb * 128 + tid;
            float s = 0.f;
            #pragma unroll 8
            for (int rs = 0; rs < 64; ++rs) s += rpart[(size_t)rs * 32768 + gid];
            out[OUT_READ + gid] = s;
        }
    }
    f32x4 acc[8];
    #pragma unroll
    for (int nt = 0; nt < 8; ++nt) {
        #pragma unroll
        for (int reg = 0; reg < 4; ++reg) {
            int rowl = w * 16 + lhi * 4 + reg;
            acc[nt][reg] = m_tm1[(size_t)(row0 + rowl) * 512 + u0 + nt * 16 + llo]
                         * keepf[rowl];
        }
    }
    #pragma unroll
    for (int s = 0; s < 2; ++s) {
        bf16x8 af = *(const bf16x8*)&cwwf[(size_t)rb * 4096 + (((s * 4 + w) * 64 + lane) << 3)];
        #pragma unroll
        for (int nt = 0; nt < 8; ++nt) {
            int N = (u0 >> 4) + nt;
            bf16x8 bf = *(const bf16x8*)&hbf[((s * 32 + N) * 64 + lane) << 3];
            acc[nt] = __builtin_amdgcn_mfma_f32_16x16x32_bf16(af, bf, acc[nt], 0, 0, 0);
        }
    }
    #pragma unroll
    for (int nt = 0; nt < 8; ++nt) {
        #pragma unroll
        for (int reg = 0; reg < 4; ++reg) {
            int rowl = w * 16 + lhi * 4 + reg;
            out[OUT_M + (size_t)(row0 + rowl) * 512 + u0 + nt * 16 + llo] = acc[nt][reg];
        }
    }
}

extern "C" void kernel_launch(void* const* d_in, const int* in_sizes, int n_in,
                              void* d_out, int out_size, void* d_ws, size_t ws_size,
                              hipStream_t stream)
{
    const float* inputs    = (const float*)d_in[0];
    const float* h_tm1     = (const float*)d_in[1];
    const float* c_tm1     = (const float*)d_in[2];
    const float* r_tm1     = (const float*)d_in[3];
    const float* m_tm1     = (const float*)d_in[4];
    const float* c_wu_tm1  = (const float*)d_in[5];
    const float* c_wlu_tm1 = (const float*)d_in[6];
    const float* c_wr_tm1  = (const float*)d_in[7];
    const float* wk        = (const float*)d_in[8];
    const float* rk        = (const float*)d_in[9];
    const float* bias      = (const float*)d_in[10];
    const float* wgate     = (const float*)d_in[11];
    float* out = (float*)d_out;
    float* ws  = (float*)d_ws;
    float* pre = out + OUT_M;   // scratch in OUT_M region; consumed by k_gates
    unsigned short* nkf  = (unsigned short*)(ws + WS_NKF);
    unsigned short* hbf  = (unsigned short*)(ws + WS_HBF);
    unsigned short* cwwf = (unsigned short*)(ws + WS_CWWF);
    unsigned short* cwrf = (unsigned short*)(ws + WS_CWRF);
    float* rpart = ws + WS_RPART;

    k_preact<<<288, 256, 0, stream>>>(inputs, h_tm1, r_tm1, wk, rk, pre);
    k_gates<<<64, 256, 0, stream>>>(pre, bias, c_tm1, out, nkf, hbf);
    k_cos<<<256, 512, 0, stream>>>(m_tm1, nkf, c_wr_tm1, c_wlu_tm1,
                                   c_wu_tm1, wgate, out, ws + WS_PMIN,
                                   (int*)(ws + WS_PIDX), cwwf, cwrf);
    k_read_part<<<512, 256, 0, stream>>>(m_tm1, cwrf, rpart,
                                         ws + WS_PMIN, (const int*)(ws + WS_PIDX),
                                         ws + WS_MINF, (int*)(ws + WS_IDXF));
    k_update<<<1024, 256, 0, stream>>>(m_tm1, cwwf, hbf,
                                       ws + WS_MINF, (const int*)(ws + WS_IDXF),
                                       rpart, out);
}